// Round 1
// baseline (7579.284 us; speedup 1.0000x reference)
//
#include <hip/hip_runtime.h>
#include <cmath>

// ---------------- constants ----------------
#define NB      4
#define NTOK    4096          // tokens per batch
#define BNTOK   16384
#define CDIM    192
#define CINNER  512
#define NHEADS  8
#define DHEAD   64
#define CFF     768
#define MFEAT   266
#define MPAD    320           // 5*64
#define MP2     272           // 17*16
#define NDEPTH  6

#define DN      0.35355339059327373f   // 64^-0.25
#define RATIO   0.06131393394849658f   // 266^-0.5
#define HALF_DN2 0.0625f               // 0.5 * dn^2

// workspace offsets (floats)
#define OFF_H    0ull
#define OFF_HN   3145728ull
#define OFF_Q    6291456ull
#define OFF_K    14680064ull      /* also attn_inner */
#define OFF_V    23068672ull
#define OFF_BIG  31457280ull      /* ff1 (12.58M floats) / decoder NCHW bufs */
#define OFF_CTXP 44040192ull
#define OFF_KSP  46661632ull
#define OFF_CTX  46702592ull
#define OFF_KSUM 47357952ull
#define OFF_KMAX 47368192ull      /* 192 uints */
#define OFF_GNP  47368448ull      /* 512 float2 */
#define OFF_GNS  47369472ull      /* 32 float2 */

__device__ __forceinline__ float gelu_f(float x) {
    return 0.5f * x * (1.0f + erff(x * 0.7071067811865476f));
}
__device__ __forceinline__ unsigned f2ord(float f) {
    int i = __float_as_int(f);
    return (i >= 0) ? ((unsigned)i | 0x80000000u) : (unsigned)(~i);
}
__device__ __forceinline__ float ord2f(unsigned u) {
    int i = (u & 0x80000000u) ? (int)(u & 0x7fffffffu) : ~(int)u;
    return __int_as_float(i);
}

// ---------------- input embed: h = x@W.T + b + pos ----------------
__global__ __launch_bounds__(256) void input_embed(const float* __restrict__ x,
    const float* __restrict__ w, const float* __restrict__ bvec,
    const float* __restrict__ pos, float* __restrict__ h)
{
    int idx = blockIdx.x * 256 + threadIdx.x;   // < 16384*192
    int row = idx / CDIM, c = idx - row * CDIM;
    int p = row & (NTOK - 1);
    const float* xr = x + (size_t)row * 3;
    h[idx] = xr[0]*w[c*3+0] + xr[1]*w[c*3+1] + xr[2]*w[c*3+2] + bvec[c] + pos[(size_t)p*CDIM + c];
}

// ---------------- scalenorm ----------------
__global__ __launch_bounds__(256) void scalenorm_kernel(const float* __restrict__ in,
    float* __restrict__ out, const float* __restrict__ gptr, int gidx)
{
    int wv = threadIdx.x >> 6, lane = threadIdx.x & 63;
    int row = blockIdx.x * 4 + wv;
    const float* p = in + (size_t)row * CDIM;
    float x0 = p[lane], x1 = p[lane + 64], x2 = p[lane + 128];
    float ss = x0*x0 + x1*x1 + x2*x2;
    #pragma unroll
    for (int off = 32; off; off >>= 1) ss += __shfl_xor(ss, off);
    float g = gptr[gidx];
    float n = sqrtf(ss * (1.0f / 192.0f));
    float s = g / fmaxf(n, 1e-5f);
    float* o = out + (size_t)row * CDIM;
    o[lane] = x0 * s; o[lane + 64] = x1 * s; o[lane + 128] = x2 * s;
}

// ---------------- GEMM: C[M,N] = A[M,K] @ B[N,K]^T (+bias,+gelu,+resid) ----------------
// epi: 1=bias, 2=gelu, 4=resid add
__global__ __launch_bounds__(256) void gemm_tn(const float* __restrict__ A,
    const float* __restrict__ Bw, const float* __restrict__ bias,
    const float* __restrict__ resid, float* __restrict__ C,
    int M, int N, int K, int epi)
{
    __shared__ __align__(16) float a_lds[32][68];
    __shared__ __align__(16) float b_lds[32][68];
    const int tid = threadIdx.x;
    const int tx = tid & 15, ty = tid >> 4;
    const int n0 = blockIdx.x * 64, m0 = blockIdx.y * 64;
    float acc[4][4] = {};
    for (int kc = 0; kc < K; kc += 32) {
        #pragma unroll
        for (int r = 0; r < 2; ++r) {
            int id = tid + r * 256;
            int row = id >> 3, kq = (id & 7) * 4;
            float4 av = *(const float4*)(A + (size_t)(m0 + row) * K + kc + kq);
            a_lds[kq+0][row] = av.x; a_lds[kq+1][row] = av.y;
            a_lds[kq+2][row] = av.z; a_lds[kq+3][row] = av.w;
            float4 bv = *(const float4*)(Bw + (size_t)(n0 + row) * K + kc + kq);
            b_lds[kq+0][row] = bv.x; b_lds[kq+1][row] = bv.y;
            b_lds[kq+2][row] = bv.z; b_lds[kq+3][row] = bv.w;
        }
        __syncthreads();
        #pragma unroll 8
        for (int kk = 0; kk < 32; ++kk) {
            float4 a = *(const float4*)&a_lds[kk][ty * 4];
            float4 b = *(const float4*)&b_lds[kk][tx * 4];
            acc[0][0] += a.x*b.x; acc[0][1] += a.x*b.y; acc[0][2] += a.x*b.z; acc[0][3] += a.x*b.w;
            acc[1][0] += a.y*b.x; acc[1][1] += a.y*b.y; acc[1][2] += a.y*b.z; acc[1][3] += a.y*b.w;
            acc[2][0] += a.z*b.x; acc[2][1] += a.z*b.y; acc[2][2] += a.z*b.z; acc[2][3] += a.z*b.w;
            acc[3][0] += a.w*b.x; acc[3][1] += a.w*b.y; acc[3][2] += a.w*b.z; acc[3][3] += a.w*b.w;
        }
        __syncthreads();
    }
    float4 bb = make_float4(0.f, 0.f, 0.f, 0.f);
    if (epi & 1) bb = *(const float4*)(bias + n0 + tx * 4);
    #pragma unroll
    for (int i = 0; i < 4; ++i) {
        size_t off = (size_t)(m0 + ty * 4 + i) * N + n0 + tx * 4;
        float4 c = make_float4(acc[i][0] + bb.x, acc[i][1] + bb.y, acc[i][2] + bb.z, acc[i][3] + bb.w);
        if (epi & 2) { c.x = gelu_f(c.x); c.y = gelu_f(c.y); c.z = gelu_f(c.z); c.w = gelu_f(c.w); }
        if (epi & 4) {
            float4 rv = *(const float4*)(resid + off);
            c.x += rv.x; c.y += rv.y; c.z += rv.z; c.w += rv.w;
        }
        *(float4*)(C + off) = c;
    }
}

// ---------------- kmax init ----------------
__global__ void kmax_init(unsigned* kmaxu) {
    if (threadIdx.x < NDEPTH * 32) kmaxu[threadIdx.x] = 0u;
}

// ---------------- k-feature global max per (b,h) ----------------
__global__ __launch_bounds__(256) void kmax_kernel(const float* __restrict__ Km,
    const float* __restrict__ pj, unsigned* __restrict__ kmaxu)
{
    __shared__ __align__(16) float projT[64][68];
    __shared__ __align__(16) float k_lds[64][68];
    __shared__ float red[256];
    const int tid = threadIdx.x;
    const int nt = blockIdx.x, bh = blockIdx.y;
    const int b = bh >> 3, hh = bh & 7;
    const int n0 = nt * 64;
    const size_t kbase = ((size_t)b * NTOK + n0) * CINNER + hh * DHEAD;
    #pragma unroll
    for (int r = 0; r < 4; ++r) {
        int id = tid + r * 256;
        int row = id >> 4, kq = (id & 15) * 4;
        *(float4*)&k_lds[row][kq] = *(const float4*)(Km + kbase + (size_t)row * CINNER + kq);
    }
    const int mg = tid & 15, jgr = tid >> 4;
    const int mm0 = mg * 4, j0 = jgr * 4;
    float lmax = -1e30f;
    for (int mt = 0; mt < 5; ++mt) {
        int m0 = mt * 64;
        __syncthreads();
        #pragma unroll
        for (int r = 0; r < 4; ++r) {
            int id = tid + r * 256;
            int mm = id >> 4, kq = (id & 15) * 4;
            int m = m0 + mm;
            float4 v = make_float4(0.f, 0.f, 0.f, 0.f);
            if (m < MFEAT) v = *(const float4*)(pj + (size_t)m * DHEAD + kq);
            projT[kq+0][mm] = v.x; projT[kq+1][mm] = v.y; projT[kq+2][mm] = v.z; projT[kq+3][mm] = v.w;
        }
        __syncthreads();
        float dot[4][4] = {};
        #pragma unroll 4
        for (int k0 = 0; k0 < 64; k0 += 4) {
            float4 p0 = *(const float4*)&projT[k0+0][mm0];
            float4 p1 = *(const float4*)&projT[k0+1][mm0];
            float4 p2 = *(const float4*)&projT[k0+2][mm0];
            float4 p3 = *(const float4*)&projT[k0+3][mm0];
            #pragma unroll
            for (int jj = 0; jj < 4; ++jj) {
                float4 kv = *(const float4*)&k_lds[j0 + jj][k0];
                dot[jj][0] += kv.x*p0.x + kv.y*p1.x + kv.z*p2.x + kv.w*p3.x;
                dot[jj][1] += kv.x*p0.y + kv.y*p1.y + kv.z*p2.y + kv.w*p3.y;
                dot[jj][2] += kv.x*p0.z + kv.y*p1.z + kv.z*p2.z + kv.w*p3.z;
                dot[jj][3] += kv.x*p0.w + kv.y*p1.w + kv.z*p2.w + kv.w*p3.w;
            }
        }
        #pragma unroll
        for (int c = 0; c < 4; ++c) {
            if (m0 + mm0 + c < MFEAT) {
                #pragma unroll
                for (int jj = 0; jj < 4; ++jj) lmax = fmaxf(lmax, dot[jj][c]);
            }
        }
    }
    lmax *= DN;
    red[tid] = lmax;
    __syncthreads();
    for (int s = 128; s; s >>= 1) {
        if (tid < s) red[tid] = fmaxf(red[tid], red[tid + s]);
        __syncthreads();
    }
    if (tid == 0) atomicMax(kmaxu + bh, f2ord(red[0]));
}

// ---------------- context accumulate: ctx[m,d]=sum_n kp*v, ksum[m]=sum_n kp ----------------
__global__ __launch_bounds__(256) void ctx_kernel(
    const float* __restrict__ Km, const float* __restrict__ Vm,
    const float* __restrict__ pj, const unsigned* __restrict__ kmaxu,
    float* __restrict__ ctx_part, float* __restrict__ ksum_part)
{
    __shared__ __align__(16) float projT[64][68];
    __shared__ __align__(16) float k_lds[32][68];
    __shared__ __align__(16) float v_lds[32][68];
    __shared__ __align__(16) float kp_lds[32][68];
    __shared__ float diag[32];
    const int tid = threadIdx.x;
    const int bh = blockIdx.x, mt = blockIdx.y, seg = blockIdx.z;
    const int b = bh >> 3, hh = bh & 7;
    const int m0 = mt * 64;
    const float kmx = ord2f(kmaxu[bh]);
    #pragma unroll
    for (int r = 0; r < 4; ++r) {
        int id = tid + r * 256;
        int mm = id >> 4, kq = (id & 15) * 4;
        int m = m0 + mm;
        float4 v = make_float4(0.f, 0.f, 0.f, 0.f);
        if (m < MFEAT) v = *(const float4*)(pj + (size_t)m * DHEAD + kq);
        projT[kq+0][mm] = v.x; projT[kq+1][mm] = v.y; projT[kq+2][mm] = v.z; projT[kq+3][mm] = v.w;
    }
    const int mg = tid & 15, jp = tid >> 4;
    const int mm0 = mg * 4, j0s = jp * 2;
    const int tdd = tid & 15, tmm = tid >> 4;
    float acc[4][4] = {};
    float ksacc = 0.f;
    const size_t rowbase = ((size_t)b * NTOK) * CINNER + hh * DHEAD;
    for (int nc = 0; nc < 32; ++nc) {
        const int n0 = seg * 1024 + nc * 32;
        __syncthreads();
        #pragma unroll
        for (int r = 0; r < 2; ++r) {
            int id = tid + r * 256;
            int j = id >> 4, kq = (id & 15) * 4;
            size_t base = rowbase + (size_t)(n0 + j) * CINNER + kq;
            *(float4*)&k_lds[j][kq] = *(const float4*)(Km + base);
            *(float4*)&v_lds[j][kq] = *(const float4*)(Vm + base);
        }
        __syncthreads();
        if (tid < 32) {
            float s = 0.f;
            #pragma unroll
            for (int k = 0; k < 64; ++k) { float xv = k_lds[tid][k]; s += xv * xv; }
            diag[tid] = HALF_DN2 * s;
        }
        __syncthreads();
        float dot[2][4] = {};
        #pragma unroll 4
        for (int k0 = 0; k0 < 64; k0 += 4) {
            float4 p0 = *(const float4*)&projT[k0+0][mm0];
            float4 p1 = *(const float4*)&projT[k0+1][mm0];
            float4 p2 = *(const float4*)&projT[k0+2][mm0];
            float4 p3 = *(const float4*)&projT[k0+3][mm0];
            #pragma unroll
            for (int jj = 0; jj < 2; ++jj) {
                float4 kv = *(const float4*)&k_lds[j0s + jj][k0];
                dot[jj][0] += kv.x*p0.x + kv.y*p1.x + kv.z*p2.x + kv.w*p3.x;
                dot[jj][1] += kv.x*p0.y + kv.y*p1.y + kv.z*p2.y + kv.w*p3.y;
                dot[jj][2] += kv.x*p0.z + kv.y*p1.z + kv.z*p2.z + kv.w*p3.z;
                dot[jj][3] += kv.x*p0.w + kv.y*p1.w + kv.z*p2.w + kv.w*p3.w;
            }
        }
        #pragma unroll
        for (int jj = 0; jj < 2; ++jj) {
            float4 kpv;
            #pragma unroll
            for (int c = 0; c < 4; ++c) {
                float val = 0.f;
                if (m0 + mm0 + c < MFEAT)
                    val = RATIO * (expf(DN * dot[jj][c] - diag[j0s + jj] - kmx) + 1e-4f);
                (&kpv.x)[c] = val;
            }
            *(float4*)&kp_lds[j0s + jj][mm0] = kpv;
        }
        __syncthreads();
        #pragma unroll 4
        for (int j = 0; j < 32; ++j) {
            float4 kv = *(const float4*)&kp_lds[j][tmm * 4];
            float4 vv = *(const float4*)&v_lds[j][tdd * 4];
            acc[0][0] += kv.x*vv.x; acc[0][1] += kv.x*vv.y; acc[0][2] += kv.x*vv.z; acc[0][3] += kv.x*vv.w;
            acc[1][0] += kv.y*vv.x; acc[1][1] += kv.y*vv.y; acc[1][2] += kv.y*vv.z; acc[1][3] += kv.y*vv.w;
            acc[2][0] += kv.z*vv.x; acc[2][1] += kv.z*vv.y; acc[2][2] += kv.z*vv.z; acc[2][3] += kv.z*vv.w;
            acc[3][0] += kv.w*vv.x; acc[3][1] += kv.w*vv.y; acc[3][2] += kv.w*vv.z; acc[3][3] += kv.w*vv.w;
        }
        if (tid < 64) {
            #pragma unroll 8
            for (int j = 0; j < 32; ++j) ksacc += kp_lds[j][tid];
        }
    }
    const size_t obase = (size_t)(seg * 32 + bh) * MPAD + m0;
    #pragma unroll
    for (int i = 0; i < 4; ++i) {
        float4 o = make_float4(acc[i][0], acc[i][1], acc[i][2], acc[i][3]);
        *(float4*)(ctx_part + (obase + tmm * 4 + i) * 64 + tdd * 4) = o;
    }
    if (tid < 64) ksum_part[obase + tid] = ksacc;
}

// ---------------- reduce ctx partials over 4 segments ----------------
__global__ __launch_bounds__(256) void ctx_reduce(const float* __restrict__ part,
    float* __restrict__ ctxo, const float* __restrict__ kspart, float* __restrict__ kso)
{
    int idx = blockIdx.x * 256 + threadIdx.x;
    const int CTXN = 32 * MPAD * 64;
    if (idx < CTXN) {
        float s = 0.f;
        #pragma unroll
        for (int sg = 0; sg < 4; ++sg) s += part[(size_t)sg * CTXN + idx];
        ctxo[idx] = s;
    } else {
        int k = idx - CTXN;
        if (k < 32 * MPAD) {
            float s = 0.f;
            #pragma unroll
            for (int sg = 0; sg < 4; ++sg) s += kspart[(size_t)sg * 32 * MPAD + k];
            kso[k] = s;
        }
    }
}

// ---------------- q-side fused: features + qp@ctx / denom ----------------
__global__ __launch_bounds__(256) void qside_kernel(const float* __restrict__ Qm,
    const float* __restrict__ pj, const float* __restrict__ ctx,
    const float* __restrict__ ksum, float* __restrict__ attn_out)
{
    __shared__ __align__(16) float q_lds[16][68];
    __shared__ __align__(16) float buf[64][68];
    __shared__ __align__(16) float dd[16][MP2];
    __shared__ float ksum_lds[MP2];
    __shared__ float red[256];
    __shared__ float diag[16], rmax[16], denomv[16];
    const int tid = threadIdx.x;
    const int nt = blockIdx.x, bh = blockIdx.y;
    const int b = bh >> 3, hh = bh & 7;
    const int n0 = nt * 16;
    {
        int t = tid >> 4, kq = (tid & 15) * 4;
        *(float4*)&q_lds[t][kq] =
            *(const float4*)(Qm + ((size_t)(b * NTOK + n0 + t)) * CINNER + hh * DHEAD + kq);
    }
    for (int i = tid; i < MP2; i += 256) ksum_lds[i] = ksum[(size_t)bh * MPAD + i];
    __syncthreads();
    {
        int t = tid >> 4, j = tid & 15;
        float s = 0.f;
        #pragma unroll
        for (int i = 0; i < 4; ++i) { float v = q_lds[t][j * 4 + i]; s += v * v; }
        red[tid] = s;
    }
    __syncthreads();
    if (tid < 16) {
        float s = 0.f;
        #pragma unroll
        for (int j = 0; j < 16; ++j) s += red[tid * 16 + j];
        diag[tid] = HALF_DN2 * s;
    }
    const int mg = tid & 15, tq = tid >> 4;
    for (int mt = 0; mt < 5; ++mt) {
        int m0 = mt * 64;
        __syncthreads();
        #pragma unroll
        for (int r = 0; r < 4; ++r) {
            int id = tid + r * 256;
            int mm = id >> 4, kq = (id & 15) * 4;
            int m = m0 + mm;
            float4 v = make_float4(0.f, 0.f, 0.f, 0.f);
            if (m < MFEAT) v = *(const float4*)(pj + (size_t)m * DHEAD + kq);
            buf[kq+0][mm] = v.x; buf[kq+1][mm] = v.y; buf[kq+2][mm] = v.z; buf[kq+3][mm] = v.w;
        }
        __syncthreads();
        float dot[4] = {};
        #pragma unroll 4
        for (int k0 = 0; k0 < 64; k0 += 4) {
            float4 q4 = *(const float4*)&q_lds[tq][k0];
            float4 p0 = *(const float4*)&buf[k0+0][mg * 4];
            float4 p1 = *(const float4*)&buf[k0+1][mg * 4];
            float4 p2 = *(const float4*)&buf[k0+2][mg * 4];
            float4 p3 = *(const float4*)&buf[k0+3][mg * 4];
            dot[0] += q4.x*p0.x + q4.y*p1.x + q4.z*p2.x + q4.w*p3.x;
            dot[1] += q4.x*p0.y + q4.y*p1.y + q4.z*p2.y + q4.w*p3.y;
            dot[2] += q4.x*p0.z + q4.y*p1.z + q4.z*p2.z + q4.w*p3.z;
            dot[3] += q4.x*p0.w + q4.y*p1.w + q4.z*p2.w + q4.w*p3.w;
        }
        int m = m0 + mg * 4;
        if (m < MP2) {
            float4 o = make_float4(dot[0]*DN, dot[1]*DN, dot[2]*DN, dot[3]*DN);
            *(float4*)&dd[tq][m] = o;
        }
    }
    __syncthreads();
    {
        int t = tid >> 4, lane = tid & 15;
        float pm = -1e30f;
        for (int m = lane; m < MFEAT; m += 16) pm = fmaxf(pm, dd[t][m]);
        red[tid] = pm;
    }
    __syncthreads();
    if (tid < 16) {
        float pm = -1e30f;
        #pragma unroll
        for (int j = 0; j < 16; ++j) pm = fmaxf(pm, red[tid * 16 + j]);
        rmax[tid] = pm;
    }
    __syncthreads();
    for (int r = 0; r < 17; ++r) {
        int id = tid + r * 256;       // exactly covers 16*272
        int t = id / MP2, m = id - t * MP2;
        float v = 0.f;
        if (m < MFEAT) v = RATIO * (expf(dd[t][m] - diag[t] - rmax[t]) + 1e-4f);
        dd[t][m] = v;
    }
    __syncthreads();
    {
        int t = tid >> 4, lane = tid & 15;
        float s = 0.f;
        for (int m = lane; m < MP2; m += 16) s += dd[t][m] * ksum_lds[m];
        red[tid] = s;
    }
    __syncthreads();
    if (tid < 16) {
        float s = 0.f;
        #pragma unroll
        for (int j = 0; j < 16; ++j) s += red[tid * 16 + j];
        denomv[tid] = s;
    }
    const int t7 = tid >> 4, dg = tid & 15;
    float4 acc = make_float4(0.f, 0.f, 0.f, 0.f);
    for (int mt = 0; mt < 5; ++mt) {
        __syncthreads();
        #pragma unroll
        for (int r = 0; r < 4; ++r) {
            int id = tid + r * 256;
            int mm = id >> 4, kq = (id & 15) * 4;
            *(float4*)&buf[mm][kq] =
                *(const float4*)(ctx + ((size_t)bh * MPAD + mt * 64 + mm) * 64 + kq);
        }
        __syncthreads();
        int mmax = (mt == 4) ? 16 : 64;
        #pragma unroll 8
        for (int mm = 0; mm < mmax; ++mm) {
            float qv = dd[t7][mt * 64 + mm];
            float4 cv = *(const float4*)&buf[mm][dg * 4];
            acc.x += qv * cv.x; acc.y += qv * cv.y; acc.z += qv * cv.z; acc.w += qv * cv.w;
        }
    }
    float inv = 1.0f / denomv[t7];
    acc.x *= inv; acc.y *= inv; acc.z *= inv; acc.w *= inv;
    *(float4*)(attn_out + ((size_t)(b * NTOK + n0 + t7)) * CINNER + hh * DHEAD + dg * 4) = acc;
}

// ---------------- group-norm ----------------
__global__ __launch_bounds__(256) void gn_part_kernel(const float* __restrict__ y,
    float2* __restrict__ part)
{
    __shared__ float s_s[256], s_q[256];
    const int tid = threadIdx.x;
    const int sp = blockIdx.x, g = blockIdx.y, b = blockIdx.z;
    int p = sp * 256 + tid;
    const float* base = y + ((size_t)(b * NTOK + p)) * CDIM + g * 24;
    float s = 0.f, q = 0.f;
    #pragma unroll
    for (int i = 0; i < 24; ++i) { float v = base[i]; s += v; q += v * v; }
    s_s[tid] = s; s_q[tid] = q;
    __syncthreads();
    for (int st = 128; st; st >>= 1) {
        if (tid < st) { s_s[tid] += s_s[tid + st]; s_q[tid] += s_q[tid + st]; }
        __syncthreads();
    }
    if (tid == 0) part[(b * 8 + g) * 16 + sp] = make_float2(s_s[0], s_q[0]);
}

__global__ void gn_stat_kernel(const float2* __restrict__ part, float2* __restrict__ stat)
{
    int bg = threadIdx.x;
    if (bg < 32) {
        float s = 0.f, q = 0.f;
        for (int i = 0; i < 16; ++i) { float2 v = part[bg * 16 + i]; s += v.x; q += v.y; }
        float mean = s * (1.0f / 98304.0f);
        float var = q * (1.0f / 98304.0f) - mean * mean;
        stat[bg] = make_float2(mean, rsqrtf(var + 1e-5f));
    }
}

__global__ __launch_bounds__(256) void gn_apply_kernel(const float* __restrict__ y,
    const float2* __restrict__ stat, const float* __restrict__ gg,
    const float* __restrict__ gb, float* __restrict__ out)
{
    __shared__ float tile[64][65];
    const int tid = threadIdx.x;
    const int pt = blockIdx.x, ct = blockIdx.y, b = blockIdx.z;
    const int p0 = pt * 64, c0 = ct * 64;
    #pragma unroll
    for (int r = 0; r < 4; ++r) {
        int id = tid + r * 256;
        int pr = id >> 4, kq = (id & 15) * 4;
        float4 v = *(const float4*)(y + ((size_t)(b * NTOK + p0 + pr)) * CDIM + c0 + kq);
        tile[pr][kq+0] = v.x; tile[pr][kq+1] = v.y; tile[pr][kq+2] = v.z; tile[pr][kq+3] = v.w;
    }
    __syncthreads();
    const int cc = tid >> 6, pp = tid & 63;
    #pragma unroll
    for (int i = 0; i < 16; ++i) {
        int c = c0 + cc * 16 + i;
        int g = c / 24;
        float2 st = stat[b * 8 + g];
        float v = tile[pp][cc * 16 + i];
        out[((size_t)(b * CDIM + c)) * NTOK + p0 + pp] = (v - st.x) * st.y * gg[c] + gb[c];
    }
}

// ---------------- grouped circular conv + gelu (NCHW) ----------------
template<int KS, int CIN, int COUT>
__global__ __launch_bounds__(256) void circ_conv_gelu(const float* __restrict__ in,
    const float* __restrict__ w, const float* __restrict__ bias,
    float* __restrict__ out, int do_gelu)
{
    constexpr int P = KS / 2;
    constexpr int ICG = CIN / 8;
    constexpr int OCG = COUT / 8;
    constexpr int T = 16 + 2 * P;
    __shared__ float in_t[T][T + 1];
    __shared__ float w_lds[ICG * KS * KS];
    const int tid = threadIdx.x;
    const int oc = blockIdx.y, b = blockIdx.z;
    const int tx0 = (blockIdx.x & 3) * 16, ty0 = (blockIdx.x >> 2) * 16;
    const int g = oc / OCG;
    const int lx = tid & 15, ly = tid >> 4;
    for (int id = tid; id < ICG * KS * KS; id += 256) w_lds[id] = w[(size_t)oc * (ICG * KS * KS) + id];
    float acc = 0.f;
    for (int ic = 0; ic < ICG; ++ic) {
        __syncthreads();
        const float* ip = in + ((size_t)(b * CIN + g * ICG + ic)) * NTOK;
        for (int id = tid; id < T * T; id += 256) {
            int tyy = id / T, txx = id - tyy * T;
            int gy = (ty0 + tyy - P) & 63, gx = (tx0 + txx - P) & 63;
            in_t[tyy][txx] = ip[gy * 64 + gx];
        }
        __syncthreads();
        const float* wp = &w_lds[ic * KS * KS];
        #pragma unroll
        for (int ky = 0; ky < KS; ++ky) {
            #pragma unroll
            for (int kx = 0; kx < KS; ++kx)
                acc += in_t[ly + ky][lx + kx] * wp[ky * KS + kx];
        }
    }
    acc += bias[oc];
    if (do_gelu) acc = gelu_f(acc);
    out[((size_t)(b * COUT + oc) * 64 + ty0 + ly) * 64 + tx0 + lx] = acc;
}

// ---------------- final 1x1 conv -> output layout [b,1,y,x,c] ----------------
__global__ __launch_bounds__(256) void conv1_kernel(const float* __restrict__ in,
    const float* __restrict__ w, const float* __restrict__ bias, float* __restrict__ out)
{
    int idx = blockIdx.x * 256 + threadIdx.x;  // 16384 pixels
    int b = idx >> 12, p = idx & 4095;
    float a0 = bias[0], a1 = bias[1], a2 = bias[2];
    const float* ip = in + (size_t)b * 48 * NTOK + p;
    #pragma unroll 8
    for (int ic = 0; ic < 48; ++ic) {
        float v = ip[(size_t)ic * NTOK];
        a0 += v * w[ic]; a1 += v * w[48 + ic]; a2 += v * w[96 + ic];
    }
    float* op = out + (size_t)idx * 3;
    op[0] = a0; op[1] = a1; op[2] = a2;
}

// ---------------- host launch ----------------
static inline void gemm(hipStream_t s, const float* A, const float* B, const float* bias,
                        const float* resid, float* C, int M, int N, int K, int epi)
{
    dim3 g(N / 64, M / 64);
    hipLaunchKernelGGL(gemm_tn, g, dim3(256), 0, s, A, B, bias, resid, C, M, N, K, epi);
}

extern "C" void kernel_launch(void* const* d_in, const int* in_sizes, int n_in,
                              void* d_out, int out_size, void* d_ws, size_t ws_size,
                              hipStream_t stream)
{
    (void)in_sizes; (void)n_in; (void)out_size; (void)ws_size;
    const float* x        = (const float*)d_in[0];
    const float* to_in_w  = (const float*)d_in[1];
    const float* to_in_b  = (const float*)d_in[2];
    const float* pos_emb  = (const float*)d_in[3];
    const float* proj     = (const float*)d_in[4];
    const float* sn_attn_g= (const float*)d_in[5];
    const float* wq       = (const float*)d_in[6];
    const float* wk       = (const float*)d_in[7];
    const float* wv       = (const float*)d_in[8];
    const float* wo       = (const float*)d_in[9];
    const float* bo       = (const float*)d_in[10];
    const float* sn_ff_g  = (const float*)d_in[11];
    const float* w1       = (const float*)d_in[12];
    const float* b1       = (const float*)d_in[13];
    const float* w2       = (const float*)d_in[14];
    const float* b2       = (const float*)d_in[15];
    const float* expand_w = (const float*)d_in[16];
    const float* fwd_w    = (const float*)d_in[17];
    const float* dec_lin_w= (const float*)d_in[18];
    const float* dec_lin_b= (const float*)d_in[19];
    const float* gn_g     = (const float*)d_in[20];
    const float* gn_b     = (const float*)d_in[21];
    const float* c9_w     = (const float*)d_in[22];
    const float* c9_b     = (const float*)d_in[23];
    const float* c7_w     = (const float*)d_in[24];
    const float* c7_b     = (const float*)d_in[25];
    const float* c5_w     = (const float*)d_in[26];
    const float* c5_b     = (const float*)d_in[27];
    const float* c1_w     = (const float*)d_in[28];
    const float* c1_b     = (const float*)d_in[29];
    float* out = (float*)d_out;

    float* ws = (float*)d_ws;
    float* h   = ws + OFF_H;
    float* hn  = ws + OFF_HN;
    float* q   = ws + OFF_Q;
    float* k   = ws + OFF_K;          // also attn_inner
    float* v   = ws + OFF_V;
    float* big = ws + OFF_BIG;        // ff1 / decoder NCHW bufs
    float* ctxp = ws + OFF_CTXP;
    float* ksp  = ws + OFF_KSP;
    float* ctx  = ws + OFF_CTX;
    float* ksum = ws + OFF_KSUM;
    unsigned* kmaxu = (unsigned*)(ws + OFF_KMAX);
    float2* gnp = (float2*)(ws + OFF_GNP);
    float2* gns = (float2*)(ws + OFF_GNS);

    // prologue
    hipLaunchKernelGGL(input_embed, dim3(BNTOK * CDIM / 256), dim3(256), 0, stream,
                       x, to_in_w, to_in_b, pos_emb, h);
    hipLaunchKernelGGL(kmax_init, dim3(1), dim3(256), 0, stream, kmaxu);

    for (int l = 0; l < NDEPTH; ++l) {
        const float* wq_l = wq + (size_t)l * CINNER * CDIM;
        const float* wk_l = wk + (size_t)l * CINNER * CDIM;
        const float* wv_l = wv + (size_t)l * CINNER * CDIM;
        const float* wo_l = wo + (size_t)l * CDIM * CINNER;
        const float* bo_l = bo + (size_t)l * CDIM;
        const float* w1_l = w1 + (size_t)l * CFF * CDIM;
        const float* b1_l = b1 + (size_t)l * CFF;
        const float* w2_l = w2 + (size_t)l * CDIM * CFF;
        const float* b2_l = b2 + (size_t)l * CDIM;
        const float* pj_l = proj + (size_t)l * MFEAT * DHEAD;
        unsigned* kmax_l = kmaxu + l * 32;

        // attn
        hipLaunchKernelGGL(scalenorm_kernel, dim3(BNTOK / 4), dim3(256), 0, stream, h, hn, sn_attn_g, l);
        gemm(stream, hn, wq_l, nullptr, nullptr, q, BNTOK, CINNER, CDIM, 0);
        gemm(stream, hn, wk_l, nullptr, nullptr, k, BNTOK, CINNER, CDIM, 0);
        gemm(stream, hn, wv_l, nullptr, nullptr, v, BNTOK, CINNER, CDIM, 0);
        hipLaunchKernelGGL(kmax_kernel, dim3(64, 32), dim3(256), 0, stream, k, pj_l, kmax_l);
        hipLaunchKernelGGL(ctx_kernel, dim3(32, 5, 4), dim3(256), 0, stream, k, v, pj_l, kmax_l, ctxp, ksp);
        hipLaunchKernelGGL(ctx_reduce, dim3((32 * MPAD * 64 + 32 * MPAD) / 256), dim3(256), 0, stream,
                           ctxp, ctx, ksp, ksum);
        hipLaunchKernelGGL(qside_kernel, dim3(256, 32), dim3(256), 0, stream, q, pj_l, ctx, ksum, k);
        gemm(stream, k, wo_l, bo_l, h, h, BNTOK, CDIM, CINNER, 1 | 4);

        // ff
        hipLaunchKernelGGL(scalenorm_kernel, dim3(BNTOK / 4), dim3(256), 0, stream, h, hn, sn_ff_g, l);
        gemm(stream, hn, w1_l, b1_l, nullptr, big, BNTOK, CFF, CDIM, 1 | 2);
        gemm(stream, big, w2_l, b2_l, h, h, BNTOK, CDIM, CFF, 1 | 4);
    }

    // decoder linears: h -> hn (expand), hn -> h (fwd), h -> hn (dec_lin + bias)
    gemm(stream, h, expand_w, nullptr, nullptr, hn, BNTOK, CDIM, CDIM, 0);
    gemm(stream, hn, fwd_w, nullptr, nullptr, h, BNTOK, CDIM, CDIM, 0);
    gemm(stream, h, dec_lin_w, dec_lin_b, nullptr, hn, BNTOK, CDIM, CDIM, 1);

    // group norm (NHWC stats) + apply/transpose to NCHW
    float* y0 = big;                    // [4,192,64,64]
    float* y1 = big + 3145728;          // [4,192,64,64]
    float* y2 = big + 6291456;          // [4,96,64,64]
    float* y3 = big + 7864320;          // [4,48,64,64]
    hipLaunchKernelGGL(gn_part_kernel, dim3(16, 8, 4), dim3(256), 0, stream, hn, gnp);
    hipLaunchKernelGGL(gn_stat_kernel, dim3(1), dim3(32), 0, stream, gnp, gns);
    hipLaunchKernelGGL(gn_apply_kernel, dim3(64, 3, 4), dim3(256), 0, stream, hn, gns, gn_g, gn_b, y0);

    // convs
    hipLaunchKernelGGL((circ_conv_gelu<9, 192, 192>), dim3(16, 192, 4), dim3(256), 0, stream,
                       y0, c9_w, c9_b, y1, 1);
    hipLaunchKernelGGL((circ_conv_gelu<7, 192, 96>), dim3(16, 96, 4), dim3(256), 0, stream,
                       y1, c7_w, c7_b, y2, 1);
    hipLaunchKernelGGL((circ_conv_gelu<5, 96, 48>), dim3(16, 48, 4), dim3(256), 0, stream,
                       y2, c5_w, c5_b, y3, 1);
    hipLaunchKernelGGL(conv1_kernel, dim3(BNTOK / 256), dim3(256), 0, stream, y3, c1_w, c1_b, out);
}

// Round 2
// 7372.658 us; speedup vs baseline: 1.0280x; 1.0280x over previous
//
#include <hip/hip_runtime.h>
#include <cmath>

// ---------------- constants ----------------
#define NB      4
#define NTOK    4096          // tokens per batch
#define BNTOK   16384
#define CDIM    192
#define CINNER  512
#define NHEADS  8
#define DHEAD   64
#define CFF     768
#define MFEAT   266
#define MPAD    320           // 5*64
#define MP2     272           // 17*16
#define NDEPTH  6

#define DN      0.35355339059327373f   // 64^-0.25
#define RATIO   0.06131393394849658f   // 266^-0.5
#define HALF_DN2 0.0625f               // 0.5 * dn^2

// workspace offsets (floats)
#define OFF_H    0ull
#define OFF_HN   3145728ull
#define OFF_Q    6291456ull
#define OFF_K    14680064ull      /* also attn_inner */
#define OFF_V    23068672ull
#define OFF_BIG  31457280ull      /* ff1 (12.58M floats) / decoder NCHW bufs */
#define OFF_CTXP 44040192ull
#define OFF_KSP  46661632ull
#define OFF_CTX  46702592ull
#define OFF_KSUM 47357952ull
#define OFF_KMAX 47368192ull      /* 192 uints */
#define OFF_GNP  47368448ull      /* 512 float2 */
#define OFF_GNS  47369472ull      /* 32 float2 */

__device__ __forceinline__ float gelu_f(float x) {
    return 0.5f * x * (1.0f + erff(x * 0.7071067811865476f));
}
__device__ __forceinline__ unsigned f2ord(float f) {
    int i = __float_as_int(f);
    return (i >= 0) ? ((unsigned)i | 0x80000000u) : (unsigned)(~i);
}
__device__ __forceinline__ float ord2f(unsigned u) {
    int i = (u & 0x80000000u) ? (int)(u & 0x7fffffffu) : ~(int)u;
    return __int_as_float(i);
}

// ---------------- input embed: h = x@W.T + b + pos ----------------
__global__ __launch_bounds__(256) void input_embed(const float* __restrict__ x,
    const float* __restrict__ w, const float* __restrict__ bvec,
    const float* __restrict__ pos, float* __restrict__ h)
{
    int idx = blockIdx.x * 256 + threadIdx.x;   // < 16384*192
    int row = idx / CDIM, c = idx - row * CDIM;
    int p = row & (NTOK - 1);
    const float* xr = x + (size_t)row * 3;
    h[idx] = xr[0]*w[c*3+0] + xr[1]*w[c*3+1] + xr[2]*w[c*3+2] + bvec[c] + pos[(size_t)p*CDIM + c];
}

// ---------------- scalenorm ----------------
__global__ __launch_bounds__(256) void scalenorm_kernel(const float* __restrict__ in,
    float* __restrict__ out, const float* __restrict__ gptr, int gidx)
{
    int wv = threadIdx.x >> 6, lane = threadIdx.x & 63;
    int row = blockIdx.x * 4 + wv;
    const float* p = in + (size_t)row * CDIM;
    float x0 = p[lane], x1 = p[lane + 64], x2 = p[lane + 128];
    float ss = x0*x0 + x1*x1 + x2*x2;
    #pragma unroll
    for (int off = 32; off; off >>= 1) ss += __shfl_xor(ss, off);
    float g = gptr[gidx];
    float n = sqrtf(ss * (1.0f / 192.0f));
    float s = g / fmaxf(n, 1e-5f);
    float* o = out + (size_t)row * CDIM;
    o[lane] = x0 * s; o[lane + 64] = x1 * s; o[lane + 128] = x2 * s;
}

// ---------------- GEMM: C[M,N] = A[M,K] @ B[N,K]^T (+bias,+gelu,+resid) ----------------
// 128x128 block tile, 8x8 microtile, split-B-column fragments (tx*4 and 64+tx*4)
// epi: 1=bias, 2=gelu, 4=resid add.  Requires M%128==0, K%32==0; N masked.
__global__ __launch_bounds__(256) void gemm_tn(const float* __restrict__ A,
    const float* __restrict__ Bw, const float* __restrict__ bias,
    const float* __restrict__ resid, float* __restrict__ C,
    int M, int N, int K, int epi)
{
    __shared__ __align__(16) float a_lds[32][132];
    __shared__ __align__(16) float b_lds[32][132];
    const int tid = threadIdx.x;
    const int tx = tid & 15, ty = tid >> 4;
    const int n0 = blockIdx.x * 128, m0 = blockIdx.y * 128;
    float acc[8][8] = {};
    for (int kc = 0; kc < K; kc += 32) {
        #pragma unroll
        for (int r = 0; r < 4; ++r) {
            int id = tid + r * 256;
            int row = id >> 3, kq = (id & 7) * 4;
            float4 av = *(const float4*)(A + (size_t)(m0 + row) * K + kc + kq);
            a_lds[kq+0][row] = av.x; a_lds[kq+1][row] = av.y;
            a_lds[kq+2][row] = av.z; a_lds[kq+3][row] = av.w;
            float4 bv = make_float4(0.f, 0.f, 0.f, 0.f);
            if (n0 + row < N)
                bv = *(const float4*)(Bw + (size_t)(n0 + row) * K + kc + kq);
            b_lds[kq+0][row] = bv.x; b_lds[kq+1][row] = bv.y;
            b_lds[kq+2][row] = bv.z; b_lds[kq+3][row] = bv.w;
        }
        __syncthreads();
        #pragma unroll 8
        for (int kk = 0; kk < 32; ++kk) {
            float4 a0 = *(const float4*)&a_lds[kk][ty * 8];
            float4 a1 = *(const float4*)&a_lds[kk][ty * 8 + 4];
            float4 b0 = *(const float4*)&b_lds[kk][tx * 4];
            float4 b1 = *(const float4*)&b_lds[kk][64 + tx * 4];
            float av[8] = {a0.x, a0.y, a0.z, a0.w, a1.x, a1.y, a1.z, a1.w};
            float bv[8] = {b0.x, b0.y, b0.z, b0.w, b1.x, b1.y, b1.z, b1.w};
            #pragma unroll
            for (int i = 0; i < 8; ++i)
                #pragma unroll
                for (int j = 0; j < 8; ++j)
                    acc[i][j] += av[i] * bv[j];
        }
        __syncthreads();
    }
    const int c0 = n0 + tx * 4, c1 = n0 + 64 + tx * 4;
    const bool v1 = (c1 < N);
    float4 bb0 = make_float4(0.f,0.f,0.f,0.f), bb1 = bb0;
    if (epi & 1) {
        bb0 = *(const float4*)(bias + c0);
        if (v1) bb1 = *(const float4*)(bias + c1);
    }
    #pragma unroll
    for (int i = 0; i < 8; ++i) {
        size_t ro = (size_t)(m0 + ty * 8 + i) * N;
        float4 ca = make_float4(acc[i][0]+bb0.x, acc[i][1]+bb0.y, acc[i][2]+bb0.z, acc[i][3]+bb0.w);
        if (epi & 2) { ca.x = gelu_f(ca.x); ca.y = gelu_f(ca.y); ca.z = gelu_f(ca.z); ca.w = gelu_f(ca.w); }
        if (epi & 4) {
            float4 rv = *(const float4*)(resid + ro + c0);
            ca.x += rv.x; ca.y += rv.y; ca.z += rv.z; ca.w += rv.w;
        }
        *(float4*)(C + ro + c0) = ca;
        if (v1) {
            float4 cb = make_float4(acc[i][4]+bb1.x, acc[i][5]+bb1.y, acc[i][6]+bb1.z, acc[i][7]+bb1.w);
            if (epi & 2) { cb.x = gelu_f(cb.x); cb.y = gelu_f(cb.y); cb.z = gelu_f(cb.z); cb.w = gelu_f(cb.w); }
            if (epi & 4) {
                float4 rv = *(const float4*)(resid + ro + c1);
                cb.x += rv.x; cb.y += rv.y; cb.z += rv.z; cb.w += rv.w;
            }
            *(float4*)(C + ro + c1) = cb;
        }
    }
}

// ---------------- kmax init ----------------
__global__ void kmax_init(unsigned* kmaxu) {
    if (threadIdx.x < NDEPTH * 32) kmaxu[threadIdx.x] = 0u;
}

// ---------------- k-feature global max per (b,h) ----------------
__global__ __launch_bounds__(256) void kmax_kernel(const float* __restrict__ Km,
    const float* __restrict__ pj, unsigned* __restrict__ kmaxu)
{
    __shared__ __align__(16) float projT[64][68];
    __shared__ __align__(16) float k_lds[64][68];
    __shared__ float red[256];
    const int tid = threadIdx.x;
    const int nt = blockIdx.x, bh = blockIdx.y;
    const int b = bh >> 3, hh = bh & 7;
    const int n0 = nt * 64;
    const size_t kbase = ((size_t)b * NTOK + n0) * CINNER + hh * DHEAD;
    #pragma unroll
    for (int r = 0; r < 4; ++r) {
        int id = tid + r * 256;
        int row = id >> 4, kq = (id & 15) * 4;
        *(float4*)&k_lds[row][kq] = *(const float4*)(Km + kbase + (size_t)row * CINNER + kq);
    }
    const int mg = tid & 15, jgr = tid >> 4;
    const int mm0 = mg * 4, j0 = jgr * 4;
    float lmax = -1e30f;
    for (int mt = 0; mt < 5; ++mt) {
        int m0 = mt * 64;
        __syncthreads();
        #pragma unroll
        for (int r = 0; r < 4; ++r) {
            int id = tid + r * 256;
            int mm = id >> 4, kq = (id & 15) * 4;
            int m = m0 + mm;
            float4 v = make_float4(0.f, 0.f, 0.f, 0.f);
            if (m < MFEAT) v = *(const float4*)(pj + (size_t)m * DHEAD + kq);
            projT[kq+0][mm] = v.x; projT[kq+1][mm] = v.y; projT[kq+2][mm] = v.z; projT[kq+3][mm] = v.w;
        }
        __syncthreads();
        float dot[4][4] = {};
        #pragma unroll 4
        for (int k0 = 0; k0 < 64; k0 += 4) {
            float4 p0 = *(const float4*)&projT[k0+0][mm0];
            float4 p1 = *(const float4*)&projT[k0+1][mm0];
            float4 p2 = *(const float4*)&projT[k0+2][mm0];
            float4 p3 = *(const float4*)&projT[k0+3][mm0];
            #pragma unroll
            for (int jj = 0; jj < 4; ++jj) {
                float4 kv = *(const float4*)&k_lds[j0 + jj][k0];
                dot[jj][0] += kv.x*p0.x + kv.y*p1.x + kv.z*p2.x + kv.w*p3.x;
                dot[jj][1] += kv.x*p0.y + kv.y*p1.y + kv.z*p2.y + kv.w*p3.y;
                dot[jj][2] += kv.x*p0.z + kv.y*p1.z + kv.z*p2.z + kv.w*p3.z;
                dot[jj][3] += kv.x*p0.w + kv.y*p1.w + kv.z*p2.w + kv.w*p3.w;
            }
        }
        #pragma unroll
        for (int c = 0; c < 4; ++c) {
            if (m0 + mm0 + c < MFEAT) {
                #pragma unroll
                for (int jj = 0; jj < 4; ++jj) lmax = fmaxf(lmax, dot[jj][c]);
            }
        }
    }
    lmax *= DN;
    red[tid] = lmax;
    __syncthreads();
    for (int s = 128; s; s >>= 1) {
        if (tid < s) red[tid] = fmaxf(red[tid], red[tid + s]);
        __syncthreads();
    }
    if (tid == 0) atomicMax(kmaxu + bh, f2ord(red[0]));
}

// ---------------- context accumulate: ctx[m,d]=sum_n kp*v, ksum[m]=sum_n kp ----------------
__global__ __launch_bounds__(256) void ctx_kernel(
    const float* __restrict__ Km, const float* __restrict__ Vm,
    const float* __restrict__ pj, const unsigned* __restrict__ kmaxu,
    float* __restrict__ ctx_part, float* __restrict__ ksum_part)
{
    __shared__ __align__(16) float projT[64][68];
    __shared__ __align__(16) float k_lds[32][68];
    __shared__ __align__(16) float v_lds[32][68];
    __shared__ __align__(16) float kp_lds[32][68];
    __shared__ float diag[32];
    const int tid = threadIdx.x;
    const int bh = blockIdx.x, mt = blockIdx.y, seg = blockIdx.z;
    const int b = bh >> 3, hh = bh & 7;
    const int m0 = mt * 64;
    const float kmx = ord2f(kmaxu[bh]);
    #pragma unroll
    for (int r = 0; r < 4; ++r) {
        int id = tid + r * 256;
        int mm = id >> 4, kq = (id & 15) * 4;
        int m = m0 + mm;
        float4 v = make_float4(0.f, 0.f, 0.f, 0.f);
        if (m < MFEAT) v = *(const float4*)(pj + (size_t)m * DHEAD + kq);
        projT[kq+0][mm] = v.x; projT[kq+1][mm] = v.y; projT[kq+2][mm] = v.z; projT[kq+3][mm] = v.w;
    }
    const int mg = tid & 15, jp = tid >> 4;
    const int mm0 = mg * 4, j0s = jp * 2;
    const int tdd = tid & 15, tmm = tid >> 4;
    float acc[4][4] = {};
    float ksacc = 0.f;
    const size_t rowbase = ((size_t)b * NTOK) * CINNER + hh * DHEAD;
    for (int nc = 0; nc < 32; ++nc) {
        const int n0 = seg * 1024 + nc * 32;
        __syncthreads();
        #pragma unroll
        for (int r = 0; r < 2; ++r) {
            int id = tid + r * 256;
            int j = id >> 4, kq = (id & 15) * 4;
            size_t base = rowbase + (size_t)(n0 + j) * CINNER + kq;
            *(float4*)&k_lds[j][kq] = *(const float4*)(Km + base);
            *(float4*)&v_lds[j][kq] = *(const float4*)(Vm + base);
        }
        __syncthreads();
        if (tid < 32) {
            float s = 0.f;
            #pragma unroll
            for (int k = 0; k < 64; ++k) { float xv = k_lds[tid][k]; s += xv * xv; }
            diag[tid] = HALF_DN2 * s;
        }
        __syncthreads();
        float dot[2][4] = {};
        #pragma unroll 4
        for (int k0 = 0; k0 < 64; k0 += 4) {
            float4 p0 = *(const float4*)&projT[k0+0][mm0];
            float4 p1 = *(const float4*)&projT[k0+1][mm0];
            float4 p2 = *(const float4*)&projT[k0+2][mm0];
            float4 p3 = *(const float4*)&projT[k0+3][mm0];
            #pragma unroll
            for (int jj = 0; jj < 2; ++jj) {
                float4 kv = *(const float4*)&k_lds[j0s + jj][k0];
                dot[jj][0] += kv.x*p0.x + kv.y*p1.x + kv.z*p2.x + kv.w*p3.x;
                dot[jj][1] += kv.x*p0.y + kv.y*p1.y + kv.z*p2.y + kv.w*p3.y;
                dot[jj][2] += kv.x*p0.z + kv.y*p1.z + kv.z*p2.z + kv.w*p3.z;
                dot[jj][3] += kv.x*p0.w + kv.y*p1.w + kv.z*p2.w + kv.w*p3.w;
            }
        }
        #pragma unroll
        for (int jj = 0; jj < 2; ++jj) {
            float4 kpv;
            #pragma unroll
            for (int c = 0; c < 4; ++c) {
                float val = 0.f;
                if (m0 + mm0 + c < MFEAT)
                    val = RATIO * (expf(DN * dot[jj][c] - diag[j0s + jj] - kmx) + 1e-4f);
                (&kpv.x)[c] = val;
            }
            *(float4*)&kp_lds[j0s + jj][mm0] = kpv;
        }
        __syncthreads();
        #pragma unroll 4
        for (int j = 0; j < 32; ++j) {
            float4 kv = *(const float4*)&kp_lds[j][tmm * 4];
            float4 vv = *(const float4*)&v_lds[j][tdd * 4];
            acc[0][0] += kv.x*vv.x; acc[0][1] += kv.x*vv.y; acc[0][2] += kv.x*vv.z; acc[0][3] += kv.x*vv.w;
            acc[1][0] += kv.y*vv.x; acc[1][1] += kv.y*vv.y; acc[1][2] += kv.y*vv.z; acc[1][3] += kv.y*vv.w;
            acc[2][0] += kv.z*vv.x; acc[2][1] += kv.z*vv.y; acc[2][2] += kv.z*vv.z; acc[2][3] += kv.z*vv.w;
            acc[3][0] += kv.w*vv.x; acc[3][1] += kv.w*vv.y; acc[3][2] += kv.w*vv.z; acc[3][3] += kv.w*vv.w;
        }
        if (tid < 64) {
            #pragma unroll 8
            for (int j = 0; j < 32; ++j) ksacc += kp_lds[j][tid];
        }
    }
    const size_t obase = (size_t)(seg * 32 + bh) * MPAD + m0;
    #pragma unroll
    for (int i = 0; i < 4; ++i) {
        float4 o = make_float4(acc[i][0], acc[i][1], acc[i][2], acc[i][3]);
        *(float4*)(ctx_part + (obase + tmm * 4 + i) * 64 + tdd * 4) = o;
    }
    if (tid < 64) ksum_part[obase + tid] = ksacc;
}

// ---------------- reduce ctx partials over 4 segments ----------------
__global__ __launch_bounds__(256) void ctx_reduce(const float* __restrict__ part,
    float* __restrict__ ctxo, const float* __restrict__ kspart, float* __restrict__ kso)
{
    int idx = blockIdx.x * 256 + threadIdx.x;
    const int CTXN = 32 * MPAD * 64;
    if (idx < CTXN) {
        float s = 0.f;
        #pragma unroll
        for (int sg = 0; sg < 4; ++sg) s += part[(size_t)sg * CTXN + idx];
        ctxo[idx] = s;
    } else {
        int k = idx - CTXN;
        if (k < 32 * MPAD) {
            float s = 0.f;
            #pragma unroll
            for (int sg = 0; sg < 4; ++sg) s += kspart[(size_t)sg * 32 * MPAD + k];
            kso[k] = s;
        }
    }
}

// ---------------- q-side fused: features + qp@ctx / denom ----------------
__global__ __launch_bounds__(256) void qside_kernel(const float* __restrict__ Qm,
    const float* __restrict__ pj, const float* __restrict__ ctx,
    const float* __restrict__ ksum, float* __restrict__ attn_out)
{
    __shared__ __align__(16) float q_lds[16][68];
    __shared__ __align__(16) float buf[64][68];
    __shared__ __align__(16) float dd[16][MP2];
    __shared__ float ksum_lds[MP2];
    __shared__ float red[256];
    __shared__ float diag[16], rmax[16], denomv[16];
    const int tid = threadIdx.x;
    const int nt = blockIdx.x, bh = blockIdx.y;
    const int b = bh >> 3, hh = bh & 7;
    const int n0 = nt * 16;
    {
        int t = tid >> 4, kq = (tid & 15) * 4;
        *(float4*)&q_lds[t][kq] =
            *(const float4*)(Qm + ((size_t)(b * NTOK + n0 + t)) * CINNER + hh * DHEAD + kq);
    }
    for (int i = tid; i < MP2; i += 256) ksum_lds[i] = ksum[(size_t)bh * MPAD + i];
    __syncthreads();
    {
        int t = tid >> 4, j = tid & 15;
        float s = 0.f;
        #pragma unroll
        for (int i = 0; i < 4; ++i) { float v = q_lds[t][j * 4 + i]; s += v * v; }
        red[tid] = s;
    }
    __syncthreads();
    if (tid < 16) {
        float s = 0.f;
        #pragma unroll
        for (int j = 0; j < 16; ++j) s += red[tid * 16 + j];
        diag[tid] = HALF_DN2 * s;
    }
    const int mg = tid & 15, tq = tid >> 4;
    for (int mt = 0; mt < 5; ++mt) {
        int m0 = mt * 64;
        __syncthreads();
        #pragma unroll
        for (int r = 0; r < 4; ++r) {
            int id = tid + r * 256;
            int mm = id >> 4, kq = (id & 15) * 4;
            int m = m0 + mm;
            float4 v = make_float4(0.f, 0.f, 0.f, 0.f);
            if (m < MFEAT) v = *(const float4*)(pj + (size_t)m * DHEAD + kq);
            buf[kq+0][mm] = v.x; buf[kq+1][mm] = v.y; buf[kq+2][mm] = v.z; buf[kq+3][mm] = v.w;
        }
        __syncthreads();
        float dot[4] = {};
        #pragma unroll 4
        for (int k0 = 0; k0 < 64; k0 += 4) {
            float4 q4 = *(const float4*)&q_lds[tq][k0];
            float4 p0 = *(const float4*)&buf[k0+0][mg * 4];
            float4 p1 = *(const float4*)&buf[k0+1][mg * 4];
            float4 p2 = *(const float4*)&buf[k0+2][mg * 4];
            float4 p3 = *(const float4*)&buf[k0+3][mg * 4];
            dot[0] += q4.x*p0.x + q4.y*p1.x + q4.z*p2.x + q4.w*p3.x;
            dot[1] += q4.x*p0.y + q4.y*p1.y + q4.z*p2.y + q4.w*p3.y;
            dot[2] += q4.x*p0.z + q4.y*p1.z + q4.z*p2.z + q4.w*p3.z;
            dot[3] += q4.x*p0.w + q4.y*p1.w + q4.z*p2.w + q4.w*p3.w;
        }
        int m = m0 + mg * 4;
        if (m < MP2) {
            float4 o = make_float4(dot[0]*DN, dot[1]*DN, dot[2]*DN, dot[3]*DN);
            *(float4*)&dd[tq][m] = o;
        }
    }
    __syncthreads();
    {
        int t = tid >> 4, lane = tid & 15;
        float pm = -1e30f;
        for (int m = lane; m < MFEAT; m += 16) pm = fmaxf(pm, dd[t][m]);
        red[tid] = pm;
    }
    __syncthreads();
    if (tid < 16) {
        float pm = -1e30f;
        #pragma unroll
        for (int j = 0; j < 16; ++j) pm = fmaxf(pm, red[tid * 16 + j]);
        rmax[tid] = pm;
    }
    __syncthreads();
    for (int r = 0; r < 17; ++r) {
        int id = tid + r * 256;       // exactly covers 16*272
        int t = id / MP2, m = id - t * MP2;
        float v = 0.f;
        if (m < MFEAT) v = RATIO * (expf(dd[t][m] - diag[t] - rmax[t]) + 1e-4f);
        dd[t][m] = v;
    }
    __syncthreads();
    {
        int t = tid >> 4, lane = tid & 15;
        float s = 0.f;
        for (int m = lane; m < MP2; m += 16) s += dd[t][m] * ksum_lds[m];
        red[tid] = s;
    }
    __syncthreads();
    if (tid < 16) {
        float s = 0.f;
        #pragma unroll
        for (int j = 0; j < 16; ++j) s += red[tid * 16 + j];
        denomv[tid] = s;
    }
    const int t7 = tid >> 4, dg = tid & 15;
    float4 acc = make_float4(0.f, 0.f, 0.f, 0.f);
    for (int mt = 0; mt < 5; ++mt) {
        __syncthreads();
        #pragma unroll
        for (int r = 0; r < 4; ++r) {
            int id = tid + r * 256;
            int mm = id >> 4, kq = (id & 15) * 4;
            *(float4*)&buf[mm][kq] =
                *(const float4*)(ctx + ((size_t)bh * MPAD + mt * 64 + mm) * 64 + kq);
        }
        __syncthreads();
        int mmax = (mt == 4) ? 16 : 64;
        #pragma unroll 8
        for (int mm = 0; mm < mmax; ++mm) {
            float qv = dd[t7][mt * 64 + mm];
            float4 cv = *(const float4*)&buf[mm][dg * 4];
            acc.x += qv * cv.x; acc.y += qv * cv.y; acc.z += qv * cv.z; acc.w += qv * cv.w;
        }
    }
    float inv = 1.0f / denomv[t7];
    acc.x *= inv; acc.y *= inv; acc.z *= inv; acc.w *= inv;
    *(float4*)(attn_out + ((size_t)(b * NTOK + n0 + t7)) * CINNER + hh * DHEAD + dg * 4) = acc;
}

// ---------------- group-norm ----------------
__global__ __launch_bounds__(256) void gn_part_kernel(const float* __restrict__ y,
    float2* __restrict__ part)
{
    __shared__ float s_s[256], s_q[256];
    const int tid = threadIdx.x;
    const int sp = blockIdx.x, g = blockIdx.y, b = blockIdx.z;
    int p = sp * 256 + tid;
    const float* base = y + ((size_t)(b * NTOK + p)) * CDIM + g * 24;
    float s = 0.f, q = 0.f;
    #pragma unroll
    for (int i = 0; i < 24; ++i) { float v = base[i]; s += v; q += v * v; }
    s_s[tid] = s; s_q[tid] = q;
    __syncthreads();
    for (int st = 128; st; st >>= 1) {
        if (tid < st) { s_s[tid] += s_s[tid + st]; s_q[tid] += s_q[tid + st]; }
        __syncthreads();
    }
    if (tid == 0) part[(b * 8 + g) * 16 + sp] = make_float2(s_s[0], s_q[0]);
}

__global__ void gn_stat_kernel(const float2* __restrict__ part, float2* __restrict__ stat)
{
    int bg = threadIdx.x;
    if (bg < 32) {
        float s = 0.f, q = 0.f;
        for (int i = 0; i < 16; ++i) { float2 v = part[bg * 16 + i]; s += v.x; q += v.y; }
        float mean = s * (1.0f / 98304.0f);
        float var = q * (1.0f / 98304.0f) - mean * mean;
        stat[bg] = make_float2(mean, rsqrtf(var + 1e-5f));
    }
}

__global__ __launch_bounds__(256) void gn_apply_kernel(const float* __restrict__ y,
    const float2* __restrict__ stat, const float* __restrict__ gg,
    const float* __restrict__ gb, float* __restrict__ out)
{
    __shared__ float tile[64][65];
    const int tid = threadIdx.x;
    const int pt = blockIdx.x, ct = blockIdx.y, b = blockIdx.z;
    const int p0 = pt * 64, c0 = ct * 64;
    #pragma unroll
    for (int r = 0; r < 4; ++r) {
        int id = tid + r * 256;
        int pr = id >> 4, kq = (id & 15) * 4;
        float4 v = *(const float4*)(y + ((size_t)(b * NTOK + p0 + pr)) * CDIM + c0 + kq);
        tile[pr][kq+0] = v.x; tile[pr][kq+1] = v.y; tile[pr][kq+2] = v.z; tile[pr][kq+3] = v.w;
    }
    __syncthreads();
    const int cc = tid >> 6, pp = tid & 63;
    #pragma unroll
    for (int i = 0; i < 16; ++i) {
        int c = c0 + cc * 16 + i;
        int g = c / 24;
        float2 st = stat[b * 8 + g];
        float v = tile[pp][cc * 16 + i];
        out[((size_t)(b * CDIM + c)) * NTOK + p0 + pp] = (v - st.x) * st.y * gg[c] + gb[c];
    }
}

// ---------------- grouped circular conv + gelu, v2 ----------------
// Block: (oc-pair, y-slice, batch). Full-width LDS tile with wrap halo.
// Thread: OX contiguous x-outputs for OCB ocs; register row buffer; uniform
// (scalar) weight loads. RS padded: mult of 4 (b128 align), non-mult of 8
// (spread ty bank phases).
template<int KS, int CIN, int COUT, int OX, int YS, int OCB>
__global__ __launch_bounds__(256) void circ_conv2(const float* __restrict__ in,
    const float* __restrict__ w, const float* __restrict__ bias,
    float* __restrict__ out, int do_gelu)
{
    constexpr int P   = KS / 2;
    constexpr int ICG = CIN / 8;
    constexpr int OCG = COUT / 8;
    constexpr int TW  = 64 + 2 * P;
    constexpr int TR  = 64 / YS + 2 * P;
    constexpr int RS0 = (TW + 3) & ~3;
    constexpr int RS  = (RS0 % 8 == 0) ? RS0 + 4 : RS0;
    constexpr int TCX = 64 / OX;
    constexpr int RV  = (OX + KS - 1 + 3) & ~3;
    __shared__ __align__(16) float tile[TR * RS];
    const int tid = threadIdx.x;
    const int oc0 = blockIdx.x * OCB;
    const int y0  = blockIdx.y * (64 / YS);
    const int b   = blockIdx.z;
    const int g   = oc0 / OCG;
    const int tx  = tid % TCX, ty = tid / TCX;
    float acc[OCB][OX] = {};
    const float* ip0 = in + ((size_t)(b * CIN + g * ICG)) * 4096;
    #pragma unroll 1
    for (int ic = 0; ic < ICG; ++ic) {
        __syncthreads();
        const float* ip = ip0 + (size_t)ic * 4096;
        for (int idx = tid; idx < TR * TW; idx += 256) {
            int r = idx / TW, c = idx - r * TW;
            int gy = (y0 + r - P) & 63, gx = (c - P) & 63;
            tile[r * RS + c] = ip[gy * 64 + gx];
        }
        __syncthreads();
        const float* wp = w + ((size_t)oc0 * ICG + ic) * (KS * KS);
        #pragma unroll 1
        for (int ky = 0; ky < KS; ++ky) {
            float wreg[OCB][KS];
            #pragma unroll
            for (int oc = 0; oc < OCB; ++oc)
                #pragma unroll
                for (int kx = 0; kx < KS; ++kx)
                    wreg[oc][kx] = wp[(size_t)oc * ICG * KS * KS + ky * KS + kx];
            float rv[RV];
            const float* rp = &tile[(ty + ky) * RS + tx * OX];
            #pragma unroll
            for (int q2 = 0; q2 < RV / 4; ++q2)
                *(float4*)&rv[q2 * 4] = *(const float4*)(rp + q2 * 4);
            #pragma unroll
            for (int kx = 0; kx < KS; ++kx)
                #pragma unroll
                for (int oc = 0; oc < OCB; ++oc)
                    #pragma unroll
                    for (int ox = 0; ox < OX; ++ox)
                        acc[oc][ox] += rv[kx + ox] * wreg[oc][kx];
        }
    }
    const int y = y0 + ty, x = tx * OX;
    #pragma unroll
    for (int oc = 0; oc < OCB; ++oc) {
        float bv = bias[oc0 + oc];
        float vo[OX];
        #pragma unroll
        for (int ox = 0; ox < OX; ++ox) {
            float vv = acc[oc][ox] + bv;
            vo[ox] = do_gelu ? gelu_f(vv) : vv;
        }
        float* op = out + (((size_t)(b * COUT + oc0 + oc) * 64 + y)) * 64 + x;
        #pragma unroll
        for (int q2 = 0; q2 < OX / 4; ++q2)
            *(float4*)(op + q2 * 4) = *(float4*)&vo[q2 * 4];
    }
}

// ---------------- final 1x1 conv -> output layout [b,1,y,x,c] ----------------
__global__ __launch_bounds__(256) void conv1_kernel(const float* __restrict__ in,
    const float* __restrict__ w, const float* __restrict__ bias, float* __restrict__ out)
{
    int idx = blockIdx.x * 256 + threadIdx.x;  // 16384 pixels
    int b = idx >> 12, p = idx & 4095;
    float a0 = bias[0], a1 = bias[1], a2 = bias[2];
    const float* ip = in + (size_t)b * 48 * NTOK + p;
    #pragma unroll 8
    for (int ic = 0; ic < 48; ++ic) {
        float v = ip[(size_t)ic * NTOK];
        a0 += v * w[ic]; a1 += v * w[48 + ic]; a2 += v * w[96 + ic];
    }
    float* op = out + (size_t)idx * 3;
    op[0] = a0; op[1] = a1; op[2] = a2;
}

// ---------------- host launch ----------------
static inline void gemm(hipStream_t s, const float* A, const float* B, const float* bias,
                        const float* resid, float* C, int M, int N, int K, int epi)
{
    dim3 g((N + 127) / 128, M / 128);
    hipLaunchKernelGGL(gemm_tn, g, dim3(256), 0, s, A, B, bias, resid, C, M, N, K, epi);
}

extern "C" void kernel_launch(void* const* d_in, const int* in_sizes, int n_in,
                              void* d_out, int out_size, void* d_ws, size_t ws_size,
                              hipStream_t stream)
{
    (void)in_sizes; (void)n_in; (void)out_size; (void)ws_size;
    const float* x        = (const float*)d_in[0];
    const float* to_in_w  = (const float*)d_in[1];
    const float* to_in_b  = (const float*)d_in[2];
    const float* pos_emb  = (const float*)d_in[3];
    const float* proj     = (const float*)d_in[4];
    const float* sn_attn_g= (const float*)d_in[5];
    const float* wq       = (const float*)d_in[6];
    const float* wk       = (const float*)d_in[7];
    const float* wv       = (const float*)d_in[8];
    const float* wo       = (const float*)d_in[9];
    const float* bo       = (const float*)d_in[10];
    const float* sn_ff_g  = (const float*)d_in[11];
    const float* w1       = (const float*)d_in[12];
    const float* b1       = (const float*)d_in[13];
    const float* w2       = (const float*)d_in[14];
    const float* b2       = (const float*)d_in[15];
    const float* expand_w = (const float*)d_in[16];
    const float* fwd_w    = (const float*)d_in[17];
    const float* dec_lin_w= (const float*)d_in[18];
    const float* dec_lin_b= (const float*)d_in[19];
    const float* gn_g     = (const float*)d_in[20];
    const float* gn_b     = (const float*)d_in[21];
    const float* c9_w     = (const float*)d_in[22];
    const float* c9_b     = (const float*)d_in[23];
    const float* c7_w     = (const float*)d_in[24];
    const float* c7_b     = (const float*)d_in[25];
    const float* c5_w     = (const float*)d_in[26];
    const float* c5_b     = (const float*)d_in[27];
    const float* c1_w     = (const float*)d_in[28];
    const float* c1_b     = (const float*)d_in[29];
    float* out = (float*)d_out;

    float* ws = (float*)d_ws;
    float* h   = ws + OFF_H;
    float* hn  = ws + OFF_HN;
    float* q   = ws + OFF_Q;
    float* k   = ws + OFF_K;          // also attn_inner
    float* v   = ws + OFF_V;
    float* big = ws + OFF_BIG;        // ff1 / decoder NCHW bufs
    float* ctxp = ws + OFF_CTXP;
    float* ksp  = ws + OFF_KSP;
    float* ctx  = ws + OFF_CTX;
    float* ksum = ws + OFF_KSUM;
    unsigned* kmaxu = (unsigned*)(ws + OFF_KMAX);
    float2* gnp = (float2*)(ws + OFF_GNP);
    float2* gns = (float2*)(ws + OFF_GNS);

    // prologue
    hipLaunchKernelGGL(input_embed, dim3(BNTOK * CDIM / 256), dim3(256), 0, stream,
                       x, to_in_w, to_in_b, pos_emb, h);
    hipLaunchKernelGGL(kmax_init, dim3(1), dim3(256), 0, stream, kmaxu);

    for (int l = 0; l < NDEPTH; ++l) {
        const float* wq_l = wq + (size_t)l * CINNER * CDIM;
        const float* wk_l = wk + (size_t)l * CINNER * CDIM;
        const float* wv_l = wv + (size_t)l * CINNER * CDIM;
        const float* wo_l = wo + (size_t)l * CDIM * CINNER;
        const float* bo_l = bo + (size_t)l * CDIM;
        const float* w1_l = w1 + (size_t)l * CFF * CDIM;
        const float* b1_l = b1 + (size_t)l * CFF;
        const float* w2_l = w2 + (size_t)l * CDIM * CFF;
        const float* b2_l = b2 + (size_t)l * CDIM;
        const float* pj_l = proj + (size_t)l * MFEAT * DHEAD;
        unsigned* kmax_l = kmaxu + l * 32;

        // attn
        hipLaunchKernelGGL(scalenorm_kernel, dim3(BNTOK / 4), dim3(256), 0, stream, h, hn, sn_attn_g, l);
        gemm(stream, hn, wq_l, nullptr, nullptr, q, BNTOK, CINNER, CDIM, 0);
        gemm(stream, hn, wk_l, nullptr, nullptr, k, BNTOK, CINNER, CDIM, 0);
        gemm(stream, hn, wv_l, nullptr, nullptr, v, BNTOK, CINNER, CDIM, 0);
        hipLaunchKernelGGL(kmax_kernel, dim3(64, 32), dim3(256), 0, stream, k, pj_l, kmax_l);
        hipLaunchKernelGGL(ctx_kernel, dim3(32, 5, 4), dim3(256), 0, stream, k, v, pj_l, kmax_l, ctxp, ksp);
        hipLaunchKernelGGL(ctx_reduce, dim3((32 * MPAD * 64 + 32 * MPAD) / 256), dim3(256), 0, stream,
                           ctxp, ctx, ksp, ksum);
        hipLaunchKernelGGL(qside_kernel, dim3(256, 32), dim3(256), 0, stream, q, pj_l, ctx, ksum, k);
        gemm(stream, k, wo_l, bo_l, h, h, BNTOK, CDIM, CINNER, 1 | 4);

        // ff
        hipLaunchKernelGGL(scalenorm_kernel, dim3(BNTOK / 4), dim3(256), 0, stream, h, hn, sn_ff_g, l);
        gemm(stream, hn, w1_l, b1_l, nullptr, big, BNTOK, CFF, CDIM, 1 | 2);
        gemm(stream, big, w2_l, b2_l, h, h, BNTOK, CDIM, CFF, 1 | 4);
    }

    // decoder linears
    gemm(stream, h, expand_w, nullptr, nullptr, hn, BNTOK, CDIM, CDIM, 0);
    gemm(stream, hn, fwd_w, nullptr, nullptr, h, BNTOK, CDIM, CDIM, 0);
    gemm(stream, h, dec_lin_w, dec_lin_b, nullptr, hn, BNTOK, CDIM, CDIM, 1);

    // group norm (NHWC stats) + apply/transpose to NCHW
    float* y0 = big;                    // [4,192,64,64]
    float* y1 = big + 3145728;          // [4,192,64,64]
    float* y2 = big + 6291456;          // [4,96,64,64]
    float* y3 = big + 7864320;          // [4,48,64,64]
    hipLaunchKernelGGL(gn_part_kernel, dim3(16, 8, 4), dim3(256), 0, stream, hn, gnp);
    hipLaunchKernelGGL(gn_stat_kernel, dim3(1), dim3(32), 0, stream, gnp, gns);
    hipLaunchKernelGGL(gn_apply_kernel, dim3(64, 3, 4), dim3(256), 0, stream, hn, gns, gn_g, gn_b, y0);

    // convs (v2): <KS, CIN, COUT, OX, YS, OCB>
    hipLaunchKernelGGL((circ_conv2<9, 192, 192, 8, 2, 2>), dim3(96, 2, 4), dim3(256), 0, stream,
                       y0, c9_w, c9_b, y1, 1);
    hipLaunchKernelGGL((circ_conv2<7, 192, 96, 8, 2, 2>), dim3(48, 2, 4), dim3(256), 0, stream,
                       y1, c7_w, c7_b, y2, 1);
    hipLaunchKernelGGL((circ_conv2<5, 96, 48, 4, 4, 2>), dim3(24, 4, 4), dim3(256), 0, stream,
                       y2, c5_w, c5_b, y3, 1);
    hipLaunchKernelGGL(conv1_kernel, dim3(BNTOK / 256), dim3(256), 0, stream, y3, c1_w, c1_b, out);
}

// Round 3
// 5619.381 us; speedup vs baseline: 1.3488x; 1.3120x over previous
//
#include <hip/hip_runtime.h>
#include <cmath>

// ---------------- constants ----------------
#define NB      4
#define NTOK    4096          // tokens per batch
#define BNTOK   16384
#define CDIM    192
#define CINNER  512
#define NHEADS  8
#define DHEAD   64
#define CFF     768
#define MFEAT   266
#define MPAD    320           // 5*64
#define MP2     272           // 17*16
#define NDEPTH  6

#define DN      0.35355339059327373f   // 64^-0.25
#define RATIO   0.06131393394849658f   // 266^-0.5
#define HALF_DN2 0.0625f               // 0.5 * dn^2

typedef unsigned short u16;
typedef __attribute__((ext_vector_type(8))) short s16x8;
typedef __attribute__((ext_vector_type(8))) u16  u16x8;
typedef __attribute__((ext_vector_type(4))) float f32x4;

// workspace offsets (floats)
#define OFF_H    0ull
#define OFF_HN   3145728ull
#define OFF_Q    6291456ull
#define OFF_K    14680064ull      /* also attn_inner; OFF_K-OFF_Q = OFF_V-OFF_K = 8388608 */
#define OFF_V    23068672ull
#define OFF_BIG  31457280ull      /* ff1 (12.58M floats) / decoder NCHW bufs */
#define OFF_CTXP 44040192ull
#define OFF_KSP  46661632ull
#define OFF_CTX  46702592ull
#define OFF_KSUM 47357952ull
#define OFF_KMAX 47368192ull      /* 192 uints */
#define OFF_GNP  47368448ull      /* 512 float2 */
#define OFF_GNS  47369472ull      /* 32 float2 */
#define OFF_WHI  47370240ull      /* u16[4239360] */
#define OFF_WLO  49489920ull      /* u16[4239360] */
// weight sub-offsets in u16 units
#define WOFF_QKV 0ull
#define WOFF_WO  1769472ull
#define WOFF_W1  2359296ull
#define WOFF_W2  3244032ull
#define WOFF_EXP 4128768ull
#define WOFF_FWD 4165632ull
#define WOFF_DEC 4202496ull
#define WTOTAL   4239360

__device__ __forceinline__ float gelu_f(float x) {
    return 0.5f * x * (1.0f + erff(x * 0.7071067811865476f));
}
__device__ __forceinline__ unsigned f2ord(float f) {
    int i = __float_as_int(f);
    return (i >= 0) ? ((unsigned)i | 0x80000000u) : (unsigned)(~i);
}
__device__ __forceinline__ float ord2f(unsigned u) {
    int i = (u & 0x80000000u) ? (int)(u & 0x7fffffffu) : ~(int)u;
    return __int_as_float(i);
}
__device__ __forceinline__ void split_bf16(float a, u16& h, u16& l) {
    unsigned ua = __float_as_uint(a);
    unsigned rh = (ua + 0x7FFFu + ((ua >> 16) & 1u)) >> 16;
    h = (u16)rh;
    float hf = __uint_as_float(rh << 16);
    float lo = a - hf;
    unsigned ul = __float_as_uint(lo);
    unsigned rl = (ul + 0x7FFFu + ((ul >> 16) & 1u)) >> 16;
    l = (u16)rl;
}

// ---------------- weight conversion kernels ----------------
__global__ __launch_bounds__(256) void cvt_qkv(const float* __restrict__ wq,
    const float* __restrict__ wk, const float* __restrict__ wv,
    u16* __restrict__ hi, u16* __restrict__ lo)
{
    int idx = blockIdx.x * 256 + threadIdx.x;     // < 6*1536*192
    int l = idx / 294912, rem = idx - l * 294912;
    int r = rem / 192, c = rem - r * 192;
    float v;
    if (r < 512)       v = wq[((size_t)l * 512 + r) * 192 + c];
    else if (r < 1024) v = wk[((size_t)l * 512 + (r - 512)) * 192 + c];
    else               v = wv[((size_t)l * 512 + (r - 1024)) * 192 + c];
    u16 h, lw; split_bf16(v, h, lw);
    hi[idx] = h; lo[idx] = lw;
}

__global__ __launch_bounds__(256) void cvt_w(const float* __restrict__ src,
    u16* __restrict__ hi, u16* __restrict__ lo, int n)
{
    int idx = blockIdx.x * 256 + threadIdx.x;
    if (idx < n) {
        u16 h, l; split_bf16(src[idx], h, l);
        hi[idx] = h; lo[idx] = l;
    }
}

__global__ __launch_bounds__(256) void cvt_dec(const float* __restrict__ e,
    const float* __restrict__ f, const float* __restrict__ d,
    u16* __restrict__ hi, u16* __restrict__ lo)
{
    int idx = blockIdx.x * 256 + threadIdx.x;     // < 3*36864
    if (idx >= 110592) return;
    int which = idx / 36864, rem = idx - which * 36864;
    float v = (which == 0) ? e[rem] : (which == 1) ? f[rem] : d[rem];
    u16 h, l; split_bf16(v, h, l);
    hi[idx] = h; lo[idx] = l;
}

// ---------------- input embed ----------------
__global__ __launch_bounds__(256) void input_embed(const float* __restrict__ x,
    const float* __restrict__ w, const float* __restrict__ bvec,
    const float* __restrict__ pos, float* __restrict__ h)
{
    int idx = blockIdx.x * 256 + threadIdx.x;
    int row = idx / CDIM, c = idx - row * CDIM;
    int p = row & (NTOK - 1);
    const float* xr = x + (size_t)row * 3;
    h[idx] = xr[0]*w[c*3+0] + xr[1]*w[c*3+1] + xr[2]*w[c*3+2] + bvec[c] + pos[(size_t)p*CDIM + c];
}

// ---------------- scalenorm ----------------
__global__ __launch_bounds__(256) void scalenorm_kernel(const float* __restrict__ in,
    float* __restrict__ out, const float* __restrict__ gptr, int gidx)
{
    int wv = threadIdx.x >> 6, lane = threadIdx.x & 63;
    int row = blockIdx.x * 4 + wv;
    const float* p = in + (size_t)row * CDIM;
    float x0 = p[lane], x1 = p[lane + 64], x2 = p[lane + 128];
    float ss = x0*x0 + x1*x1 + x2*x2;
    #pragma unroll
    for (int off = 32; off; off >>= 1) ss += __shfl_xor(ss, off);
    float g = gptr[gidx];
    float n = sqrtf(ss * (1.0f / 192.0f));
    float s = g / fmaxf(n, 1e-5f);
    float* o = out + (size_t)row * CDIM;
    o[lane] = x0 * s; o[lane + 64] = x1 * s; o[lane + 128] = x2 * s;
}

// ---------------- split-bf16 MFMA GEMM ----------------
// C[M,N] = A[M,K] @ B[N,K]^T.  A fp32 (split inline), B pre-split bf16 hi/lo.
// 128x128 block, 4 waves each 64x64 (4x4 tiles of 16x16x32), 3 MFMA per tile
// (hi*hi + hi*lo + lo*hi).  epi: 1=bias 2=gelu 4=resid 8=qkv-split-dst.
#define LP 40   // LDS row pitch in u16 (32 + 8 pad; 80B rows -> <=2-way banks)
__global__ __launch_bounds__(256) void gemm_mfma(const float* __restrict__ A,
    const u16* __restrict__ Bhi, const u16* __restrict__ Blo,
    const float* __restrict__ bias, const float* __restrict__ resid,
    float* __restrict__ C, int M, int N, int K, int epi)
{
    __shared__ u16 a_hi[128 * LP], a_lo[128 * LP], b_hi[128 * LP], b_lo[128 * LP];
    const int tid = threadIdx.x;
    const int n0 = blockIdx.x * 128, m0 = blockIdx.y * 128;
    const int wave = tid >> 6, lane = tid & 63;
    const int wr = wave >> 1, wc = wave & 1;
    const int fr = lane & 15, q = lane >> 4;
    f32x4 acc[4][4];
    #pragma unroll
    for (int i = 0; i < 4; ++i)
        #pragma unroll
        for (int j = 0; j < 4; ++j) { acc[i][j][0]=0.f; acc[i][j][1]=0.f; acc[i][j][2]=0.f; acc[i][j][3]=0.f; }

    const int srow = tid >> 1, sc0 = (tid & 1) * 16;
    const float* aptr = A + (size_t)(m0 + srow) * K + sc0;
    const bool bval = (n0 + srow) < N;
    const u16* bhp = Bhi + (size_t)(n0 + srow) * K + sc0;
    const u16* blp = Blo + (size_t)(n0 + srow) * K + sc0;
    const int soff = srow * LP + sc0;
    const int aoffb = (wr * 64 + fr) * LP + q * 8;
    const int boffb = (wc * 64 + fr) * LP + q * 8;

    for (int kc = 0; kc < K; kc += 32) {
        // ---- stage A (fp32 -> hi/lo bf16) ----
        float4 f0 = *(const float4*)(aptr + kc);
        float4 f1 = *(const float4*)(aptr + kc + 4);
        float4 f2 = *(const float4*)(aptr + kc + 8);
        float4 f3 = *(const float4*)(aptr + kc + 12);
        u16x8 h0, l0, h1, l1;
        {
            float v[16] = {f0.x,f0.y,f0.z,f0.w, f1.x,f1.y,f1.z,f1.w,
                           f2.x,f2.y,f2.z,f2.w, f3.x,f3.y,f3.z,f3.w};
            u16 hh[16], ll[16];
            #pragma unroll
            for (int i = 0; i < 16; ++i) split_bf16(v[i], hh[i], ll[i]);
            #pragma unroll
            for (int i = 0; i < 8; ++i) { h0[i]=hh[i]; l0[i]=ll[i]; h1[i]=hh[8+i]; l1[i]=ll[8+i]; }
        }
        *(u16x8*)&a_hi[soff]     = h0;  *(u16x8*)&a_hi[soff + 8] = h1;
        *(u16x8*)&a_lo[soff]     = l0;  *(u16x8*)&a_lo[soff + 8] = l1;
        // ---- stage B (pre-split) ----
        u16x8 bh0 = (u16x8)0, bh1 = (u16x8)0, bl0 = (u16x8)0, bl1 = (u16x8)0;
        if (bval) {
            bh0 = *(const u16x8*)(bhp + kc);  bh1 = *(const u16x8*)(bhp + kc + 8);
            bl0 = *(const u16x8*)(blp + kc);  bl1 = *(const u16x8*)(blp + kc + 8);
        }
        *(u16x8*)&b_hi[soff]     = bh0;  *(u16x8*)&b_hi[soff + 8] = bh1;
        *(u16x8*)&b_lo[soff]     = bl0;  *(u16x8*)&b_lo[soff + 8] = bl1;
        __syncthreads();
        // ---- fragments ----
        s16x8 Ah[4], Al[4], Bh[4], Bl[4];
        #pragma unroll
        for (int t = 0; t < 4; ++t) {
            Ah[t] = *(const s16x8*)&a_hi[aoffb + t * 16 * LP];
            Al[t] = *(const s16x8*)&a_lo[aoffb + t * 16 * LP];
            Bh[t] = *(const s16x8*)&b_hi[boffb + t * 16 * LP];
            Bl[t] = *(const s16x8*)&b_lo[boffb + t * 16 * LP];
        }
        // ---- MFMA: hi*hi, hi*lo, lo*hi ----
        #pragma unroll
        for (int i = 0; i < 4; ++i)
            #pragma unroll
            for (int j = 0; j < 4; ++j)
                acc[i][j] = __builtin_amdgcn_mfma_f32_16x16x32_bf16(Ah[i], Bh[j], acc[i][j], 0, 0, 0);
        #pragma unroll
        for (int i = 0; i < 4; ++i)
            #pragma unroll
            for (int j = 0; j < 4; ++j)
                acc[i][j] = __builtin_amdgcn_mfma_f32_16x16x32_bf16(Ah[i], Bl[j], acc[i][j], 0, 0, 0);
        #pragma unroll
        for (int i = 0; i < 4; ++i)
            #pragma unroll
            for (int j = 0; j < 4; ++j)
                acc[i][j] = __builtin_amdgcn_mfma_f32_16x16x32_bf16(Al[i], Bh[j], acc[i][j], 0, 0, 0);
        __syncthreads();
    }
    // ---- epilogue ----
    const int colb = n0 + wc * 64;
    const int rowb = m0 + wr * 64;
    #pragma unroll
    for (int j = 0; j < 4; ++j) {
        int c = colb + j * 16 + fr;
        if (c >= N) continue;
        float bb = (epi & 1) ? bias[c] : 0.f;
        float* cp;
        if (epi & 8) cp = C + (size_t)(c >> 9) * 8388608ull + (size_t)(c & 511);
        else         cp = C + c;
        const float* rp = (epi & 4) ? (resid + c) : nullptr;
        #pragma unroll
        for (int i = 0; i < 4; ++i) {
            #pragma unroll
            for (int r = 0; r < 4; ++r) {
                int row = rowb + i * 16 + q * 4 + r;
                float val = acc[i][j][r] + bb;
                if (epi & 2) val = gelu_f(val);
                if (epi & 4) val += rp[(size_t)row * N];
                size_t off = (epi & 8) ? (size_t)row * 512 : (size_t)row * N;
                cp[off] = val;
            }
        }
    }
}

// ---------------- kmax init ----------------
__global__ void kmax_init(unsigned* kmaxu) {
    if (threadIdx.x < NDEPTH * 32) kmaxu[threadIdx.x] = 0u;
}

// ---------------- k-feature global max per (b,h) ----------------
__global__ __launch_bounds__(256) void kmax_kernel(const float* __restrict__ Km,
    const float* __restrict__ pj, unsigned* __restrict__ kmaxu)
{
    __shared__ __align__(16) float projT[64][68];
    __shared__ __align__(16) float k_lds[64][68];
    __shared__ float red[256];
    const int tid = threadIdx.x;
    const int nt = blockIdx.x, bh = blockIdx.y;
    const int b = bh >> 3, hh = bh & 7;
    const int n0 = nt * 64;
    const size_t kbase = ((size_t)b * NTOK + n0) * CINNER + hh * DHEAD;
    #pragma unroll
    for (int r = 0; r < 4; ++r) {
        int id = tid + r * 256;
        int row = id >> 4, kq = (id & 15) * 4;
        *(float4*)&k_lds[row][kq] = *(const float4*)(Km + kbase + (size_t)row * CINNER + kq);
    }
    const int mg = tid & 15, jgr = tid >> 4;
    const int mm0 = mg * 4, j0 = jgr * 4;
    float lmax = -1e30f;
    for (int mt = 0; mt < 5; ++mt) {
        int m0 = mt * 64;
        __syncthreads();
        #pragma unroll
        for (int r = 0; r < 4; ++r) {
            int id = tid + r * 256;
            int mm = id >> 4, kq = (id & 15) * 4;
            int m = m0 + mm;
            float4 v = make_float4(0.f, 0.f, 0.f, 0.f);
            if (m < MFEAT) v = *(const float4*)(pj + (size_t)m * DHEAD + kq);
            projT[kq+0][mm] = v.x; projT[kq+1][mm] = v.y; projT[kq+2][mm] = v.z; projT[kq+3][mm] = v.w;
        }
        __syncthreads();
        float dot[4][4] = {};
        #pragma unroll 4
        for (int k0 = 0; k0 < 64; k0 += 4) {
            float4 p0 = *(const float4*)&projT[k0+0][mm0];
            float4 p1 = *(const float4*)&projT[k0+1][mm0];
            float4 p2 = *(const float4*)&projT[k0+2][mm0];
            float4 p3 = *(const float4*)&projT[k0+3][mm0];
            #pragma unroll
            for (int jj = 0; jj < 4; ++jj) {
                float4 kv = *(const float4*)&k_lds[j0 + jj][k0];
                dot[jj][0] += kv.x*p0.x + kv.y*p1.x + kv.z*p2.x + kv.w*p3.x;
                dot[jj][1] += kv.x*p0.y + kv.y*p1.y + kv.z*p2.y + kv.w*p3.y;
                dot[jj][2] += kv.x*p0.z + kv.y*p1.z + kv.z*p2.z + kv.w*p3.z;
                dot[jj][3] += kv.x*p0.w + kv.y*p1.w + kv.z*p2.w + kv.w*p3.w;
            }
        }
        #pragma unroll
        for (int c = 0; c < 4; ++c) {
            if (m0 + mm0 + c < MFEAT) {
                #pragma unroll
                for (int jj = 0; jj < 4; ++jj) lmax = fmaxf(lmax, dot[jj][c]);
            }
        }
    }
    lmax *= DN;
    red[tid] = lmax;
    __syncthreads();
    for (int s = 128; s; s >>= 1) {
        if (tid < s) red[tid] = fmaxf(red[tid], red[tid + s]);
        __syncthreads();
    }
    if (tid == 0) atomicMax(kmaxu + bh, f2ord(red[0]));
}

// ---------------- context accumulate ----------------
__global__ __launch_bounds__(256) void ctx_kernel(
    const float* __restrict__ Km, const float* __restrict__ Vm,
    const float* __restrict__ pj, const unsigned* __restrict__ kmaxu,
    float* __restrict__ ctx_part, float* __restrict__ ksum_part)
{
    __shared__ __align__(16) float projT[64][68];
    __shared__ __align__(16) float k_lds[32][68];
    __shared__ __align__(16) float v_lds[32][68];
    __shared__ __align__(16) float kp_lds[32][68];
    __shared__ float diag[32];
    const int tid = threadIdx.x;
    const int bh = blockIdx.x, mt = blockIdx.y, seg = blockIdx.z;
    const int b = bh >> 3, hh = bh & 7;
    const int m0 = mt * 64;
    const float kmx = ord2f(kmaxu[bh]);
    #pragma unroll
    for (int r = 0; r < 4; ++r) {
        int id = tid + r * 256;
        int mm = id >> 4, kq = (id & 15) * 4;
        int m = m0 + mm;
        float4 v = make_float4(0.f, 0.f, 0.f, 0.f);
        if (m < MFEAT) v = *(const float4*)(pj + (size_t)m * DHEAD + kq);
        projT[kq+0][mm] = v.x; projT[kq+1][mm] = v.y; projT[kq+2][mm] = v.z; projT[kq+3][mm] = v.w;
    }
    const int mg = tid & 15, jp = tid >> 4;
    const int mm0 = mg * 4, j0s = jp * 2;
    const int tdd = tid & 15, tmm = tid >> 4;
    float acc[4][4] = {};
    float ksacc = 0.f;
    const size_t rowbase = ((size_t)b * NTOK) * CINNER + hh * DHEAD;
    for (int nc = 0; nc < 32; ++nc) {
        const int n0 = seg * 1024 + nc * 32;
        __syncthreads();
        #pragma unroll
        for (int r = 0; r < 2; ++r) {
            int id = tid + r * 256;
            int j = id >> 4, kq = (id & 15) * 4;
            size_t base = rowbase + (size_t)(n0 + j) * CINNER + kq;
            *(float4*)&k_lds[j][kq] = *(const float4*)(Km + base);
            *(float4*)&v_lds[j][kq] = *(const float4*)(Vm + base);
        }
        __syncthreads();
        if (tid < 32) {
            float s = 0.f;
            #pragma unroll
            for (int k = 0; k < 64; ++k) { float xv = k_lds[tid][k]; s += xv * xv; }
            diag[tid] = HALF_DN2 * s;
        }
        __syncthreads();
        float dot[2][4] = {};
        #pragma unroll 4
        for (int k0 = 0; k0 < 64; k0 += 4) {
            float4 p0 = *(const float4*)&projT[k0+0][mm0];
            float4 p1 = *(const float4*)&projT[k0+1][mm0];
            float4 p2 = *(const float4*)&projT[k0+2][mm0];
            float4 p3 = *(const float4*)&projT[k0+3][mm0];
            #pragma unroll
            for (int jj = 0; jj < 2; ++jj) {
                float4 kv = *(const float4*)&k_lds[j0s + jj][k0];
                dot[jj][0] += kv.x*p0.x + kv.y*p1.x + kv.z*p2.x + kv.w*p3.x;
                dot[jj][1] += kv.x*p0.y + kv.y*p1.y + kv.z*p2.y + kv.w*p3.y;
                dot[jj][2] += kv.x*p0.z + kv.y*p1.z + kv.z*p2.z + kv.w*p3.z;
                dot[jj][3] += kv.x*p0.w + kv.y*p1.w + kv.z*p2.w + kv.w*p3.w;
            }
        }
        #pragma unroll
        for (int jj = 0; jj < 2; ++jj) {
            float4 kpv;
            #pragma unroll
            for (int c = 0; c < 4; ++c) {
                float val = 0.f;
                if (m0 + mm0 + c < MFEAT)
                    val = RATIO * (expf(DN * dot[jj][c] - diag[j0s + jj] - kmx) + 1e-4f);
                (&kpv.x)[c] = val;
            }
            *(float4*)&kp_lds[j0s + jj][mm0] = kpv;
        }
        __syncthreads();
        #pragma unroll 4
        for (int j = 0; j < 32; ++j) {
            float4 kv = *(const float4*)&kp_lds[j][tmm * 4];
            float4 vv = *(const float4*)&v_lds[j][tdd * 4];
            acc[0][0] += kv.x*vv.x; acc[0][1] += kv.x*vv.y; acc[0][2] += kv.x*vv.z; acc[0][3] += kv.x*vv.w;
            acc[1][0] += kv.y*vv.x; acc[1][1] += kv.y*vv.y; acc[1][2] += kv.y*vv.z; acc[1][3] += kv.y*vv.w;
            acc[2][0] += kv.z*vv.x; acc[2][1] += kv.z*vv.y; acc[2][2] += kv.z*vv.z; acc[2][3] += kv.z*vv.w;
            acc[3][0] += kv.w*vv.x; acc[3][1] += kv.w*vv.y; acc[3][2] += kv.w*vv.z; acc[3][3] += kv.w*vv.w;
        }
        if (tid < 64) {
            #pragma unroll 8
            for (int j = 0; j < 32; ++j) ksacc += kp_lds[j][tid];
        }
    }
    const size_t obase = (size_t)(seg * 32 + bh) * MPAD + m0;
    #pragma unroll
    for (int i = 0; i < 4; ++i) {
        float4 o = make_float4(acc[i][0], acc[i][1], acc[i][2], acc[i][3]);
        *(float4*)(ctx_part + (obase + tmm * 4 + i) * 64 + tdd * 4) = o;
    }
    if (tid < 64) ksum_part[obase + tid] = ksacc;
}

// ---------------- reduce ctx partials ----------------
__global__ __launch_bounds__(256) void ctx_reduce(const float* __restrict__ part,
    float* __restrict__ ctxo, const float* __restrict__ kspart, float* __restrict__ kso)
{
    int idx = blockIdx.x * 256 + threadIdx.x;
    const int CTXN = 32 * MPAD * 64;
    if (idx < CTXN) {
        float s = 0.f;
        #pragma unroll
        for (int sg = 0; sg < 4; ++sg) s += part[(size_t)sg * CTXN + idx];
        ctxo[idx] = s;
    } else {
        int k = idx - CTXN;
        if (k < 32 * MPAD) {
            float s = 0.f;
            #pragma unroll
            for (int sg = 0; sg < 4; ++sg) s += kspart[(size_t)sg * 32 * MPAD + k];
            kso[k] = s;
        }
    }
}

// ---------------- q-side fused ----------------
__global__ __launch_bounds__(256) void qside_kernel(const float* __restrict__ Qm,
    const float* __restrict__ pj, const float* __restrict__ ctx,
    const float* __restrict__ ksum, float* __restrict__ attn_out)
{
    __shared__ __align__(16) float q_lds[16][68];
    __shared__ __align__(16) float buf[64][68];
    __shared__ __align__(16) float dd[16][MP2];
    __shared__ float ksum_lds[MP2];
    __shared__ float red[256];
    __shared__ float diag[16], rmax[16], denomv[16];
    const int tid = threadIdx.x;
    const int nt = blockIdx.x, bh = blockIdx.y;
    const int b = bh >> 3, hh = bh & 7;
    const int n0 = nt * 16;
    {
        int t = tid >> 4, kq = (tid & 15) * 4;
        *(float4*)&q_lds[t][kq] =
            *(const float4*)(Qm + ((size_t)(b * NTOK + n0 + t)) * CINNER + hh * DHEAD + kq);
    }
    for (int i = tid; i < MP2; i += 256) ksum_lds[i] = ksum[(size_t)bh * MPAD + i];
    __syncthreads();
    {
        int t = tid >> 4, j = tid & 15;
        float s = 0.f;
        #pragma unroll
        for (int i = 0; i < 4; ++i) { float v = q_lds[t][j * 4 + i]; s += v * v; }
        red[tid] = s;
    }
    __syncthreads();
    if (tid < 16) {
        float s = 0.f;
        #pragma unroll
        for (int j = 0; j < 16; ++j) s += red[tid * 16 + j];
        diag[tid] = HALF_DN2 * s;
    }
    const int mg = tid & 15, tq = tid >> 4;
    for (int mt = 0; mt < 5; ++mt) {
        int m0 = mt * 64;
        __syncthreads();
        #pragma unroll
        for (int r = 0; r < 4; ++r) {
            int id = tid + r * 256;
            int mm = id >> 4, kq = (id & 15) * 4;
            int m = m0 + mm;
            float4 v = make_float4(0.f, 0.f, 0.f, 0.f);
            if (m < MFEAT) v = *(const float4*)(pj + (size_t)m * DHEAD + kq);
            buf[kq+0][mm] = v.x; buf[kq+1][mm] = v.y; buf[kq+2][mm] = v.z; buf[kq+3][mm] = v.w;
        }
        __syncthreads();
        float dot[4] = {};
        #pragma unroll 4
        for (int k0 = 0; k0 < 64; k0 += 4) {
            float4 q4 = *(const float4*)&q_lds[tq][k0];
            float4 p0 = *(const float4*)&buf[k0+0][mg * 4];
            float4 p1 = *(const float4*)&buf[k0+1][mg * 4];
            float4 p2 = *(const float4*)&buf[k0+2][mg * 4];
            float4 p3 = *(const float4*)&buf[k0+3][mg * 4];
            dot[0] += q4.x*p0.x + q4.y*p1.x + q4.z*p2.x + q4.w*p3.x;
            dot[1] += q4.x*p0.y + q4.y*p1.y + q4.z*p2.y + q4.w*p3.y;
            dot[2] += q4.x*p0.z + q4.y*p1.z + q4.z*p2.z + q4.w*p3.z;
            dot[3] += q4.x*p0.w + q4.y*p1.w + q4.z*p2.w + q4.w*p3.w;
        }
        int m = m0 + mg * 4;
        if (m < MP2) {
            float4 o = make_float4(dot[0]*DN, dot[1]*DN, dot[2]*DN, dot[3]*DN);
            *(float4*)&dd[tq][m] = o;
        }
    }
    __syncthreads();
    {
        int t = tid >> 4, lane = tid & 15;
        float pm = -1e30f;
        for (int m = lane; m < MFEAT; m += 16) pm = fmaxf(pm, dd[t][m]);
        red[tid] = pm;
    }
    __syncthreads();
    if (tid < 16) {
        float pm = -1e30f;
        #pragma unroll
        for (int j = 0; j < 16; ++j) pm = fmaxf(pm, red[tid * 16 + j]);
        rmax[tid] = pm;
    }
    __syncthreads();
    for (int r = 0; r < 17; ++r) {
        int id = tid + r * 256;
        int t = id / MP2, m = id - t * MP2;
        float v = 0.f;
        if (m < MFEAT) v = RATIO * (expf(dd[t][m] - diag[t] - rmax[t]) + 1e-4f);
        dd[t][m] = v;
    }
    __syncthreads();
    {
        int t = tid >> 4, lane = tid & 15;
        float s = 0.f;
        for (int m = lane; m < MP2; m += 16) s += dd[t][m] * ksum_lds[m];
        red[tid] = s;
    }
    __syncthreads();
    if (tid < 16) {
        float s = 0.f;
        #pragma unroll
        for (int j = 0; j < 16; ++j) s += red[tid * 16 + j];
        denomv[tid] = s;
    }
    const int t7 = tid >> 4, dg = tid & 15;
    float4 acc = make_float4(0.f, 0.f, 0.f, 0.f);
    for (int mt = 0; mt < 5; ++mt) {
        __syncthreads();
        #pragma unroll
        for (int r = 0; r < 4; ++r) {
            int id = tid + r * 256;
            int mm = id >> 4, kq = (id & 15) * 4;
            *(float4*)&buf[mm][kq] =
                *(const float4*)(ctx + ((size_t)bh * MPAD + mt * 64 + mm) * 64 + kq);
        }
        __syncthreads();
        int mmax = (mt == 4) ? 16 : 64;
        #pragma unroll 8
        for (int mm = 0; mm < mmax; ++mm) {
            float qv = dd[t7][mt * 64 + mm];
            float4 cv = *(const float4*)&buf[mm][dg * 4];
            acc.x += qv * cv.x; acc.y += qv * cv.y; acc.z += qv * cv.z; acc.w += qv * cv.w;
        }
    }
    float inv = 1.0f / denomv[t7];
    acc.x *= inv; acc.y *= inv; acc.z *= inv; acc.w *= inv;
    *(float4*)(attn_out + ((size_t)(b * NTOK + n0 + t7)) * CINNER + hh * DHEAD + dg * 4) = acc;
}

// ---------------- group-norm ----------------
__global__ __launch_bounds__(256) void gn_part_kernel(const float* __restrict__ y,
    float2* __restrict__ part)
{
    __shared__ float s_s[256], s_q[256];
    const int tid = threadIdx.x;
    const int sp = blockIdx.x, g = blockIdx.y, b = blockIdx.z;
    int p = sp * 256 + tid;
    const float* base = y + ((size_t)(b * NTOK + p)) * CDIM + g * 24;
    float s = 0.f, q = 0.f;
    #pragma unroll
    for (int i = 0; i < 24; ++i) { float v = base[i]; s += v; q += v * v; }
    s_s[tid] = s; s_q[tid] = q;
    __syncthreads();
    for (int st = 128; st; st >>= 1) {
        if (tid < st) { s_s[tid] += s_s[tid + st]; s_q[tid] += s_q[tid + st]; }
        __syncthreads();
    }
    if (tid == 0) part[(b * 8 + g) * 16 + sp] = make_float2(s_s[0], s_q[0]);
}

__global__ void gn_stat_kernel(const float2* __restrict__ part, float2* __restrict__ stat)
{
    int bg = threadIdx.x;
    if (bg < 32) {
        float s = 0.f, q = 0.f;
        for (int i = 0; i < 16; ++i) { float2 v = part[bg * 16 + i]; s += v.x; q += v.y; }
        float mean = s * (1.0f / 98304.0f);
        float var = q * (1.0f / 98304.0f) - mean * mean;
        stat[bg] = make_float2(mean, rsqrtf(var + 1e-5f));
    }
}

__global__ __launch_bounds__(256) void gn_apply_kernel(const float* __restrict__ y,
    const float2* __restrict__ stat, const float* __restrict__ gg,
    const float* __restrict__ gb, float* __restrict__ out)
{
    __shared__ float tile[64][65];
    const int tid = threadIdx.x;
    const int pt = blockIdx.x, ct = blockIdx.y, b = blockIdx.z;
    const int p0 = pt * 64, c0 = ct * 64;
    #pragma unroll
    for (int r = 0; r < 4; ++r) {
        int id = tid + r * 256;
        int pr = id >> 4, kq = (id & 15) * 4;
        float4 v = *(const float4*)(y + ((size_t)(b * NTOK + p0 + pr)) * CDIM + c0 + kq);
        tile[pr][kq+0] = v.x; tile[pr][kq+1] = v.y; tile[pr][kq+2] = v.z; tile[pr][kq+3] = v.w;
    }
    __syncthreads();
    const int cc = tid >> 6, pp = tid & 63;
    #pragma unroll
    for (int i = 0; i < 16; ++i) {
        int c = c0 + cc * 16 + i;
        int g = c / 24;
        float2 st = stat[b * 8 + g];
        float v = tile[pp][cc * 16 + i];
        out[((size_t)(b * CDIM + c)) * NTOK + p0 + pp] = (v - st.x) * st.y * gg[c] + gb[c];
    }
}

// ---------------- grouped circular conv + gelu ----------------
template<int KS, int CIN, int COUT, int OX, int YS, int OCB>
__global__ __launch_bounds__(256) void circ_conv2(const float* __restrict__ in,
    const float* __restrict__ w, const float* __restrict__ bias,
    float* __restrict__ out, int do_gelu)
{
    constexpr int P   = KS / 2;
    constexpr int ICG = CIN / 8;
    constexpr int OCG = COUT / 8;
    constexpr int TW  = 64 + 2 * P;
    constexpr int TR  = 64 / YS + 2 * P;
    constexpr int RS0 = (TW + 3) & ~3;
    constexpr int RS  = (RS0 % 8 == 0) ? RS0 + 4 : RS0;
    constexpr int TCX = 64 / OX;
    constexpr int RV  = (OX + KS - 1 + 3) & ~3;
    __shared__ __align__(16) float tile[TR * RS];
    const int tid = threadIdx.x;
    const int oc0 = blockIdx.x * OCB;
    const int y0  = blockIdx.y * (64 / YS);
    const int b   = blockIdx.z;
    const int g   = oc0 / OCG;
    const int tx  = tid % TCX, ty = tid / TCX;
    float acc[OCB][OX] = {};
    const float* ip0 = in + ((size_t)(b * CIN + g * ICG)) * 4096;
    #pragma unroll 1
    for (int ic = 0; ic < ICG; ++ic) {
        __syncthreads();
        const float* ip = ip0 + (size_t)ic * 4096;
        for (int idx = tid; idx < TR * TW; idx += 256) {
            int r = idx / TW, c = idx - r * TW;
            int gy = (y0 + r - P) & 63, gx = (c - P) & 63;
            tile[r * RS + c] = ip[gy * 64 + gx];
        }
        __syncthreads();
        const float* wp = w + ((size_t)oc0 * ICG + ic) * (KS * KS);
        #pragma unroll 1
        for (int ky = 0; ky < KS; ++ky) {
            float wreg[OCB][KS];
            #pragma unroll
            for (int oc = 0; oc < OCB; ++oc)
                #pragma unroll
                for (int kx = 0; kx < KS; ++kx)
                    wreg[oc][kx] = wp[(size_t)oc * ICG * KS * KS + ky * KS + kx];
            float rv[RV];
            const float* rp = &tile[(ty + ky) * RS + tx * OX];
            #pragma unroll
            for (int q2 = 0; q2 < RV / 4; ++q2)
                *(float4*)&rv[q2 * 4] = *(const float4*)(rp + q2 * 4);
            #pragma unroll
            for (int kx = 0; kx < KS; ++kx)
                #pragma unroll
                for (int oc = 0; oc < OCB; ++oc)
                    #pragma unroll
                    for (int ox = 0; ox < OX; ++ox)
                        acc[oc][ox] += rv[kx + ox] * wreg[oc][kx];
        }
    }
    const int y = y0 + ty, x = tx * OX;
    #pragma unroll
    for (int oc = 0; oc < OCB; ++oc) {
        float bv = bias[oc0 + oc];
        float vo[OX];
        #pragma unroll
        for (int ox = 0; ox < OX; ++ox) {
            float vv = acc[oc][ox] + bv;
            vo[ox] = do_gelu ? gelu_f(vv) : vv;
        }
        float* op = out + (((size_t)(b * COUT + oc0 + oc) * 64 + y)) * 64 + x;
        #pragma unroll
        for (int q2 = 0; q2 < OX / 4; ++q2)
            *(float4*)(op + q2 * 4) = *(float4*)&vo[q2 * 4];
    }
}

// ---------------- final 1x1 conv ----------------
__global__ __launch_bounds__(256) void conv1_kernel(const float* __restrict__ in,
    const float* __restrict__ w, const float* __restrict__ bias, float* __restrict__ out)
{
    int idx = blockIdx.x * 256 + threadIdx.x;
    int b = idx >> 12, p = idx & 4095;
    float a0 = bias[0], a1 = bias[1], a2 = bias[2];
    const float* ip = in + (size_t)b * 48 * NTOK + p;
    #pragma unroll 8
    for (int ic = 0; ic < 48; ++ic) {
        float v = ip[(size_t)ic * NTOK];
        a0 += v * w[ic]; a1 += v * w[48 + ic]; a2 += v * w[96 + ic];
    }
    float* op = out + (size_t)idx * 3;
    op[0] = a0; op[1] = a1; op[2] = a2;
}

// ---------------- host launch ----------------
static inline void gemm_mf(hipStream_t s, const float* A, const u16* Bhi, const u16* Blo,
                           const float* bias, const float* resid, float* C,
                           int M, int N, int K, int epi)
{
    dim3 g((N + 127) / 128, M / 128);
    hipLaunchKernelGGL(gemm_mfma, g, dim3(256), 0, s, A, Bhi, Blo, bias, resid, C, M, N, K, epi);
}

extern "C" void kernel_launch(void* const* d_in, const int* in_sizes, int n_in,
                              void* d_out, int out_size, void* d_ws, size_t ws_size,
                              hipStream_t stream)
{
    (void)in_sizes; (void)n_in; (void)out_size; (void)ws_size;
    const float* x        = (const float*)d_in[0];
    const float* to_in_w  = (const float*)d_in[1];
    const float* to_in_b  = (const float*)d_in[2];
    const float* pos_emb  = (const float*)d_in[3];
    const float* proj     = (const float*)d_in[4];
    const float* sn_attn_g= (const float*)d_in[5];
    const float* wq       = (const float*)d_in[6];
    const float* wk       = (const float*)d_in[7];
    const float* wv       = (const float*)d_in[8];
    const float* wo       = (const float*)d_in[9];
    const float* bo       = (const float*)d_in[10];
    const float* sn_ff_g  = (const float*)d_in[11];
    const float* w1       = (const float*)d_in[12];
    const float* b1       = (const float*)d_in[13];
    const float* w2       = (const float*)d_in[14];
    const float* b2       = (const float*)d_in[15];
    const float* expand_w = (const float*)d_in[16];
    const float* fwd_w    = (const float*)d_in[17];
    const float* dec_lin_w= (const float*)d_in[18];
    const float* dec_lin_b= (const float*)d_in[19];
    const float* gn_g     = (const float*)d_in[20];
    const float* gn_b     = (const float*)d_in[21];
    const float* c9_w     = (const float*)d_in[22];
    const float* c9_b     = (const float*)d_in[23];
    const float* c7_w     = (const float*)d_in[24];
    const float* c7_b     = (const float*)d_in[25];
    const float* c5_w     = (const float*)d_in[26];
    const float* c5_b     = (const float*)d_in[27];
    const float* c1_w     = (const float*)d_in[28];
    const float* c1_b     = (const float*)d_in[29];
    float* out = (float*)d_out;

    float* ws = (float*)d_ws;
    float* h   = ws + OFF_H;
    float* hn  = ws + OFF_HN;
    float* q   = ws + OFF_Q;
    float* k   = ws + OFF_K;
    float* v   = ws + OFF_V;
    float* big = ws + OFF_BIG;
    float* ctxp = ws + OFF_CTXP;
    float* ksp  = ws + OFF_KSP;
    float* ctx  = ws + OFF_CTX;
    float* ksum = ws + OFF_KSUM;
    unsigned* kmaxu = (unsigned*)(ws + OFF_KMAX);
    float2* gnp = (float2*)(ws + OFF_GNP);
    float2* gns = (float2*)(ws + OFF_GNS);
    u16* whi = (u16*)(ws + OFF_WHI);
    u16* wlo = (u16*)(ws + OFF_WLO);

    // prologue: embed + weight split-conversion
    hipLaunchKernelGGL(input_embed, dim3(BNTOK * CDIM / 256), dim3(256), 0, stream,
                       x, to_in_w, to_in_b, pos_emb, h);
    hipLaunchKernelGGL(kmax_init, dim3(1), dim3(256), 0, stream, kmaxu);
    hipLaunchKernelGGL(cvt_qkv, dim3(6912), dim3(256), 0, stream, wq, wk, wv,
                       whi + WOFF_QKV, wlo + WOFF_QKV);
    hipLaunchKernelGGL(cvt_w, dim3(2304), dim3(256), 0, stream, wo, whi + WOFF_WO, wlo + WOFF_WO, 589824);
    hipLaunchKernelGGL(cvt_w, dim3(3456), dim3(256), 0, stream, w1, whi + WOFF_W1, wlo + WOFF_W1, 884736);
    hipLaunchKernelGGL(cvt_w, dim3(3456), dim3(256), 0, stream, w2, whi + WOFF_W2, wlo + WOFF_W2, 884736);
    hipLaunchKernelGGL(cvt_dec, dim3(432), dim3(256), 0, stream, expand_w, fwd_w, dec_lin_w,
                       whi + WOFF_EXP, wlo + WOFF_EXP);

    for (int l = 0; l < NDEPTH; ++l) {
        const float* bo_l = bo + (size_t)l * CDIM;
        const float* b1_l = b1 + (size_t)l * CFF;
        const float* b2_l = b2 + (size_t)l * CDIM;
        const float* pj_l = proj + (size_t)l * MFEAT * DHEAD;
        unsigned* kmax_l = kmaxu + l * 32;

        // attn
        hipLaunchKernelGGL(scalenorm_kernel, dim3(BNTOK / 4), dim3(256), 0, stream, h, hn, sn_attn_g, l);
        gemm_mf(stream, hn, whi + WOFF_QKV + (size_t)l * 294912, wlo + WOFF_QKV + (size_t)l * 294912,
                nullptr, nullptr, q, BNTOK, 1536, CDIM, 8);
        hipLaunchKernelGGL(kmax_kernel, dim3(64, 32), dim3(256), 0, stream, k, pj_l, kmax_l);
        hipLaunchKernelGGL(ctx_kernel, dim3(32, 5, 4), dim3(256), 0, stream, k, v, pj_l, kmax_l, ctxp, ksp);
        hipLaunchKernelGGL(ctx_reduce, dim3((32 * MPAD * 64 + 32 * MPAD) / 256), dim3(256), 0, stream,
                           ctxp, ctx, ksp, ksum);
        hipLaunchKernelGGL(qside_kernel, dim3(256, 32), dim3(256), 0, stream, q, pj_l, ctx, ksum, k);
        gemm_mf(stream, k, whi + WOFF_WO + (size_t)l * 98304, wlo + WOFF_WO + (size_t)l * 98304,
                bo_l, h, h, BNTOK, CDIM, CINNER, 1 | 4);

        // ff
        hipLaunchKernelGGL(scalenorm_kernel, dim3(BNTOK / 4), dim3(256), 0, stream, h, hn, sn_ff_g, l);
        gemm_mf(stream, hn, whi + WOFF_W1 + (size_t)l * 147456, wlo + WOFF_W1 + (size_t)l * 147456,
                b1_l, nullptr, big, BNTOK, CFF, CDIM, 1 | 2);
        gemm_mf(stream, big, whi + WOFF_W2 + (size_t)l * 147456, wlo + WOFF_W2 + (size_t)l * 147456,
                b2_l, h, h, BNTOK, CDIM, CFF, 1 | 4);
    }

    // decoder linears
    gemm_mf(stream, h, whi + WOFF_EXP, wlo + WOFF_EXP, nullptr, nullptr, hn, BNTOK, CDIM, CDIM, 0);
    gemm_mf(stream, hn, whi + WOFF_FWD, wlo + WOFF_FWD, nullptr, nullptr, h, BNTOK, CDIM, CDIM, 0);
    gemm_mf(stream, h, whi + WOFF_DEC, wlo + WOFF_DEC, dec_lin_b, nullptr, hn, BNTOK, CDIM, CDIM, 1);

    // group norm + apply/transpose to NCHW
    float* y0 = big;
    float* y1 = big + 3145728;
    float* y2 = big + 6291456;
    float* y3 = big + 7864320;
    hipLaunchKernelGGL(gn_part_kernel, dim3(16, 8, 4), dim3(256), 0, stream, hn, gnp);
    hipLaunchKernelGGL(gn_stat_kernel, dim3(1), dim3(32), 0, stream, gnp, gns);
    hipLaunchKernelGGL(gn_apply_kernel, dim3(64, 3, 4), dim3(256), 0, stream, hn, gns, gn_g, gn_b, y0);

    // convs
    hipLaunchKernelGGL((circ_conv2<9, 192, 192, 8, 2, 2>), dim3(96, 2, 4), dim3(256), 0, stream,
                       y0, c9_w, c9_b, y1, 1);
    hipLaunchKernelGGL((circ_conv2<7, 192, 96, 8, 2, 2>), dim3(48, 2, 4), dim3(256), 0, stream,
                       y1, c7_w, c7_b, y2, 1);
    hipLaunchKernelGGL((circ_conv2<5, 96, 48, 4, 4, 2>), dim3(24, 4, 4), dim3(256), 0, stream,
                       y2, c5_w, c5_b, y3, 1);
    hipLaunchKernelGGL(conv1_kernel, dim3(BNTOK / 256), dim3(256), 0, stream, y3, c1_w, c1_b, out);
}

// Round 5
// 3780.067 us; speedup vs baseline: 2.0051x; 1.4866x over previous
//
#include <hip/hip_runtime.h>
#include <cmath>

// ---------------- constants ----------------
#define NB      4
#define NTOK    4096
#define BNTOK   16384
#define CDIM    192
#define CINNER  512
#define NHEADS  8
#define DHEAD   64
#define CFF     768
#define MFEAT   266
#define NDEPTH  6

#define DN      0.35355339059327373f   // 64^-0.25
#define RATIO   0.06131393394849658f   // 266^-0.5

typedef unsigned short u16;
typedef __attribute__((ext_vector_type(8))) short s16x8;
typedef __attribute__((ext_vector_type(8))) u16  u16x8;
typedef __attribute__((ext_vector_type(4))) float f32x4;

// workspace offsets (floats)
#define OFF_H    0ull
#define OFF_HN   3145728ull
#define OFF_Q    6291456ull
#define OFF_K    14680064ull      /* also attn_inner */
#define OFF_V    23068672ull
#define OFF_BIG  31457280ull      /* ff1 / ctxT partials / decoder NCHW bufs (12.58M floats) */
#define OFF_PJ   44040192ull      /* u16 pjhi[6*320*64] + pjlo[6*320*64] = 245760 u16 = 122880 f */
#define OFF_CTXT 44163072ull      /* u16 cthi[32*80*320] + ctlo = 1638400 u16 = 819200 f (FIXED: was overlapping pjlo) */
#define OFF_KMAX 47368192ull      /* 192 uints */
#define OFF_GNP  47368448ull
#define OFF_GNS  47369472ull
#define OFF_WHI  47370240ull      /* u16[4239360] */
#define OFF_WLO  49489920ull
// weight sub-offsets (u16 units)
#define WOFF_QKV 0ull
#define WOFF_WO  1769472ull
#define WOFF_W1  2359296ull
#define WOFF_W2  3244032ull
#define WOFF_EXP 4128768ull
#define WOFF_FWD 4165632ull
#define WOFF_DEC 4202496ull

#define PJL      20480            /* per-layer u16 count: 320*64 */
#define CTXTN    819200           /* 32*80*320 */

__device__ __forceinline__ float gelu_f(float x) {
    return 0.5f * x * (1.0f + erff(x * 0.7071067811865476f));
}
__device__ __forceinline__ unsigned f2ord(float f) {
    int i = __float_as_int(f);
    return (i >= 0) ? ((unsigned)i | 0x80000000u) : (unsigned)(~i);
}
__device__ __forceinline__ float ord2f(unsigned u) {
    int i = (u & 0x80000000u) ? (int)(u & 0x7fffffffu) : ~(int)u;
    return __int_as_float(i);
}
__device__ __forceinline__ void split_bf16(float a, u16& h, u16& l) {
    unsigned ua = __float_as_uint(a);
    unsigned rh = (ua + 0x7FFFu + ((ua >> 16) & 1u)) >> 16;
    h = (u16)rh;
    float hf = __uint_as_float(rh << 16);
    float lo = a - hf;
    unsigned ul = __float_as_uint(lo);
    unsigned rl = (ul + 0x7FFFu + ((ul >> 16) & 1u)) >> 16;
    l = (u16)rl;
}
__device__ __forceinline__ u16 hi_bf16(float a) {
    unsigned ua = __float_as_uint(a);
    return (u16)((ua + 0x7FFFu + ((ua >> 16) & 1u)) >> 16);
}

// ---------------- weight conversion ----------------
__global__ __launch_bounds__(256) void cvt_qkv(const float* __restrict__ wq,
    const float* __restrict__ wk, const float* __restrict__ wv,
    u16* __restrict__ hi, u16* __restrict__ lo)
{
    int idx = blockIdx.x * 256 + threadIdx.x;
    int l = idx / 294912, rem = idx - l * 294912;
    int r = rem / 192, c = rem - r * 192;
    float v;
    if (r < 512)       v = wq[((size_t)l * 512 + r) * 192 + c];
    else if (r < 1024) v = wk[((size_t)l * 512 + (r - 512)) * 192 + c];
    else               v = wv[((size_t)l * 512 + (r - 1024)) * 192 + c];
    u16 h, lw; split_bf16(v, h, lw);
    hi[idx] = h; lo[idx] = lw;
}

__global__ __launch_bounds__(256) void cvt_w(const float* __restrict__ src,
    u16* __restrict__ hi, u16* __restrict__ lo, int n)
{
    int idx = blockIdx.x * 256 + threadIdx.x;
    if (idx < n) {
        u16 h, l; split_bf16(src[idx], h, l);
        hi[idx] = h; lo[idx] = l;
    }
}

__global__ __launch_bounds__(256) void cvt_dec(const float* __restrict__ e,
    const float* __restrict__ f, const float* __restrict__ d,
    u16* __restrict__ hi, u16* __restrict__ lo)
{
    int idx = blockIdx.x * 256 + threadIdx.x;
    if (idx >= 110592) return;
    int which = idx / 36864, rem = idx - which * 36864;
    float v = (which == 0) ? e[rem] : (which == 1) ? f[rem] : d[rem];
    u16 h, l; split_bf16(v, h, l);
    hi[idx] = h; lo[idx] = l;
}

// proj split: [6][320][64], zero-padded m>=266
__global__ __launch_bounds__(256) void cvt_pj(const float* __restrict__ proj,
    u16* __restrict__ hi, u16* __restrict__ lo)
{
    int idx = blockIdx.x * 256 + threadIdx.x;     // < 6*320*64
    int l = idx / PJL, rem = idx - l * PJL;
    int m = rem >> 6, k = rem & 63;
    float v = (m < MFEAT) ? proj[(size_t)l * MFEAT * DHEAD + m * 64 + k] : 0.f;
    u16 h, lw; split_bf16(v, h, lw);
    hi[idx] = h; lo[idx] = lw;
}

// ---------------- input embed ----------------
__global__ __launch_bounds__(256) void input_embed(const float* __restrict__ x,
    const float* __restrict__ w, const float* __restrict__ bvec,
    const float* __restrict__ pos, float* __restrict__ h)
{
    int idx = blockIdx.x * 256 + threadIdx.x;
    int row = idx / CDIM, c = idx - row * CDIM;
    int p = row & (NTOK - 1);
    const float* xr = x + (size_t)row * 3;
    h[idx] = xr[0]*w[c*3+0] + xr[1]*w[c*3+1] + xr[2]*w[c*3+2] + bvec[c] + pos[(size_t)p*CDIM + c];
}

// ---------------- scalenorm ----------------
__global__ __launch_bounds__(256) void scalenorm_kernel(const float* __restrict__ in,
    float* __restrict__ out, const float* __restrict__ gptr, int gidx)
{
    int wv = threadIdx.x >> 6, lane = threadIdx.x & 63;
    int row = blockIdx.x * 4 + wv;
    const float* p = in + (size_t)row * CDIM;
    float x0 = p[lane], x1 = p[lane + 64], x2 = p[lane + 128];
    float ss = x0*x0 + x1*x1 + x2*x2;
    #pragma unroll
    for (int off = 32; off; off >>= 1) ss += __shfl_xor(ss, off);
    float g = gptr[gidx];
    float n = sqrtf(ss * (1.0f / 192.0f));
    float s = g / fmaxf(n, 1e-5f);
    float* o = out + (size_t)row * CDIM;
    o[lane] = x0 * s; o[lane + 64] = x1 * s; o[lane + 128] = x2 * s;
}

// ---------------- split-bf16 MFMA GEMM ----------------
#define LP 40
__global__ __launch_bounds__(256) void gemm_mfma(const float* __restrict__ A,
    const u16* __restrict__ Bhi, const u16* __restrict__ Blo,
    const float* __restrict__ bias, const float* __restrict__ resid,
    float* __restrict__ C, int M, int N, int K, int epi)
{
    __shared__ u16 a_hi[128 * LP], a_lo[128 * LP], b_hi[128 * LP], b_lo[128 * LP];
    const int tid = threadIdx.x;
    const int n0 = blockIdx.x * 128, m0 = blockIdx.y * 128;
    const int wave = tid >> 6, lane = tid & 63;
    const int wr = wave >> 1, wc = wave & 1;
    const int fr = lane & 15, q = lane >> 4;
    f32x4 acc[4][4];
    #pragma unroll
    for (int i = 0; i < 4; ++i)
        #pragma unroll
        for (int j = 0; j < 4; ++j) { acc[i][j][0]=0.f; acc[i][j][1]=0.f; acc[i][j][2]=0.f; acc[i][j][3]=0.f; }

    const int srow = tid >> 1, sc0 = (tid & 1) * 16;
    const float* aptr = A + (size_t)(m0 + srow) * K + sc0;
    const bool bval = (n0 + srow) < N;
    const u16* bhp = Bhi + (size_t)(n0 + srow) * K + sc0;
    const u16* blp = Blo + (size_t)(n0 + srow) * K + sc0;
    const int soff = srow * LP + sc0;
    const int aoffb = (wr * 64 + fr) * LP + q * 8;
    const int boffb = (wc * 64 + fr) * LP + q * 8;

    for (int kc = 0; kc < K; kc += 32) {
        float4 f0 = *(const float4*)(aptr + kc);
        float4 f1 = *(const float4*)(aptr + kc + 4);
        float4 f2 = *(const float4*)(aptr + kc + 8);
        float4 f3 = *(const float4*)(aptr + kc + 12);
        u16x8 h0, l0, h1, l1;
        {
            float v[16] = {f0.x,f0.y,f0.z,f0.w, f1.x,f1.y,f1.z,f1.w,
                           f2.x,f2.y,f2.z,f2.w, f3.x,f3.y,f3.z,f3.w};
            u16 hh[16], ll[16];
            #pragma unroll
            for (int i = 0; i < 16; ++i) split_bf16(v[i], hh[i], ll[i]);
            #pragma unroll
            for (int i = 0; i < 8; ++i) { h0[i]=hh[i]; l0[i]=ll[i]; h1[i]=hh[8+i]; l1[i]=ll[8+i]; }
        }
        *(u16x8*)&a_hi[soff]     = h0;  *(u16x8*)&a_hi[soff + 8] = h1;
        *(u16x8*)&a_lo[soff]     = l0;  *(u16x8*)&a_lo[soff + 8] = l1;
        u16x8 bh0 = (u16x8)0, bh1 = (u16x8)0, bl0 = (u16x8)0, bl1 = (u16x8)0;
        if (bval) {
            bh0 = *(const u16x8*)(bhp + kc);  bh1 = *(const u16x8*)(bhp + kc + 8);
            bl0 = *(const u16x8*)(blp + kc);  bl1 = *(const u16x8*)(blp + kc + 8);
        }
        *(u16x8*)&b_hi[soff]     = bh0;  *(u16x8*)&b_hi[soff + 8] = bh1;
        *(u16x8*)&b_lo[soff]     = bl0;  *(u16x8*)&b_lo[soff + 8] = bl1;
        __syncthreads();
        s16x8 Ah[4], Al[4], Bh[4], Bl[4];
        #pragma unroll
        for (int t = 0; t < 4; ++t) {
            Ah[t] = *(const s16x8*)&a_hi[aoffb + t * 16 * LP];
            Al[t] = *(const s16x8*)&a_lo[aoffb + t * 16 * LP];
            Bh[t] = *(const s16x8*)&b_hi[boffb + t * 16 * LP];
            Bl[t] = *(const s16x8*)&b_lo[boffb + t * 16 * LP];
        }
        #pragma unroll
        for (int i = 0; i < 4; ++i)
            #pragma unroll
            for (int j = 0; j < 4; ++j)
                acc[i][j] = __builtin_amdgcn_mfma_f32_16x16x32_bf16(Ah[i], Bh[j], acc[i][j], 0, 0, 0);
        #pragma unroll
        for (int i = 0; i < 4; ++i)
            #pragma unroll
            for (int j = 0; j < 4; ++j)
                acc[i][j] = __builtin_amdgcn_mfma_f32_16x16x32_bf16(Ah[i], Bl[j], acc[i][j], 0, 0, 0);
        #pragma unroll
        for (int i = 0; i < 4; ++i)
            #pragma unroll
            for (int j = 0; j < 4; ++j)
                acc[i][j] = __builtin_amdgcn_mfma_f32_16x16x32_bf16(Al[i], Bh[j], acc[i][j], 0, 0, 0);
        __syncthreads();
    }
    const int c0 = n0 + wc * 64;
    const int rowb = m0 + wr * 64;
    #pragma unroll
    for (int j = 0; j < 4; ++j) {
        int c = c0 + j * 16 + fr;
        if (c >= N) continue;
        float bb = (epi & 1) ? bias[c] : 0.f;
        float* cp;
        if (epi & 8) cp = C + (size_t)(c >> 9) * 8388608ull + (size_t)(c & 511);
        else         cp = C + c;
        const float* rp = (epi & 4) ? (resid + c) : nullptr;
        #pragma unroll
        for (int i = 0; i < 4; ++i) {
            #pragma unroll
            for (int r = 0; r < 4; ++r) {
                int row = rowb + i * 16 + q * 4 + r;
                float val = acc[i][j][r] + bb;
                if (epi & 2) val = gelu_f(val);
                if (epi & 4) val += rp[(size_t)row * N];
                size_t off = (epi & 8) ? (size_t)row * 512 : (size_t)row * N;
                cp[off] = val;
            }
        }
    }
}

// ---------------- kmax init ----------------
__global__ void kmax_init(unsigned* kmaxu) {
    if (threadIdx.x < NDEPTH * 32) kmaxu[threadIdx.x] = 0u;
}

// ---------------- kmax2: MFMA dd global max (hi-only) ----------------
__global__ __launch_bounds__(256) void kmax2_kernel(const float* __restrict__ Km,
    const u16* __restrict__ pjh, unsigned* __restrict__ kmaxu)
{
    __shared__ __align__(16) u16 khi[64 * 72];
    __shared__ float wred[4];
    const int tid = threadIdx.x;
    const int nt = blockIdx.x, bh = blockIdx.y;
    const int b = bh >> 3, hh = bh & 7;
    const int wave = tid >> 6, lane = tid & 63;
    const int fr = lane & 15, quad = lane >> 4;
    float lm = -1e30f;
    const size_t kbase = ((size_t)b * NTOK) * CINNER + hh * DHEAD;
    for (int ch = 0; ch < 8; ++ch) {
        const int n0 = nt * 512 + ch * 64;
        __syncthreads();
        {
            int tok = tid >> 2, koff = (tid & 3) * 16;
            const float* kp = Km + kbase + (size_t)(n0 + tok) * CINNER + koff;
            u16 hh16[16];
            #pragma unroll
            for (int qd = 0; qd < 4; ++qd) {
                float4 f = *(const float4*)(kp + qd * 4);
                hh16[qd*4+0] = hi_bf16(f.x * DN); hh16[qd*4+1] = hi_bf16(f.y * DN);
                hh16[qd*4+2] = hi_bf16(f.z * DN); hh16[qd*4+3] = hi_bf16(f.w * DN);
            }
            u16x8 v0, v1;
            #pragma unroll
            for (int i = 0; i < 8; ++i) { v0[i] = hh16[i]; v1[i] = hh16[8+i]; }
            *(u16x8*)&khi[tok * 72 + koff] = v0;
            *(u16x8*)&khi[tok * 72 + koff + 8] = v1;
        }
        __syncthreads();
        int rowA = (wave * 16 + fr) * 72;
        s16x8 A0 = *(const s16x8*)&khi[rowA + quad * 8];
        s16x8 A1 = *(const s16x8*)&khi[rowA + 32 + quad * 8];
        for (int ct = 0; ct < 17; ++ct) {
            const u16* bp = pjh + (ct * 16 + fr) * 64 + quad * 8;
            s16x8 B0 = *(const s16x8*)bp;
            s16x8 B1 = *(const s16x8*)(bp + 32);
            f32x4 t; t[0]=0.f; t[1]=0.f; t[2]=0.f; t[3]=0.f;
            t = __builtin_amdgcn_mfma_f32_16x16x32_bf16(A0, B0, t, 0, 0, 0);
            t = __builtin_amdgcn_mfma_f32_16x16x32_bf16(A1, B1, t, 0, 0, 0);
            if (ct * 16 + fr < MFEAT) {
                #pragma unroll
                for (int r = 0; r < 4; ++r) lm = fmaxf(lm, t[r]);
            }
        }
    }
    #pragma unroll
    for (int off = 32; off; off >>= 1) lm = fmaxf(lm, __shfl_xor(lm, off));
    if (lane == 0) wred[wave] = lm;
    __syncthreads();
    if (tid == 0) {
        float m = fmaxf(fmaxf(wred[0], wred[1]), fmaxf(wred[2], wred[3]));
        atomicMax(kmaxu + bh, f2ord(m));
    }
}

// ---------------- ctx2: K-side features + ctxT accumulate (MFMA) ----------------
// grid (32 bh, 8 seg).  Output partials fp32 [seg][bh][80][320] (row 64 = ksum).
__global__ __launch_bounds__(256) void ctx2_kernel(const float* __restrict__ Km,
    const float* __restrict__ Vm, const u16* __restrict__ pjh, const u16* __restrict__ pjl,
    const unsigned* __restrict__ kmaxu, float* __restrict__ part)
{
    __shared__ __align__(16) u16 khi[32 * 72], klo[32 * 72];
    __shared__ __align__(16) u16 vth[80 * 40], vtl[80 * 40];
    __shared__ __align__(16) u16 kph[64 * 40], kpl[64 * 40];
    __shared__ float diag[32];
    const int tid = threadIdx.x;
    const int bh = blockIdx.x, seg = blockIdx.y;
    const int b = bh >> 3, hh = bh & 7;
    const int wave = tid >> 6, lane = tid & 63;
    const int fr = lane & 15, quad = lane >> 4;
    const float kmx = ord2f(kmaxu[bh]);
    for (int i = tid; i < 16 * 40; i += 256) {
        int row = 64 + i / 40, col = i - (i / 40) * 40;
        vth[row * 40 + col] = (row == 64) ? (u16)0x3F80 : (u16)0;
        vtl[row * 40 + col] = 0;
    }
    f32x4 accv[5][5];
    #pragma unroll
    for (int i = 0; i < 5; ++i)
        #pragma unroll
        for (int j = 0; j < 5; ++j) { accv[i][j][0]=0.f; accv[i][j][1]=0.f; accv[i][j][2]=0.f; accv[i][j][3]=0.f; }
    const size_t rowbase = ((size_t)b * NTOK) * CINNER + hh * DHEAD;
    const int rt = wave & 1, ctp = wave >> 1;
    for (int nc = 0; nc < 16; ++nc) {
        const int n0 = seg * 512 + nc * 32;
        __syncthreads();
        {   // stage k (scaled+split) + diag
            int tok = tid >> 3, koff = (tid & 7) * 8;
            const float* kp = Km + rowbase + (size_t)(n0 + tok) * CINNER + koff;
            float4 f0 = *(const float4*)kp;
            float4 f1 = *(const float4*)(kp + 4);
            float v[8] = {f0.x*DN, f0.y*DN, f0.z*DN, f0.w*DN, f1.x*DN, f1.y*DN, f1.z*DN, f1.w*DN};
            u16x8 hv, lv; float ps = 0.f;
            #pragma unroll
            for (int i = 0; i < 8; ++i) { u16 h, l; split_bf16(v[i], h, l); hv[i]=h; lv[i]=l; ps += v[i]*v[i]; }
            *(u16x8*)&khi[tok * 72 + koff] = hv;
            *(u16x8*)&klo[tok * 72 + koff] = lv;
            ps += __shfl_xor(ps, 1); ps += __shfl_xor(ps, 2); ps += __shfl_xor(ps, 4);
            if ((tid & 7) == 0) diag[tok] = 0.5f * ps;
            const float* vp = Vm + rowbase + (size_t)(n0 + tok) * CINNER + koff;
            float4 g0 = *(const float4*)vp;
            float4 g1 = *(const float4*)(vp + 4);
            float vv[8] = {g0.x, g0.y, g0.z, g0.w, g1.x, g1.y, g1.z, g1.w};
            #pragma unroll
            for (int i = 0; i < 8; ++i) {
                u16 h, l; split_bf16(vv[i], h, l);
                vth[(koff + i) * 40 + tok] = h;
                vtl[(koff + i) * 40 + tok] = l;
            }
        }
        __syncthreads();
        for (int mc = 0; mc < 5; ++mc) {
            f32x4 dd2[2];
            dd2[0][0]=0.f; dd2[0][1]=0.f; dd2[0][2]=0.f; dd2[0][3]=0.f;
            dd2[1] = dd2[0];
            {
                int rowA = (rt * 16 + fr) * 72;
                s16x8 A0h = *(const s16x8*)&khi[rowA + quad * 8];
                s16x8 A1h = *(const s16x8*)&khi[rowA + 32 + quad * 8];
                s16x8 A0l = *(const s16x8*)&klo[rowA + quad * 8];
                s16x8 A1l = *(const s16x8*)&klo[rowA + 32 + quad * 8];
                #pragma unroll
                for (int c = 0; c < 2; ++c) {
                    int ct = mc * 4 + ctp * 2 + c;
                    const u16* bph = pjh + (ct * 16 + fr) * 64 + quad * 8;
                    const u16* bpl = pjl + (ct * 16 + fr) * 64 + quad * 8;
                    s16x8 B0h = *(const s16x8*)bph, B1h = *(const s16x8*)(bph + 32);
                    s16x8 B0l = *(const s16x8*)bpl, B1l = *(const s16x8*)(bpl + 32);
                    dd2[c] = __builtin_amdgcn_mfma_f32_16x16x32_bf16(A0h, B0h, dd2[c], 0, 0, 0);
                    dd2[c] = __builtin_amdgcn_mfma_f32_16x16x32_bf16(A0h, B0l, dd2[c], 0, 0, 0);
                    dd2[c] = __builtin_amdgcn_mfma_f32_16x16x32_bf16(A0l, B0h, dd2[c], 0, 0, 0);
                    dd2[c] = __builtin_amdgcn_mfma_f32_16x16x32_bf16(A1h, B1h, dd2[c], 0, 0, 0);
                    dd2[c] = __builtin_amdgcn_mfma_f32_16x16x32_bf16(A1h, B1l, dd2[c], 0, 0, 0);
                    dd2[c] = __builtin_amdgcn_mfma_f32_16x16x32_bf16(A1l, B1h, dd2[c], 0, 0, 0);
                }
            }
            #pragma unroll
            for (int c = 0; c < 2; ++c) {
                int ct = mc * 4 + ctp * 2 + c;
                bool valid = (ct * 16 + fr) < MFEAT;
                ushort4 ph, pl;
                #pragma unroll
                for (int r = 0; r < 4; ++r) {
                    float dgv = diag[rt * 16 + quad * 4 + r];
                    float val = valid ? RATIO * (expf(dd2[c][r] - dgv - kmx) + 1e-4f) : 0.f;
                    u16 h, l; split_bf16(val, h, l);
                    (&ph.x)[r] = h; (&pl.x)[r] = l;
                }
                int ml = (ctp * 2 + c) * 16 + fr;
                *(ushort4*)&kph[ml * 40 + rt * 16 + quad * 4] = ph;
                *(ushort4*)&kpl[ml * 40 + rt * 16 + quad * 4] = pl;
            }
            __syncthreads();
            {
                s16x8 Bh = *(const s16x8*)&kph[(wave * 16 + fr) * 40 + quad * 8];
                s16x8 Bl = *(const s16x8*)&kpl[(wave * 16 + fr) * 40 + quad * 8];
                #pragma unroll
                for (int rt2 = 0; rt2 < 5; ++rt2) {
                    s16x8 Ah = *(const s16x8*)&vth[(rt2 * 16 + fr) * 40 + quad * 8];
                    s16x8 Al = *(const s16x8*)&vtl[(rt2 * 16 + fr) * 40 + quad * 8];
                    accv[rt2][mc] = __builtin_amdgcn_mfma_f32_16x16x32_bf16(Ah, Bh, accv[rt2][mc], 0, 0, 0);
                    accv[rt2][mc] = __builtin_amdgcn_mfma_f32_16x16x32_bf16(Ah, Bl, accv[rt2][mc], 0, 0, 0);
                    accv[rt2][mc] = __builtin_amdgcn_mfma_f32_16x16x32_bf16(Al, Bh, accv[rt2][mc], 0, 0, 0);
                }
            }
            __syncthreads();
        }
    }
    float* pb = part + ((size_t)(seg * 32 + bh)) * 80 * 320;
    #pragma unroll
    for (int rt2 = 0; rt2 < 5; ++rt2) {
        #pragma unroll
        for (int mc = 0; mc < 5; ++mc) {
            int ct = mc * 4 + wave;
            #pragma unroll
            for (int r = 0; r < 4; ++r)
                pb[(size_t)(rt2 * 16 + quad * 4 + r) * 320 + ct * 16 + fr] = accv[rt2][mc][r];
        }
    }
}

// ---------------- reduce ctxT partials (8 segs) + split to bf16 ----------------
__global__ __launch_bounds__(256) void ctxt_reduce(const float* __restrict__ part,
    u16* __restrict__ cth, u16* __restrict__ ctl)
{
    int idx = blockIdx.x * 256 + threadIdx.x;   // < 819200
    float s = 0.f;
    #pragma unroll
    for (int sg = 0; sg < 8; ++sg) s += part[(size_t)sg * CTXTN + idx];
    u16 h, l; split_bf16(s, h, l);
    cth[idx] = h; ctl[idx] = l;
}

// ---------------- qside2: Q features + PV + divide (MFMA) ----------------
// grid (64 nt, 32 bh).  64 tokens/block.
__global__ __launch_bounds__(256) void qside2_kernel(const float* __restrict__ Qm,
    const u16* __restrict__ pjh, const u16* __restrict__ pjl,
    const u16* __restrict__ cth, const u16* __restrict__ ctl,
    float* __restrict__ attn_out)
{
    __shared__ __align__(16) u16 qhi[64 * 72], qlo[64 * 72];
    __shared__ __align__(16) u16 slabh[4][16 * 72], slabl[4][16 * 72];
    __shared__ float diag[64];
    const int tid = threadIdx.x;
    const int nt = blockIdx.x, bh = blockIdx.y;
    const int b = bh >> 3, hh = bh & 7;
    const int wave = tid >> 6, lane = tid & 63;
    const int fr = lane & 15, quad = lane >> 4;
    const int n0 = nt * 64;
    {
        int tok = tid >> 2, koff = (tid & 3) * 16;
        const float* qp = Qm + ((size_t)(b * NTOK + n0 + tok)) * CINNER + hh * DHEAD + koff;
        float v[16]; float ps = 0.f;
        #pragma unroll
        for (int qd = 0; qd < 4; ++qd) {
            float4 f = *(const float4*)(qp + qd * 4);
            v[qd*4+0]=f.x*DN; v[qd*4+1]=f.y*DN; v[qd*4+2]=f.z*DN; v[qd*4+3]=f.w*DN;
        }
        u16x8 h0, l0, h1, l1;
        #pragma unroll
        for (int i = 0; i < 8; ++i) {
            u16 h, l; split_bf16(v[i], h, l); h0[i]=h; l0[i]=l;
            split_bf16(v[8+i], h, l); h1[i]=h; l1[i]=l;
        }
        #pragma unroll
        for (int i = 0; i < 16; ++i) ps += v[i]*v[i];
        *(u16x8*)&qhi[tok * 72 + koff] = h0;  *(u16x8*)&qhi[tok * 72 + koff + 8] = h1;
        *(u16x8*)&qlo[tok * 72 + koff] = l0;  *(u16x8*)&qlo[tok * 72 + koff + 8] = l1;
        ps += __shfl_xor(ps, 1); ps += __shfl_xor(ps, 2);
        if ((tid & 3) == 0) diag[tok] = 0.5f * ps;
    }
    __syncthreads();
    f32x4 dd[20];
    #pragma unroll
    for (int ct = 0; ct < 20; ++ct) { dd[ct][0]=0.f; dd[ct][1]=0.f; dd[ct][2]=0.f; dd[ct][3]=0.f; }
    {
        int rowA = (wave * 16 + fr) * 72;
        s16x8 A0h = *(const s16x8*)&qhi[rowA + quad * 8];
        s16x8 A1h = *(const s16x8*)&qhi[rowA + 32 + quad * 8];
        s16x8 A0l = *(const s16x8*)&qlo[rowA + quad * 8];
        s16x8 A1l = *(const s16x8*)&qlo[rowA + 32 + quad * 8];
        #pragma unroll
        for (int ct = 0; ct < 20; ++ct) {
            const u16* bph = pjh + (ct * 16 + fr) * 64 + quad * 8;
            const u16* bpl = pjl + (ct * 16 + fr) * 64 + quad * 8;
            s16x8 B0h = *(const s16x8*)bph, B1h = *(const s16x8*)(bph + 32);
            s16x8 B0l = *(const s16x8*)bpl, B1l = *(const s16x8*)(bpl + 32);
            dd[ct] = __builtin_amdgcn_mfma_f32_16x16x32_bf16(A0h, B0h, dd[ct], 0, 0, 0);
            dd[ct] = __builtin_amdgcn_mfma_f32_16x16x32_bf16(A0h, B0l, dd[ct], 0, 0, 0);
            dd[ct] = __builtin_amdgcn_mfma_f32_16x16x32_bf16(A0l, B0h, dd[ct], 0, 0, 0);
            dd[ct] = __builtin_amdgcn_mfma_f32_16x16x32_bf16(A1h, B1h, dd[ct], 0, 0, 0);
            dd[ct] = __builtin_amdgcn_mfma_f32_16x16x32_bf16(A1h, B1l, dd[ct], 0, 0, 0);
            dd[ct] = __builtin_amdgcn_mfma_f32_16x16x32_bf16(A1l, B1h, dd[ct], 0, 0, 0);
        }
    }
    float pm[4] = {-1e30f, -1e30f, -1e30f, -1e30f};
    #pragma unroll
    for (int ct = 0; ct < 20; ++ct) {
        if (ct * 16 + fr < MFEAT) {
            #pragma unroll
            for (int r = 0; r < 4; ++r) pm[r] = fmaxf(pm[r], dd[ct][r]);
        }
    }
    #pragma unroll
    for (int r = 0; r < 4; ++r) {
        pm[r] = fmaxf(pm[r], __shfl_xor(pm[r], 1));
        pm[r] = fmaxf(pm[r], __shfl_xor(pm[r], 2));
        pm[r] = fmaxf(pm[r], __shfl_xor(pm[r], 4));
        pm[r] = fmaxf(pm[r], __shfl_xor(pm[r], 8));
    }
    float dg[4];
    #pragma unroll
    for (int r = 0; r < 4; ++r) dg[r] = diag[wave * 16 + quad * 4 + r];
    #pragma unroll
    for (int ct = 0; ct < 20; ++ct) {
        bool valid = (ct * 16 + fr) < MFEAT;
        #pragma unroll
        for (int r = 0; r < 4; ++r)
            dd[ct][r] = valid ? RATIO * (expf(dd[ct][r] - dg[r] - pm[r]) + 1e-4f) : 0.f;
    }
    f32x4 acc[5];
    #pragma unroll
    for (int dt = 0; dt < 5; ++dt) { acc[dt][0]=0.f; acc[dt][1]=0.f; acc[dt][2]=0.f; acc[dt][3]=0.f; }
    u16* sh = slabh[wave];  u16* sl = slabl[wave];
    for (int mc = 0; mc < 5; ++mc) {
        #pragma unroll
        for (int c = 0; c < 4; ++c) {
            int ct = mc * 4 + c;
            #pragma unroll
            for (int r = 0; r < 4; ++r) {
                u16 h, l; split_bf16(dd[ct][r], h, l);
                int tok = quad * 4 + r;
                sh[tok * 72 + c * 16 + fr] = h;
                sl[tok * 72 + c * 16 + fr] = l;
            }
        }
        __syncthreads();
        #pragma unroll
        for (int ks = 0; ks < 2; ++ks) {
            s16x8 Ah = *(const s16x8*)&sh[fr * 72 + ks * 32 + quad * 8];
            s16x8 Al = *(const s16x8*)&sl[fr * 72 + ks * 32 + quad * 8];
            #pragma unroll
            for (int dt = 0; dt < 5; ++dt) {
                const u16* bph = cth + ((size_t)bh * 80 + dt * 16 + fr) * 320 + mc * 64 + ks * 32 + quad * 8;
                const u16* bpl = ctl + ((size_t)bh * 80 + dt * 16 + fr) * 320 + mc * 64 + ks * 32 + quad * 8;
                s16x8 Bh = *(const s16x8*)bph;
                s16x8 Bl = *(const s16x8*)bpl;
                acc[dt] = __builtin_amdgcn_mfma_f32_16x16x32_bf16(Ah, Bh, acc[dt], 0, 0, 0);
                acc[dt] = __builtin_amdgcn_mfma_f32_16x16x32_bf16(Ah, Bl, acc[dt], 0, 0, 0);
                acc[dt] = __builtin_amdgcn_mfma_f32_16x16x32_bf16(Al, Bh, acc[dt], 0, 0, 0);
            }
        }
        __syncthreads();
    }
    #pragma unroll
    for (int r = 0; r < 4; ++r) {
        float denom = __shfl(acc[4][r], lane & 48);
        float inv = 1.0f / denom;
        int token = n0 + wave * 16 + quad * 4 + r;
        float* op = attn_out + ((size_t)(b * NTOK + token)) * CINNER + hh * DHEAD;
        #pragma unroll
        for (int dt = 0; dt < 4; ++dt)
            op[dt * 16 + fr] = acc[dt][r] * inv;
    }
}

// ---------------- group-norm ----------------
__global__ __launch_bounds__(256) void gn_part_kernel(const float* __restrict__ y,
    float2* __restrict__ part)
{
    __shared__ float s_s[256], s_q[256];
    const int tid = threadIdx.x;
    const int sp = blockIdx.x, g = blockIdx.y, b = blockIdx.z;
    int p = sp * 256 + tid;
    const float* base = y + ((size_t)(b * NTOK + p)) * CDIM + g * 24;
    float s = 0.f, q = 0.f;
    #pragma unroll
    for (int i = 0; i < 24; ++i) { float v = base[i]; s += v; q += v * v; }
    s_s[tid] = s; s_q[tid] = q;
    __syncthreads();
    for (int st = 128; st; st >>= 1) {
        if (tid < st) { s_s[tid] += s_s[tid + st]; s_q[tid] += s_q[tid + st]; }
        __syncthreads();
    }
    if (tid == 0) part[(b * 8 + g) * 16 + sp] = make_float2(s_s[0], s_q[0]);
}

__global__ void gn_stat_kernel(const float2* __restrict__ part, float2* __restrict__ stat)
{
    int bg = threadIdx.x;
    if (bg < 32) {
        float s = 0.f, q = 0.f;
        for (int i = 0; i < 16; ++i) { float2 v = part[bg * 16 + i]; s += v.x; q += v.y; }
        float mean = s * (1.0f / 98304.0f);
        float var = q * (1.0f / 98304.0f) - mean * mean;
        stat[bg] = make_float2(mean, rsqrtf(var + 1e-5f));
    }
}

__global__ __launch_bounds__(256) void gn_apply_kernel(const float* __restrict__ y,
    const float2* __restrict__ stat, const float* __restrict__ gg,
    const float* __restrict__ gb, float* __restrict__ out)
{
    __shared__ float tile[64][65];
    const int tid = threadIdx.x;
    const int pt = blockIdx.x, ct = blockIdx.y, b = blockIdx.z;
    const int p0 = pt * 64, c0 = ct * 64;
    #pragma unroll
    for (int r = 0; r < 4; ++r) {
        int id = tid + r * 256;
        int pr = id >> 4, kq = (id & 15) * 4;
        float4 v = *(const float4*)(y + ((size_t)(b * NTOK + p0 + pr)) * CDIM + c0 + kq);
        tile[pr][kq+0] = v.x; tile[pr][kq+1] = v.y; tile[pr][kq+2] = v.z; tile[pr][kq+3] = v.w;
    }
    __syncthreads();
    const int cc = tid >> 6, pp = tid & 63;
    #pragma unroll
    for (int i = 0; i < 16; ++i) {
        int c = c0 + cc * 16 + i;
        int g = c / 24;
        float2 st = stat[b * 8 + g];
        float v = tile[pp][cc * 16 + i];
        out[((size_t)(b * CDIM + c)) * NTOK + p0 + pp] = (v - st.x) * st.y * gg[c] + gb[c];
    }
}

// ---------------- grouped circular conv + gelu ----------------
template<int KS, int CIN, int COUT, int OX, int YS, int OCB>
__global__ __launch_bounds__(256) void circ_conv2(const float* __restrict__ in,
    const float* __restrict__ w, const float* __restrict__ bias,
    float* __restrict__ out, int do_gelu)
{
    constexpr int P   = KS / 2;
    constexpr int ICG = CIN / 8;
    constexpr int OCG = COUT / 8;
    constexpr int TW  = 64 + 2 * P;
    constexpr int TR  = 64 / YS + 2 * P;
    constexpr int RS0 = (TW + 3) & ~3;
    constexpr int RS  = (RS0 % 8 == 0) ? RS0 + 4 : RS0;
    constexpr int TCX = 64 / OX;
    constexpr int RV  = (OX + KS - 1 + 3) & ~3;
    __shared__ __align__(16) float tile[TR * RS];
    const int tid = threadIdx.x;
    const int oc0 = blockIdx.x * OCB;
    const int y0  = blockIdx.y * (64 / YS);
    const int b   = blockIdx.z;
    const int g   = oc0 / OCG;
    const int tx  = tid % TCX, ty = tid / TCX;
    float acc[OCB][OX] = {};
    const float* ip0 = in + ((size_t)(b * CIN + g * ICG)) * 4096;
    #pragma unroll 1
    for (int ic = 0; ic < ICG; ++ic) {
        __syncthreads();
        const float* ip = ip0 + (size_t)ic * 4096;
        for (int idx = tid; idx < TR * TW; idx += 256) {
            int r = idx / TW, c = idx - r * TW;
            int gy = (y0 + r - P) & 63, gx = (c - P) & 63;
            tile[r * RS + c] = ip[gy * 64 + gx];
        }
        __syncthreads();
        const float* wp = w + ((size_t)oc0 * ICG + ic) * (KS * KS);
        #pragma unroll 1
        for (int ky = 0; ky < KS; ++ky) {
            float wreg[OCB][KS];
            #pragma unroll
            for (int oc = 0; oc < OCB; ++oc)
                #pragma unroll
                for (int kx = 0; kx < KS; ++kx)
                    wreg[oc][kx] = wp[(size_t)oc * ICG * KS * KS + ky * KS + kx];
            float rv[RV];
            const float* rp = &tile[(ty + ky) * RS + tx * OX];
            #pragma unroll
            for (int q2 = 0; q2 < RV / 4; ++q2)
                *(float4*)&rv[q2 * 4] = *(const float4*)(rp + q2 * 4);
            #pragma unroll
            for (int kx = 0; kx < KS; ++kx)
                #pragma unroll
                for (int oc = 0; oc < OCB; ++oc)
                    #pragma unroll
                    for (int ox = 0; ox < OX; ++ox)
                        acc[oc][ox] += rv[kx + ox] * wreg[oc][kx];
        }
    }
    const int y = y0 + ty, x = tx * OX;
    #pragma unroll
    for (int oc = 0; oc < OCB; ++oc) {
        float bv = bias[oc0 + oc];
        float vo[OX];
        #pragma unroll
        for (int ox = 0; ox < OX; ++ox) {
            float vv = acc[oc][ox] + bv;
            vo[ox] = do_gelu ? gelu_f(vv) : vv;
        }
        float* op = out + (((size_t)(b * COUT + oc0 + oc) * 64 + y)) * 64 + x;
        #pragma unroll
        for (int q2 = 0; q2 < OX / 4; ++q2)
            *(float4*)(op + q2 * 4) = *(float4*)&vo[q2 * 4];
    }
}

// ---------------- final 1x1 conv ----------------
__global__ __launch_bounds__(256) void conv1_kernel(const float* __restrict__ in,
    const float* __restrict__ w, const float* __restrict__ bias, float* __restrict__ out)
{
    int idx = blockIdx.x * 256 + threadIdx.x;
    int b = idx >> 12, p = idx & 4095;
    float a0 = bias[0], a1 = bias[1], a2 = bias[2];
    const float* ip = in + (size_t)b * 48 * NTOK + p;
    #pragma unroll 8
    for (int ic = 0; ic < 48; ++ic) {
        float v = ip[(size_t)ic * NTOK];
        a0 += v * w[ic]; a1 += v * w[48 + ic]; a2 += v * w[96 + ic];
    }
    float* op = out + (size_t)idx * 3;
    op[0] = a0; op[1] = a1; op[2] = a2;
}

// ---------------- host launch ----------------
static inline void gemm_mf(hipStream_t s, const float* A, const u16* Bhi, const u16* Blo,
                           const float* bias, const float* resid, float* C,
                           int M, int N, int K, int epi)
{
    dim3 g((N + 127) / 128, M / 128);
    hipLaunchKernelGGL(gemm_mfma, g, dim3(256), 0, s, A, Bhi, Blo, bias, resid, C, M, N, K, epi);
}

extern "C" void kernel_launch(void* const* d_in, const int* in_sizes, int n_in,
                              void* d_out, int out_size, void* d_ws, size_t ws_size,
                              hipStream_t stream)
{
    (void)in_sizes; (void)n_in; (void)out_size; (void)ws_size;
    const float* x        = (const float*)d_in[0];
    const float* to_in_w  = (const float*)d_in[1];
    const float* to_in_b  = (const float*)d_in[2];
    const float* pos_emb  = (const float*)d_in[3];
    const float* proj     = (const float*)d_in[4];
    const float* sn_attn_g= (const float*)d_in[5];
    const float* wq       = (const float*)d_in[6];
    const float* wk       = (const float*)d_in[7];
    const float* wv       = (const float*)d_in[8];
    const float* wo       = (const float*)d_in[9];
    const float* bo       = (const float*)d_in[10];
    const float* sn_ff_g  = (const float*)d_in[11];
    const float* w1       = (const float*)d_in[12];
    const float* b1       = (const float*)d_in[13];
    const float* w2       = (const float*)d_in[14];
    const float* b2       = (const float*)d_in[15];
    const float* expand_w = (const float*)d_in[16];
    const float* fwd_w    = (const float*)d_in[17];
    const float* dec_lin_w= (const float*)d_in[18];
    const float* dec_lin_b= (const float*)d_in[19];
    const float* gn_g     = (const float*)d_in[20];
    const float* gn_b     = (const float*)d_in[21];
    const float* c9_w     = (const float*)d_in[22];
    const float* c9_b     = (const float*)d_in[23];
    const float* c7_w     = (const float*)d_in[24];
    const float* c7_b     = (const float*)d_in[25];
    const float* c5_w     = (const float*)d_in[26];
    const float* c5_b     = (const float*)d_in[27];
    const float* c1_w     = (const float*)d_in[28];
    const float* c1_b     = (const float*)d_in[29];
    float* out = (float*)d_out;

    float* ws = (float*)d_ws;
    float* h   = ws + OFF_H;
    float* hn  = ws + OFF_HN;
    float* q   = ws + OFF_Q;
    float* k   = ws + OFF_K;
    float* v   = ws + OFF_V;
    float* big = ws + OFF_BIG;
    u16* pjhi = (u16*)(ws + OFF_PJ);
    u16* pjlo = pjhi + 6 * PJL;
    u16* cthi = (u16*)(ws + OFF_CTXT);
    u16* ctlo = cthi + CTXTN;
    unsigned* kmaxu = (unsigned*)(ws + OFF_KMAX);
    float2* gnp = (float2*)(ws + OFF_GNP);
    float2* gns = (float2*)(ws + OFF_GNS);
    u16* whi = (u16*)(ws + OFF_WHI);
    u16* wlo = (u16*)(ws + OFF_WLO);

    // prologue
    hipLaunchKernelGGL(input_embed, dim3(BNTOK * CDIM / 256), dim3(256), 0, stream,
                       x, to_in_w, to_in_b, pos_emb, h);
    hipLaunchKernelGGL(kmax_init, dim3(1), dim3(256), 0, stream, kmaxu);
    hipLaunchKernelGGL(cvt_qkv, dim3(6912), dim3(256), 0, stream, wq, wk, wv,
                       whi + WOFF_QKV, wlo + WOFF_QKV);
    hipLaunchKernelGGL(cvt_w, dim3(2304), dim3(256), 0, stream, wo, whi + WOFF_WO, wlo + WOFF_WO, 589824);
    hipLaunchKernelGGL(cvt_w, dim3(3456), dim3(256), 0, stream, w1, whi + WOFF_W1, wlo + WOFF_W1, 884736);
    hipLaunchKernelGGL(cvt_w, dim3(3456), dim3(256), 0, stream, w2, whi + WOFF_W2, wlo + WOFF_W2, 884736);
    hipLaunchKernelGGL(cvt_dec, dim3(432), dim3(256), 0, stream, expand_w, fwd_w, dec_lin_w,
                       whi + WOFF_EXP, wlo + WOFF_EXP);
    hipLaunchKernelGGL(cvt_pj, dim3(480), dim3(256), 0, stream, proj, pjhi, pjlo);

    for (int l = 0; l < NDEPTH; ++l) {
        const float* bo_l = bo + (size_t)l * CDIM;
        const float* b1_l = b1 + (size_t)l * CFF;
        const float* b2_l = b2 + (size_t)l * CDIM;
        const u16* pjh_l = pjhi + (size_t)l * PJL;
        const u16* pjl_l = pjlo + (size_t)l * PJL;
        unsigned* kmax_l = kmaxu + l * 32;

        // attn
        hipLaunchKernelGGL(scalenorm_kernel, dim3(BNTOK / 4), dim3(256), 0, stream, h, hn, sn_attn_g, l);
        gemm_mf(stream, hn, whi + WOFF_QKV + (size_t)l * 294912, wlo + WOFF_QKV + (size_t)l * 294912,
                nullptr, nullptr, q, BNTOK, 1536, CDIM, 8);
        hipLaunchKernelGGL(kmax2_kernel, dim3(8, 32), dim3(256), 0, stream, k, pjh_l, kmax_l);
        hipLaunchKernelGGL(ctx2_kernel, dim3(32, 8), dim3(256), 0, stream, k, v, pjh_l, pjl_l, kmax_l, big);
        hipLaunchKernelGGL(ctxt_reduce, dim3(CTXTN / 256), dim3(256), 0, stream, big, cthi, ctlo);
        hipLaunchKernelGGL(qside2_kernel, dim3(64, 32), dim3(256), 0, stream, q, pjh_l, pjl_l, cthi, ctlo, k);
        gemm_mf(stream, k, whi + WOFF_WO + (size_t)l * 98304, wlo + WOFF_WO + (size_t)l * 98304,
                bo_l, h, h, BNTOK, CDIM, CINNER, 1 | 4);

        // ff
        hipLaunchKernelGGL(scalenorm_kernel, dim3(BNTOK / 4), dim3(256), 0, stream, h, hn, sn_ff_g, l);
        gemm_mf(stream, hn, whi + WOFF_W1 + (size_t)l * 147456, wlo + WOFF_W1 + (size_t)l * 147456,
                b1_l, nullptr, big, BNTOK, CFF, CDIM, 1 | 2);
        gemm_mf(stream, big, whi + WOFF_W2 + (size_t)l * 147456, wlo + WOFF_W2 + (size_t)l * 147456,
                b2_l, h, h, BNTOK, CDIM, CFF, 1 | 4);
    }

    // decoder linears
    gemm_mf(stream, h, whi + WOFF_EXP, wlo + WOFF_EXP, nullptr, nullptr, hn, BNTOK, CDIM, CDIM, 0);
    gemm_mf(stream, hn, whi + WOFF_FWD, wlo + WOFF_FWD, nullptr, nullptr, h, BNTOK, CDIM, CDIM, 0);
    gemm_mf(stream, h, whi + WOFF_DEC, wlo + WOFF_DEC, dec_lin_b, nullptr, hn, BNTOK, CDIM, CDIM, 1);

    // group norm + transpose to NCHW
    float* y0 = big;
    float* y1 = big + 3145728;
    float* y2 = big + 6291456;
    float* y3 = big + 7864320;
    hipLaunchKernelGGL(gn_part_kernel, dim3(16, 8, 4), dim3(256), 0, stream, hn, gnp);
    hipLaunchKernelGGL(gn_stat_kernel, dim3(1), dim3(32), 0, stream, gnp, gns);
    hipLaunchKernelGGL(gn_apply_kernel, dim3(64, 3, 4), dim3(256), 0, stream, hn, gns, gn_g, gn_b, y0);

    // convs
    hipLaunchKernelGGL((circ_conv2<9, 192, 192, 8, 2, 2>), dim3(96, 2, 4), dim3(256), 0, stream,
                       y0, c9_w, c9_b, y1, 1);
    hipLaunchKernelGGL((circ_conv2<7, 192, 96, 8, 2, 2>), dim3(48, 2, 4), dim3(256), 0, stream,
                       y1, c7_w, c7_b, y2, 1);
    hipLaunchKernelGGL((circ_conv2<5, 96, 48, 4, 4, 2>), dim3(24, 4, 4), dim3(256), 0, stream,
                       y2, c5_w, c5_b, y3, 1);
    hipLaunchKernelGGL(conv1_kernel, dim3(BNTOK / 256), dim3(256), 0, stream, y3, c1_w, c1_b, out);
}

// Round 6
// 3634.189 us; speedup vs baseline: 2.0856x; 1.0401x over previous
//
#include <hip/hip_runtime.h>
#include <cmath>

// ---------------- constants ----------------
#define NB      4
#define NTOK    4096
#define BNTOK   16384
#define CDIM    192
#define CINNER  512
#define NHEADS  8
#define DHEAD   64
#define CFF     768
#define MFEAT   266
#define NDEPTH  6

#define DN      0.35355339059327373f   // 64^-0.25
#define RATIO   0.06131393394849658f   // 266^-0.5

typedef unsigned short u16;
typedef __attribute__((ext_vector_type(8))) short s16x8;
typedef __attribute__((ext_vector_type(8))) u16  u16x8;
typedef __attribute__((ext_vector_type(4))) float f32x4;

// workspace offsets (floats)
#define OFF_H    0ull
#define OFF_HN   3145728ull
#define OFF_Q    6291456ull
#define OFF_K    14680064ull      /* also attn_inner */
#define OFF_V    23068672ull
#define OFF_BIG  31457280ull      /* ff1 / ctxT partials / decoder NCHW bufs (12.58M floats) */
#define OFF_PJ   44040192ull      /* u16 pjhi[6*320*64] + pjlo = 245760 u16 = 122880 f */
#define OFF_CTXT 44163072ull      /* u16 cthi[32*80*320] + ctlo = 1638400 u16 = 819200 f */
#define OFF_KMAX 47368192ull      /* 192 uints */
#define OFF_GNP  47368448ull
#define OFF_GNS  47369472ull
#define OFF_WHI  47370240ull      /* u16[4239360] */
#define OFF_WLO  49489920ull
// weight sub-offsets (u16 units)
#define WOFF_QKV 0ull
#define WOFF_WO  1769472ull
#define WOFF_W1  2359296ull
#define WOFF_W2  3244032ull
#define WOFF_EXP 4128768ull
#define WOFF_FWD 4165632ull
#define WOFF_DEC 4202496ull

#define PJL      20480            /* per-layer u16 count: 320*64 */
#define CTXTN    819200           /* 32*80*320 */

__device__ __forceinline__ float gelu_f(float x) {
    return 0.5f * x * (1.0f + erff(x * 0.7071067811865476f));
}
__device__ __forceinline__ unsigned f2ord(float f) {
    int i = __float_as_int(f);
    return (i >= 0) ? ((unsigned)i | 0x80000000u) : (unsigned)(~i);
}
__device__ __forceinline__ float ord2f(unsigned u) {
    int i = (u & 0x80000000u) ? (int)(u & 0x7fffffffu) : ~(int)u;
    return __int_as_float(i);
}
__device__ __forceinline__ void split_bf16(float a, u16& h, u16& l) {
    unsigned ua = __float_as_uint(a);
    unsigned rh = (ua + 0x7FFFu + ((ua >> 16) & 1u)) >> 16;
    h = (u16)rh;
    float hf = __uint_as_float(rh << 16);
    float lo = a - hf;
    unsigned ul = __float_as_uint(lo);
    unsigned rl = (ul + 0x7FFFu + ((ul >> 16) & 1u)) >> 16;
    l = (u16)rl;
}
__device__ __forceinline__ u16 hi_bf16(float a) {
    unsigned ua = __float_as_uint(a);
    return (u16)((ua + 0x7FFFu + ((ua >> 16) & 1u)) >> 16);
}

// ---------------- weight conversion ----------------
__global__ __launch_bounds__(256) void cvt_qkv(const float* __restrict__ wq,
    const float* __restrict__ wk, const float* __restrict__ wv,
    u16* __restrict__ hi, u16* __restrict__ lo)
{
    int idx = blockIdx.x * 256 + threadIdx.x;
    int l = idx / 294912, rem = idx - l * 294912;
    int r = rem / 192, c = rem - r * 192;
    float v;
    if (r < 512)       v = wq[((size_t)l * 512 + r) * 192 + c];
    else if (r < 1024) v = wk[((size_t)l * 512 + (r - 512)) * 192 + c];
    else               v = wv[((size_t)l * 512 + (r - 1024)) * 192 + c];
    u16 h, lw; split_bf16(v, h, lw);
    hi[idx] = h; lo[idx] = lw;
}

__global__ __launch_bounds__(256) void cvt_w(const float* __restrict__ src,
    u16* __restrict__ hi, u16* __restrict__ lo, int n)
{
    int idx = blockIdx.x * 256 + threadIdx.x;
    if (idx < n) {
        u16 h, l; split_bf16(src[idx], h, l);
        hi[idx] = h; lo[idx] = l;
    }
}

__global__ __launch_bounds__(256) void cvt_dec(const float* __restrict__ e,
    const float* __restrict__ f, const float* __restrict__ d,
    u16* __restrict__ hi, u16* __restrict__ lo)
{
    int idx = blockIdx.x * 256 + threadIdx.x;
    if (idx >= 110592) return;
    int which = idx / 36864, rem = idx - which * 36864;
    float v = (which == 0) ? e[rem] : (which == 1) ? f[rem] : d[rem];
    u16 h, l; split_bf16(v, h, l);
    hi[idx] = h; lo[idx] = l;
}

// proj split: [6][320][64], zero-padded m>=266
__global__ __launch_bounds__(256) void cvt_pj(const float* __restrict__ proj,
    u16* __restrict__ hi, u16* __restrict__ lo)
{
    int idx = blockIdx.x * 256 + threadIdx.x;     // < 6*320*64
    int l = idx / PJL, rem = idx - l * PJL;
    int m = rem >> 6, k = rem & 63;
    float v = (m < MFEAT) ? proj[(size_t)l * MFEAT * DHEAD + m * 64 + k] : 0.f;
    u16 h, lw; split_bf16(v, h, lw);
    hi[idx] = h; lo[idx] = lw;
}

// ---------------- input embed ----------------
__global__ __launch_bounds__(256) void input_embed(const float* __restrict__ x,
    const float* __restrict__ w, const float* __restrict__ bvec,
    const float* __restrict__ pos, float* __restrict__ h)
{
    int idx = blockIdx.x * 256 + threadIdx.x;
    int row = idx / CDIM, c = idx - row * CDIM;
    int p = row & (NTOK - 1);
    const float* xr = x + (size_t)row * 3;
    h[idx] = xr[0]*w[c*3+0] + xr[1]*w[c*3+1] + xr[2]*w[c*3+2] + bvec[c] + pos[(size_t)p*CDIM + c];
}

// ---------------- scalenorm ----------------
__global__ __launch_bounds__(256) void scalenorm_kernel(const float* __restrict__ in,
    float* __restrict__ out, const float* __restrict__ gptr, int gidx)
{
    int wv = threadIdx.x >> 6, lane = threadIdx.x & 63;
    int row = blockIdx.x * 4 + wv;
    const float* p = in + (size_t)row * CDIM;
    float x0 = p[lane], x1 = p[lane + 64], x2 = p[lane + 128];
    float ss = x0*x0 + x1*x1 + x2*x2;
    #pragma unroll
    for (int off = 32; off; off >>= 1) ss += __shfl_xor(ss, off);
    float g = gptr[gidx];
    float n = sqrtf(ss * (1.0f / 192.0f));
    float s = g / fmaxf(n, 1e-5f);
    float* o = out + (size_t)row * CDIM;
    o[lane] = x0 * s; o[lane + 64] = x1 * s; o[lane + 128] = x2 * s;
}

// ---------------- split-bf16 MFMA GEMM ----------------
#define LP 40
__global__ __launch_bounds__(256) void gemm_mfma(const float* __restrict__ A,
    const u16* __restrict__ Bhi, const u16* __restrict__ Blo,
    const float* __restrict__ bias, const float* __restrict__ resid,
    float* __restrict__ C, int M, int N, int K, int epi)
{
    __shared__ u16 a_hi[128 * LP], a_lo[128 * LP], b_hi[128 * LP], b_lo[128 * LP];
    const int tid = threadIdx.x;
    const int n0 = blockIdx.x * 128, m0 = blockIdx.y * 128;
    const int wave = tid >> 6, lane = tid & 63;
    const int wr = wave >> 1, wc = wave & 1;
    const int fr = lane & 15, q = lane >> 4;
    const bool wactive = (n0 + wc * 64) < N;   // skip MFMA for fully-masked column waves
    f32x4 acc[4][4];
    #pragma unroll
    for (int i = 0; i < 4; ++i)
        #pragma unroll
        for (int j = 0; j < 4; ++j) { acc[i][j][0]=0.f; acc[i][j][1]=0.f; acc[i][j][2]=0.f; acc[i][j][3]=0.f; }

    const int srow = tid >> 1, sc0 = (tid & 1) * 16;
    const float* aptr = A + (size_t)(m0 + srow) * K + sc0;
    const bool bval = (n0 + srow) < N;
    const u16* bhp = Bhi + (size_t)(n0 + srow) * K + sc0;
    const u16* blp = Blo + (size_t)(n0 + srow) * K + sc0;
    const int soff = srow * LP + sc0;
    const int aoffb = (wr * 64 + fr) * LP + q * 8;
    const int boffb = (wc * 64 + fr) * LP + q * 8;

    for (int kc = 0; kc < K; kc += 32) {
        float4 f0 = *(const float4*)(aptr + kc);
        float4 f1 = *(const float4*)(aptr + kc + 4);
        float4 f2 = *(const float4*)(aptr + kc + 8);
        float4 f3 = *(const float4*)(aptr + kc + 12);
        u16x8 h0, l0, h1, l1;
        {
            float v[16] = {f0.x,f0.y,f0.z,f0.w, f1.x,f1.y,f1.z,f1.w,
                           f2.x,f2.y,f2.z,f2.w, f3.x,f3.y,f3.z,f3.w};
            u16 hh[16], ll[16];
            #pragma unroll
            for (int i = 0; i < 16; ++i) split_bf16(v[i], hh[i], ll[i]);
            #pragma unroll
            for (int i = 0; i < 8; ++i) { h0[i]=hh[i]; l0[i]=ll[i]; h1[i]=hh[8+i]; l1[i]=ll[8+i]; }
        }
        *(u16x8*)&a_hi[soff]     = h0;  *(u16x8*)&a_hi[soff + 8] = h1;
        *(u16x8*)&a_lo[soff]     = l0;  *(u16x8*)&a_lo[soff + 8] = l1;
        u16x8 bh0 = (u16x8)0, bh1 = (u16x8)0, bl0 = (u16x8)0, bl1 = (u16x8)0;
        if (bval) {
            bh0 = *(const u16x8*)(bhp + kc);  bh1 = *(const u16x8*)(bhp + kc + 8);
            bl0 = *(const u16x8*)(blp + kc);  bl1 = *(const u16x8*)(blp + kc + 8);
        }
        *(u16x8*)&b_hi[soff]     = bh0;  *(u16x8*)&b_hi[soff + 8] = bh1;
        *(u16x8*)&b_lo[soff]     = bl0;  *(u16x8*)&b_lo[soff + 8] = bl1;
        __syncthreads();
        if (wactive) {
            s16x8 Ah[4], Al[4], Bh[4], Bl[4];
            #pragma unroll
            for (int t = 0; t < 4; ++t) {
                Ah[t] = *(const s16x8*)&a_hi[aoffb + t * 16 * LP];
                Al[t] = *(const s16x8*)&a_lo[aoffb + t * 16 * LP];
                Bh[t] = *(const s16x8*)&b_hi[boffb + t * 16 * LP];
                Bl[t] = *(const s16x8*)&b_lo[boffb + t * 16 * LP];
            }
            #pragma unroll
            for (int i = 0; i < 4; ++i)
                #pragma unroll
                for (int j = 0; j < 4; ++j)
                    acc[i][j] = __builtin_amdgcn_mfma_f32_16x16x32_bf16(Ah[i], Bh[j], acc[i][j], 0, 0, 0);
            #pragma unroll
            for (int i = 0; i < 4; ++i)
                #pragma unroll
                for (int j = 0; j < 4; ++j)
                    acc[i][j] = __builtin_amdgcn_mfma_f32_16x16x32_bf16(Ah[i], Bl[j], acc[i][j], 0, 0, 0);
            #pragma unroll
            for (int i = 0; i < 4; ++i)
                #pragma unroll
                for (int j = 0; j < 4; ++j)
                    acc[i][j] = __builtin_amdgcn_mfma_f32_16x16x32_bf16(Al[i], Bh[j], acc[i][j], 0, 0, 0);
        }
        __syncthreads();
    }
    const int c0 = n0 + wc * 64;
    const int rowb = m0 + wr * 64;
    #pragma unroll
    for (int j = 0; j < 4; ++j) {
        int c = c0 + j * 16 + fr;
        if (c >= N) continue;
        float bb = (epi & 1) ? bias[c] : 0.f;
        float* cp;
        if (epi & 8) cp = C + (size_t)(c >> 9) * 8388608ull + (size_t)(c & 511);
        else         cp = C + c;
        const float* rp = (epi & 4) ? (resid + c) : nullptr;
        #pragma unroll
        for (int i = 0; i < 4; ++i) {
            #pragma unroll
            for (int r = 0; r < 4; ++r) {
                int row = rowb + i * 16 + q * 4 + r;
                float val = acc[i][j][r] + bb;
                if (epi & 2) val = gelu_f(val);
                if (epi & 4) val += rp[(size_t)row * N];
                size_t off = (epi & 8) ? (size_t)row * 512 : (size_t)row * N;
                cp[off] = val;
            }
        }
    }
}

// ---------------- kmax init ----------------
__global__ void kmax_init(unsigned* kmaxu) {
    if (threadIdx.x < NDEPTH * 32) kmaxu[threadIdx.x] = 0u;
}

// ---------------- kmax2: MFMA dd global max (hi-only) ----------------
// grid (16 nt, 32 bh); 4 chunks of 64 tokens per block.
__global__ __launch_bounds__(256) void kmax2_kernel(const float* __restrict__ Km,
    const u16* __restrict__ pjh, unsigned* __restrict__ kmaxu)
{
    __shared__ __align__(16) u16 khi[64 * 72];
    __shared__ float wred[4];
    const int tid = threadIdx.x;
    const int nt = blockIdx.x, bh = blockIdx.y;
    const int b = bh >> 3, hh = bh & 7;
    const int wave = tid >> 6, lane = tid & 63;
    const int fr = lane & 15, quad = lane >> 4;
    float lm = -1e30f;
    const size_t kbase = ((size_t)b * NTOK) * CINNER + hh * DHEAD;
    for (int ch = 0; ch < 4; ++ch) {
        const int n0 = nt * 256 + ch * 64;
        __syncthreads();
        {
            int tok = tid >> 2, koff = (tid & 3) * 16;
            const float* kp = Km + kbase + (size_t)(n0 + tok) * CINNER + koff;
            u16 hh16[16];
            #pragma unroll
            for (int qd = 0; qd < 4; ++qd) {
                float4 f = *(const float4*)(kp + qd * 4);
                hh16[qd*4+0] = hi_bf16(f.x * DN); hh16[qd*4+1] = hi_bf16(f.y * DN);
                hh16[qd*4+2] = hi_bf16(f.z * DN); hh16[qd*4+3] = hi_bf16(f.w * DN);
            }
            u16x8 v0, v1;
            #pragma unroll
            for (int i = 0; i < 8; ++i) { v0[i] = hh16[i]; v1[i] = hh16[8+i]; }
            *(u16x8*)&khi[tok * 72 + koff] = v0;
            *(u16x8*)&khi[tok * 72 + koff + 8] = v1;
        }
        __syncthreads();
        int rowA = (wave * 16 + fr) * 72;
        s16x8 A0 = *(const s16x8*)&khi[rowA + quad * 8];
        s16x8 A1 = *(const s16x8*)&khi[rowA + 32 + quad * 8];
        for (int ct = 0; ct < 17; ++ct) {
            const u16* bp = pjh + (ct * 16 + fr) * 64 + quad * 8;
            s16x8 B0 = *(const s16x8*)bp;
            s16x8 B1 = *(const s16x8*)(bp + 32);
            f32x4 t; t[0]=0.f; t[1]=0.f; t[2]=0.f; t[3]=0.f;
            t = __builtin_amdgcn_mfma_f32_16x16x32_bf16(A0, B0, t, 0, 0, 0);
            t = __builtin_amdgcn_mfma_f32_16x16x32_bf16(A1, B1, t, 0, 0, 0);
            if (ct * 16 + fr < MFEAT) {
                #pragma unroll
                for (int r = 0; r < 4; ++r) lm = fmaxf(lm, t[r]);
            }
        }
    }
    #pragma unroll
    for (int off = 32; off; off >>= 1) lm = fmaxf(lm, __shfl_xor(lm, off));
    if (lane == 0) wred[wave] = lm;
    __syncthreads();
    if (tid == 0) {
        float m = fmaxf(fmaxf(wred[0], wred[1]), fmaxf(wred[2], wred[3]));
        atomicMax(kmaxu + bh, f2ord(m));
    }
}

// ---------------- ctx2: K-side features + ctxT accumulate (MFMA) ----------------
// grid (32 bh, 8 seg).  Wave-private kpT slabs: each wave computes dd for its own
// coltile (ct = mc*4+wave), so no barriers inside the mc loop (in-wave DS ordering).
__global__ __launch_bounds__(256) void ctx2_kernel(const float* __restrict__ Km,
    const float* __restrict__ Vm, const u16* __restrict__ pjh, const u16* __restrict__ pjl,
    const unsigned* __restrict__ kmaxu, float* __restrict__ part)
{
    __shared__ __align__(16) u16 khi[32 * 72], klo[32 * 72];
    __shared__ __align__(16) u16 vth[80 * 40], vtl[80 * 40];
    __shared__ __align__(16) u16 kph[4][16 * 40], kpl[4][16 * 40];
    __shared__ float diag[32];
    const int tid = threadIdx.x;
    const int bh = blockIdx.x, seg = blockIdx.y;
    const int b = bh >> 3, hh = bh & 7;
    const int wave = tid >> 6, lane = tid & 63;
    const int fr = lane & 15, quad = lane >> 4;
    const float kmx = ord2f(kmaxu[bh]);
    for (int i = tid; i < 16 * 40; i += 256) {
        int row = 64 + i / 40, col = i - (i / 40) * 40;
        vth[row * 40 + col] = (row == 64) ? (u16)0x3F80 : (u16)0;
        vtl[row * 40 + col] = 0;
    }
    f32x4 accv[5][5];
    #pragma unroll
    for (int i = 0; i < 5; ++i)
        #pragma unroll
        for (int j = 0; j < 5; ++j) { accv[i][j][0]=0.f; accv[i][j][1]=0.f; accv[i][j][2]=0.f; accv[i][j][3]=0.f; }
    const size_t rowbase = ((size_t)b * NTOK) * CINNER + hh * DHEAD;
    u16* sh = kph[wave];  u16* sl = kpl[wave];
    for (int nc = 0; nc < 16; ++nc) {
        const int n0 = seg * 512 + nc * 32;
        __syncthreads();
        {   // stage k (scaled+split) + diag + vT
            int tok = tid >> 3, koff = (tid & 7) * 8;
            const float* kp = Km + rowbase + (size_t)(n0 + tok) * CINNER + koff;
            float4 f0 = *(const float4*)kp;
            float4 f1 = *(const float4*)(kp + 4);
            float v[8] = {f0.x*DN, f0.y*DN, f0.z*DN, f0.w*DN, f1.x*DN, f1.y*DN, f1.z*DN, f1.w*DN};
            u16x8 hv, lv; float ps = 0.f;
            #pragma unroll
            for (int i = 0; i < 8; ++i) { u16 h, l; split_bf16(v[i], h, l); hv[i]=h; lv[i]=l; ps += v[i]*v[i]; }
            *(u16x8*)&khi[tok * 72 + koff] = hv;
            *(u16x8*)&klo[tok * 72 + koff] = lv;
            ps += __shfl_xor(ps, 1); ps += __shfl_xor(ps, 2); ps += __shfl_xor(ps, 4);
            if ((tid & 7) == 0) diag[tok] = 0.5f * ps;
            const float* vp = Vm + rowbase + (size_t)(n0 + tok) * CINNER + koff;
            float4 g0 = *(const float4*)vp;
            float4 g1 = *(const float4*)(vp + 4);
            float vv[8] = {g0.x, g0.y, g0.z, g0.w, g1.x, g1.y, g1.z, g1.w};
            #pragma unroll
            for (int i = 0; i < 8; ++i) {
                u16 h, l; split_bf16(vv[i], h, l);
                vth[(koff + i) * 40 + tok] = h;
                vtl[(koff + i) * 40 + tok] = l;
            }
        }
        __syncthreads();
        // A-frags for both row tiles (tokens 0-15 and 16-31)
        s16x8 Ah[2][2], Al[2][2];
        #pragma unroll
        for (int rt = 0; rt < 2; ++rt) {
            int rowA = (rt * 16 + fr) * 72;
            Ah[rt][0] = *(const s16x8*)&khi[rowA + quad * 8];
            Ah[rt][1] = *(const s16x8*)&khi[rowA + 32 + quad * 8];
            Al[rt][0] = *(const s16x8*)&klo[rowA + quad * 8];
            Al[rt][1] = *(const s16x8*)&klo[rowA + 32 + quad * 8];
        }
        for (int mc = 0; mc < 5; ++mc) {
            const int ct = mc * 4 + wave;
            const u16* bph = pjh + (ct * 16 + fr) * 64 + quad * 8;
            const u16* bpl = pjl + (ct * 16 + fr) * 64 + quad * 8;
            s16x8 B0h = *(const s16x8*)bph, B1h = *(const s16x8*)(bph + 32);
            s16x8 B0l = *(const s16x8*)bpl, B1l = *(const s16x8*)(bpl + 32);
            const bool valid = (ct * 16 + fr) < MFEAT;
            #pragma unroll
            for (int rt = 0; rt < 2; ++rt) {
                f32x4 dd; dd[0]=0.f; dd[1]=0.f; dd[2]=0.f; dd[3]=0.f;
                dd = __builtin_amdgcn_mfma_f32_16x16x32_bf16(Ah[rt][0], B0h, dd, 0, 0, 0);
                dd = __builtin_amdgcn_mfma_f32_16x16x32_bf16(Ah[rt][0], B0l, dd, 0, 0, 0);
                dd = __builtin_amdgcn_mfma_f32_16x16x32_bf16(Al[rt][0], B0h, dd, 0, 0, 0);
                dd = __builtin_amdgcn_mfma_f32_16x16x32_bf16(Ah[rt][1], B1h, dd, 0, 0, 0);
                dd = __builtin_amdgcn_mfma_f32_16x16x32_bf16(Ah[rt][1], B1l, dd, 0, 0, 0);
                dd = __builtin_amdgcn_mfma_f32_16x16x32_bf16(Al[rt][1], B1h, dd, 0, 0, 0);
                ushort4 ph, pl;
                #pragma unroll
                for (int r = 0; r < 4; ++r) {
                    float dgv = diag[rt * 16 + quad * 4 + r];
                    float val = valid ? RATIO * (expf(dd[r] - dgv - kmx) + 1e-4f) : 0.f;
                    u16 h, l; split_bf16(val, h, l);
                    (&ph.x)[r] = h; (&pl.x)[r] = l;
                }
                *(ushort4*)&sh[fr * 40 + rt * 16 + quad * 4] = ph;
                *(ushort4*)&sl[fr * 40 + rt * 16 + quad * 4] = pl;
            }
            // PV from wave-private slab (no barrier: in-wave DS ordering)
            s16x8 Bh = *(const s16x8*)&sh[fr * 40 + quad * 8];
            s16x8 Bl = *(const s16x8*)&sl[fr * 40 + quad * 8];
            #pragma unroll
            for (int rt2 = 0; rt2 < 5; ++rt2) {
                s16x8 Vh = *(const s16x8*)&vth[(rt2 * 16 + fr) * 40 + quad * 8];
                s16x8 Vl = *(const s16x8*)&vtl[(rt2 * 16 + fr) * 40 + quad * 8];
                accv[rt2][mc] = __builtin_amdgcn_mfma_f32_16x16x32_bf16(Vh, Bh, accv[rt2][mc], 0, 0, 0);
                accv[rt2][mc] = __builtin_amdgcn_mfma_f32_16x16x32_bf16(Vh, Bl, accv[rt2][mc], 0, 0, 0);
                accv[rt2][mc] = __builtin_amdgcn_mfma_f32_16x16x32_bf16(Vl, Bh, accv[rt2][mc], 0, 0, 0);
            }
        }
    }
    float* pb = part + ((size_t)(seg * 32 + bh)) * 80 * 320;
    #pragma unroll
    for (int rt2 = 0; rt2 < 5; ++rt2) {
        #pragma unroll
        for (int mc = 0; mc < 5; ++mc) {
            int ct = mc * 4 + wave;
            #pragma unroll
            for (int r = 0; r < 4; ++r)
                pb[(size_t)(rt2 * 16 + quad * 4 + r) * 320 + ct * 16 + fr] = accv[rt2][mc][r];
        }
    }
}

// ---------------- reduce ctxT partials (8 segs) + split to bf16 ----------------
__global__ __launch_bounds__(256) void ctxt_reduce(const float* __restrict__ part,
    u16* __restrict__ cth, u16* __restrict__ ctl)
{
    int idx = blockIdx.x * 256 + threadIdx.x;   // < 819200
    float s = 0.f;
    #pragma unroll
    for (int sg = 0; sg < 8; ++sg) s += part[(size_t)sg * CTXTN + idx];
    u16 h, l; split_bf16(s, h, l);
    cth[idx] = h; ctl[idx] = l;
}

// ---------------- qside2: Q features + PV + divide (MFMA) ----------------
// grid (64 nt, 32 bh).  64 tokens/block; phase-2 slab is wave-private (no barriers).
__global__ __launch_bounds__(256) void qside2_kernel(const float* __restrict__ Qm,
    const u16* __restrict__ pjh, const u16* __restrict__ pjl,
    const u16* __restrict__ cth, const u16* __restrict__ ctl,
    float* __restrict__ attn_out)
{
    __shared__ __align__(16) u16 qhi[64 * 72], qlo[64 * 72];
    __shared__ __align__(16) u16 slabh[4][16 * 72], slabl[4][16 * 72];
    __shared__ float diag[64];
    const int tid = threadIdx.x;
    const int nt = blockIdx.x, bh = blockIdx.y;
    const int b = bh >> 3, hh = bh & 7;
    const int wave = tid >> 6, lane = tid & 63;
    const int fr = lane & 15, quad = lane >> 4;
    const int n0 = nt * 64;
    {
        int tok = tid >> 2, koff = (tid & 3) * 16;
        const float* qp = Qm + ((size_t)(b * NTOK + n0 + tok)) * CINNER + hh * DHEAD + koff;
        float v[16]; float ps = 0.f;
        #pragma unroll
        for (int qd = 0; qd < 4; ++qd) {
            float4 f = *(const float4*)(qp + qd * 4);
            v[qd*4+0]=f.x*DN; v[qd*4+1]=f.y*DN; v[qd*4+2]=f.z*DN; v[qd*4+3]=f.w*DN;
        }
        u16x8 h0, l0, h1, l1;
        #pragma unroll
        for (int i = 0; i < 8; ++i) {
            u16 h, l; split_bf16(v[i], h, l); h0[i]=h; l0[i]=l;
            split_bf16(v[8+i], h, l); h1[i]=h; l1[i]=l;
        }
        #pragma unroll
        for (int i = 0; i < 16; ++i) ps += v[i]*v[i];
        *(u16x8*)&qhi[tok * 72 + koff] = h0;  *(u16x8*)&qhi[tok * 72 + koff + 8] = h1;
        *(u16x8*)&qlo[tok * 72 + koff] = l0;  *(u16x8*)&qlo[tok * 72 + koff + 8] = l1;
        ps += __shfl_xor(ps, 1); ps += __shfl_xor(ps, 2);
        if ((tid & 3) == 0) diag[tok] = 0.5f * ps;
    }
    __syncthreads();
    f32x4 dd[20];
    #pragma unroll
    for (int ct = 0; ct < 20; ++ct) { dd[ct][0]=0.f; dd[ct][1]=0.f; dd[ct][2]=0.f; dd[ct][3]=0.f; }
    {
        int rowA = (wave * 16 + fr) * 72;
        s16x8 A0h = *(const s16x8*)&qhi[rowA + quad * 8];
        s16x8 A1h = *(const s16x8*)&qhi[rowA + 32 + quad * 8];
        s16x8 A0l = *(const s16x8*)&qlo[rowA + quad * 8];
        s16x8 A1l = *(const s16x8*)&qlo[rowA + 32 + quad * 8];
        #pragma unroll
        for (int ct = 0; ct < 20; ++ct) {
            const u16* bph = pjh + (ct * 16 + fr) * 64 + quad * 8;
            const u16* bpl = pjl + (ct * 16 + fr) * 64 + quad * 8;
            s16x8 B0h = *(const s16x8*)bph, B1h = *(const s16x8*)(bph + 32);
            s16x8 B0l = *(const s16x8*)bpl, B1l = *(const s16x8*)(bpl + 32);
            dd[ct] = __builtin_amdgcn_mfma_f32_16x16x32_bf16(A0h, B0h, dd[ct], 0, 0, 0);
            dd[ct] = __builtin_amdgcn_mfma_f32_16x16x32_bf16(A0h, B0l, dd[ct], 0, 0, 0);
            dd[ct] = __builtin_amdgcn_mfma_f32_16x16x32_bf16(A0l, B0h, dd[ct], 0, 0, 0);
            dd[ct] = __builtin_amdgcn_mfma_f32_16x16x32_bf16(A1h, B1h, dd[ct], 0, 0, 0);
            dd[ct] = __builtin_amdgcn_mfma_f32_16x16x32_bf16(A1h, B1l, dd[ct], 0, 0, 0);
            dd[ct] = __builtin_amdgcn_mfma_f32_16x16x32_bf16(A1l, B1h, dd[ct], 0, 0, 0);
        }
    }
    float pm[4] = {-1e30f, -1e30f, -1e30f, -1e30f};
    #pragma unroll
    for (int ct = 0; ct < 20; ++ct) {
        if (ct * 16 + fr < MFEAT) {
            #pragma unroll
            for (int r = 0; r < 4; ++r) pm[r] = fmaxf(pm[r], dd[ct][r]);
        }
    }
    #pragma unroll
    for (int r = 0; r < 4; ++r) {
        pm[r] = fmaxf(pm[r], __shfl_xor(pm[r], 1));
        pm[r] = fmaxf(pm[r], __shfl_xor(pm[r], 2));
        pm[r] = fmaxf(pm[r], __shfl_xor(pm[r], 4));
        pm[r] = fmaxf(pm[r], __shfl_xor(pm[r], 8));
    }
    float dg[4];
    #pragma unroll
    for (int r = 0; r < 4; ++r) dg[r] = diag[wave * 16 + quad * 4 + r];
    #pragma unroll
    for (int ct = 0; ct < 20; ++ct) {
        bool valid = (ct * 16 + fr) < MFEAT;
        #pragma unroll
        for (int r = 0; r < 4; ++r)
            dd[ct][r] = valid ? RATIO * (expf(dd[ct][r] - dg[r] - pm[r]) + 1e-4f) : 0.f;
    }
    f32x4 acc[5];
    #pragma unroll
    for (int dt = 0; dt < 5; ++dt) { acc[dt][0]=0.f; acc[dt][1]=0.f; acc[dt][2]=0.f; acc[dt][3]=0.f; }
    u16* sh = slabh[wave];  u16* sl = slabl[wave];
    for (int mc = 0; mc < 5; ++mc) {
        #pragma unroll
        for (int c = 0; c < 4; ++c) {
            int ct = mc * 4 + c;
            #pragma unroll
            for (int r = 0; r < 4; ++r) {
                u16 h, l; split_bf16(dd[ct][r], h, l);
                int tok = quad * 4 + r;
                sh[tok * 72 + c * 16 + fr] = h;
                sl[tok * 72 + c * 16 + fr] = l;
            }
        }
        // no barrier: slab is wave-private, in-wave DS ordering suffices
        #pragma unroll
        for (int ks = 0; ks < 2; ++ks) {
            s16x8 Ah = *(const s16x8*)&sh[fr * 72 + ks * 32 + quad * 8];
            s16x8 Al = *(const s16x8*)&sl[fr * 72 + ks * 32 + quad * 8];
            #pragma unroll
            for (int dt = 0; dt < 5; ++dt) {
                const u16* bph = cth + ((size_t)bh * 80 + dt * 16 + fr) * 320 + mc * 64 + ks * 32 + quad * 8;
                const u16* bpl = ctl + ((size_t)bh * 80 + dt * 16 + fr) * 320 + mc * 64 + ks * 32 + quad * 8;
                s16x8 Bh = *(const s16x8*)bph;
                s16x8 Bl = *(const s16x8*)bpl;
                acc[dt] = __builtin_amdgcn_mfma_f32_16x16x32_bf16(Ah, Bh, acc[dt], 0, 0, 0);
                acc[dt] = __builtin_amdgcn_mfma_f32_16x16x32_bf16(Ah, Bl, acc[dt], 0, 0, 0);
                acc[dt] = __builtin_amdgcn_mfma_f32_16x16x32_bf16(Al, Bh, acc[dt], 0, 0, 0);
            }
        }
    }
    #pragma unroll
    for (int r = 0; r < 4; ++r) {
        float denom = __shfl(acc[4][r], lane & 48);
        float inv = 1.0f / denom;
        int token = n0 + wave * 16 + quad * 4 + r;
        float* op = attn_out + ((size_t)(b * NTOK + token)) * CINNER + hh * DHEAD;
        #pragma unroll
        for (int dt = 0; dt < 4; ++dt)
            op[dt * 16 + fr] = acc[dt][r] * inv;
    }
}

// ---------------- group-norm ----------------
__global__ __launch_bounds__(256) void gn_part_kernel(const float* __restrict__ y,
    float2* __restrict__ part)
{
    __shared__ float s_s[256], s_q[256];
    const int tid = threadIdx.x;
    const int sp = blockIdx.x, g = blockIdx.y, b = blockIdx.z;
    int p = sp * 256 + tid;
    const float* base = y + ((size_t)(b * NTOK + p)) * CDIM + g * 24;
    float s = 0.f, q = 0.f;
    #pragma unroll
    for (int i = 0; i < 24; ++i) { float v = base[i]; s += v; q += v * v; }
    s_s[tid] = s; s_q[tid] = q;
    __syncthreads();
    for (int st = 128; st; st >>= 1) {
        if (tid < st) { s_s[tid] += s_s[tid + st]; s_q[tid] += s_q[tid + st]; }
        __syncthreads();
    }
    if (tid == 0) part[(b * 8 + g) * 16 + sp] = make_float2(s_s[0], s_q[0]);
}

__global__ void gn_stat_kernel(const float2* __restrict__ part, float2* __restrict__ stat)
{
    int bg = threadIdx.x;
    if (bg < 32) {
        float s = 0.f, q = 0.f;
        for (int i = 0; i < 16; ++i) { float2 v = part[bg * 16 + i]; s += v.x; q += v.y; }
        float mean = s * (1.0f / 98304.0f);
        float var = q * (1.0f / 98304.0f) - mean * mean;
        stat[bg] = make_float2(mean, rsqrtf(var + 1e-5f));
    }
}

__global__ __launch_bounds__(256) void gn_apply_kernel(const float* __restrict__ y,
    const float2* __restrict__ stat, const float* __restrict__ gg,
    const float* __restrict__ gb, float* __restrict__ out)
{
    __shared__ float tile[64][65];
    const int tid = threadIdx.x;
    const int pt = blockIdx.x, ct = blockIdx.y, b = blockIdx.z;
    const int p0 = pt * 64, c0 = ct * 64;
    #pragma unroll
    for (int r = 0; r < 4; ++r) {
        int id = tid + r * 256;
        int pr = id >> 4, kq = (id & 15) * 4;
        float4 v = *(const float4*)(y + ((size_t)(b * NTOK + p0 + pr)) * CDIM + c0 + kq);
        tile[pr][kq+0] = v.x; tile[pr][kq+1] = v.y; tile[pr][kq+2] = v.z; tile[pr][kq+3] = v.w;
    }
    __syncthreads();
    const int cc = tid >> 6, pp = tid & 63;
    #pragma unroll
    for (int i = 0; i < 16; ++i) {
        int c = c0 + cc * 16 + i;
        int g = c / 24;
        float2 st = stat[b * 8 + g];
        float v = tile[pp][cc * 16 + i];
        out[((size_t)(b * CDIM + c)) * NTOK + p0 + pp] = (v - st.x) * st.y * gg[c] + gb[c];
    }
}

// ---------------- grouped circular conv + gelu ----------------
// OX=4 => 16 lanes/row reading contiguous 16B each: <=2-way banks (free).
template<int KS, int CIN, int COUT, int OX, int YS, int OCB>
__global__ __launch_bounds__(256) void circ_conv2(const float* __restrict__ in,
    const float* __restrict__ w, const float* __restrict__ bias,
    float* __restrict__ out, int do_gelu)
{
    constexpr int P   = KS / 2;
    constexpr int ICG = CIN / 8;
    constexpr int OCG = COUT / 8;
    constexpr int TW  = 64 + 2 * P;
    constexpr int TR  = 64 / YS + 2 * P;
    constexpr int RS0 = (TW + 3) & ~3;
    constexpr int RS  = (RS0 % 8 == 0) ? RS0 + 4 : RS0;
    constexpr int TCX = 64 / OX;
    constexpr int RV  = (OX + KS - 1 + 3) & ~3;
    __shared__ __align__(16) float tile[TR * RS];
    const int tid = threadIdx.x;
    const int oc0 = blockIdx.x * OCB;
    const int y0  = blockIdx.y * (64 / YS);
    const int b   = blockIdx.z;
    const int g   = oc0 / OCG;
    const int tx  = tid % TCX, ty = tid / TCX;
    float acc[OCB][OX] = {};
    const float* ip0 = in + ((size_t)(b * CIN + g * ICG)) * 4096;
    #pragma unroll 1
    for (int ic = 0; ic < ICG; ++ic) {
        __syncthreads();
        const float* ip = ip0 + (size_t)ic * 4096;
        for (int idx = tid; idx < TR * TW; idx += 256) {
            int r = idx / TW, c = idx - r * TW;
            int gy = (y0 + r - P) & 63, gx = (c - P) & 63;
            tile[r * RS + c] = ip[gy * 64 + gx];
        }
        __syncthreads();
        const float* wp = w + ((size_t)oc0 * ICG + ic) * (KS * KS);
        #pragma unroll 1
        for (int ky = 0; ky < KS; ++ky) {
            float wreg[OCB][KS];
            #pragma unroll
            for (int oc = 0; oc < OCB; ++oc)
                #pragma unroll
                for (int kx = 0; kx < KS; ++kx)
                    wreg[oc][kx] = wp[(size_t)oc * ICG * KS * KS + ky * KS + kx];
            float rv[RV];
            const float* rp = &tile[(ty + ky) * RS + tx * OX];
            #pragma unroll
            for (int q2 = 0; q2 < RV / 4; ++q2)
                *(float4*)&rv[q2 * 4] = *(const float4*)(rp + q2 * 4);
            #pragma unroll
            for (int kx = 0; kx < KS; ++kx)
                #pragma unroll
                for (int oc = 0; oc < OCB; ++oc)
                    #pragma unroll
                    for (int ox = 0; ox < OX; ++ox)
                        acc[oc][ox] += rv[kx + ox] * wreg[oc][kx];
        }
    }
    const int y = y0 + ty, x = tx * OX;
    #pragma unroll
    for (int oc = 0; oc < OCB; ++oc) {
        float bv = bias[oc0 + oc];
        float vo[OX];
        #pragma unroll
        for (int ox = 0; ox < OX; ++ox) {
            float vv = acc[oc][ox] + bv;
            vo[ox] = do_gelu ? gelu_f(vv) : vv;
        }
        float* op = out + (((size_t)(b * COUT + oc0 + oc) * 64 + y)) * 64 + x;
        #pragma unroll
        for (int q2 = 0; q2 < OX / 4; ++q2)
            *(float4*)(op + q2 * 4) = *(float4*)&vo[q2 * 4];
    }
}

// ---------------- final 1x1 conv ----------------
__global__ __launch_bounds__(256) void conv1_kernel(const float* __restrict__ in,
    const float* __restrict__ w, const float* __restrict__ bias, float* __restrict__ out)
{
    int idx = blockIdx.x * 256 + threadIdx.x;
    int b = idx >> 12, p = idx & 4095;
    float a0 = bias[0], a1 = bias[1], a2 = bias[2];
    const float* ip = in + (size_t)b * 48 * NTOK + p;
    #pragma unroll 8
    for (int ic = 0; ic < 48; ++ic) {
        float v = ip[(size_t)ic * NTOK];
        a0 += v * w[ic]; a1 += v * w[48 + ic]; a2 += v * w[96 + ic];
    }
    float* op = out + (size_t)idx * 3;
    op[0] = a0; op[1] = a1; op[2] = a2;
}

// ---------------- host launch ----------------
static inline void gemm_mf(hipStream_t s, const float* A, const u16* Bhi, const u16* Blo,
                           const float* bias, const float* resid, float* C,
                           int M, int N, int K, int epi)
{
    dim3 g((N + 127) / 128, M / 128);
    hipLaunchKernelGGL(gemm_mfma, g, dim3(256), 0, s, A, Bhi, Blo, bias, resid, C, M, N, K, epi);
}

extern "C" void kernel_launch(void* const* d_in, const int* in_sizes, int n_in,
                              void* d_out, int out_size, void* d_ws, size_t ws_size,
                              hipStream_t stream)
{
    (void)in_sizes; (void)n_in; (void)out_size; (void)ws_size;
    const float* x        = (const float*)d_in[0];
    const float* to_in_w  = (const float*)d_in[1];
    const float* to_in_b  = (const float*)d_in[2];
    const float* pos_emb  = (const float*)d_in[3];
    const float* proj     = (const float*)d_in[4];
    const float* sn_attn_g= (const float*)d_in[5];
    const float* wq       = (const float*)d_in[6];
    const float* wk       = (const float*)d_in[7];
    const float* wv       = (const float*)d_in[8];
    const float* wo       = (const float*)d_in[9];
    const float* bo       = (const float*)d_in[10];
    const float* sn_ff_g  = (const float*)d_in[11];
    const float* w1       = (const float*)d_in[12];
    const float* b1       = (const float*)d_in[13];
    const float* w2       = (const float*)d_in[14];
    const float* b2       = (const float*)d_in[15];
    const float* expand_w = (const float*)d_in[16];
    const float* fwd_w    = (const float*)d_in[17];
    const float* dec_lin_w= (const float*)d_in[18];
    const float* dec_lin_b= (const float*)d_in[19];
    const float* gn_g     = (const float*)d_in[20];
    const float* gn_b     = (const float*)d_in[21];
    const float* c9_w     = (const float*)d_in[22];
    const float* c9_b     = (const float*)d_in[23];
    const float* c7_w     = (const float*)d_in[24];
    const float* c7_b     = (const float*)d_in[25];
    const float* c5_w     = (const float*)d_in[26];
    const float* c5_b     = (const float*)d_in[27];
    const float* c1_w     = (const float*)d_in[28];
    const float* c1_b     = (const float*)d_in[29];
    float* out = (float*)d_out;

    float* ws = (float*)d_ws;
    float* h   = ws + OFF_H;
    float* hn  = ws + OFF_HN;
    float* q   = ws + OFF_Q;
    float* k   = ws + OFF_K;
    float* v   = ws + OFF_V;
    float* big = ws + OFF_BIG;
    u16* pjhi = (u16*)(ws + OFF_PJ);
    u16* pjlo = pjhi + 6 * PJL;
    u16* cthi = (u16*)(ws + OFF_CTXT);
    u16* ctlo = cthi + CTXTN;
    unsigned* kmaxu = (unsigned*)(ws + OFF_KMAX);
    float2* gnp = (float2*)(ws + OFF_GNP);
    float2* gns = (float2*)(ws + OFF_GNS);
    u16* whi = (u16*)(ws + OFF_WHI);
    u16* wlo = (u16*)(ws + OFF_WLO);

    // prologue
    hipLaunchKernelGGL(input_embed, dim3(BNTOK * CDIM / 256), dim3(256), 0, stream,
                       x, to_in_w, to_in_b, pos_emb, h);
    hipLaunchKernelGGL(kmax_init, dim3(1), dim3(256), 0, stream, kmaxu);
    hipLaunchKernelGGL(cvt_qkv, dim3(6912), dim3(256), 0, stream, wq, wk, wv,
                       whi + WOFF_QKV, wlo + WOFF_QKV);
    hipLaunchKernelGGL(cvt_w, dim3(2304), dim3(256), 0, stream, wo, whi + WOFF_WO, wlo + WOFF_WO, 589824);
    hipLaunchKernelGGL(cvt_w, dim3(3456), dim3(256), 0, stream, w1, whi + WOFF_W1, wlo + WOFF_W1, 884736);
    hipLaunchKernelGGL(cvt_w, dim3(3456), dim3(256), 0, stream, w2, whi + WOFF_W2, wlo + WOFF_W2, 884736);
    hipLaunchKernelGGL(cvt_dec, dim3(432), dim3(256), 0, stream, expand_w, fwd_w, dec_lin_w,
                       whi + WOFF_EXP, wlo + WOFF_EXP);
    hipLaunchKernelGGL(cvt_pj, dim3(480), dim3(256), 0, stream, proj, pjhi, pjlo);

    for (int l = 0; l < NDEPTH; ++l) {
        const float* bo_l = bo + (size_t)l * CDIM;
        const float* b1_l = b1 + (size_t)l * CFF;
        const float* b2_l = b2 + (size_t)l * CDIM;
        const u16* pjh_l = pjhi + (size_t)l * PJL;
        const u16* pjl_l = pjlo + (size_t)l * PJL;
        unsigned* kmax_l = kmaxu + l * 32;

        // attn
        hipLaunchKernelGGL(scalenorm_kernel, dim3(BNTOK / 4), dim3(256), 0, stream, h, hn, sn_attn_g, l);
        gemm_mf(stream, hn, whi + WOFF_QKV + (size_t)l * 294912, wlo + WOFF_QKV + (size_t)l * 294912,
                nullptr, nullptr, q, BNTOK, 1536, CDIM, 8);
        hipLaunchKernelGGL(kmax2_kernel, dim3(16, 32), dim3(256), 0, stream, k, pjh_l, kmax_l);
        hipLaunchKernelGGL(ctx2_kernel, dim3(32, 8), dim3(256), 0, stream, k, v, pjh_l, pjl_l, kmax_l, big);
        hipLaunchKernelGGL(ctxt_reduce, dim3(CTXTN / 256), dim3(256), 0, stream, big, cthi, ctlo);
        hipLaunchKernelGGL(qside2_kernel, dim3(64, 32), dim3(256), 0, stream, q, pjh_l, pjl_l, cthi, ctlo, k);
        gemm_mf(stream, k, whi + WOFF_WO + (size_t)l * 98304, wlo + WOFF_WO + (size_t)l * 98304,
                bo_l, h, h, BNTOK, CDIM, CINNER, 1 | 4);

        // ff
        hipLaunchKernelGGL(scalenorm_kernel, dim3(BNTOK / 4), dim3(256), 0, stream, h, hn, sn_ff_g, l);
        gemm_mf(stream, hn, whi + WOFF_W1 + (size_t)l * 147456, wlo + WOFF_W1 + (size_t)l * 147456,
                b1_l, nullptr, big, BNTOK, CFF, CDIM, 1 | 2);
        gemm_mf(stream, big, whi + WOFF_W2 + (size_t)l * 147456, wlo + WOFF_W2 + (size_t)l * 147456,
                b2_l, h, h, BNTOK, CDIM, CFF, 1 | 4);
    }

    // decoder linears
    gemm_mf(stream, h, whi + WOFF_EXP, wlo + WOFF_EXP, nullptr, nullptr, hn, BNTOK, CDIM, CDIM, 0);
    gemm_mf(stream, hn, whi + WOFF_FWD, wlo + WOFF_FWD, nullptr, nullptr, h, BNTOK, CDIM, CDIM, 0);
    gemm_mf(stream, h, whi + WOFF_DEC, wlo + WOFF_DEC, dec_lin_b, nullptr, hn, BNTOK, CDIM, CDIM, 1);

    // group norm + transpose to NCHW
    float* y0 = big;
    float* y1 = big + 3145728;
    float* y2 = big + 6291456;
    float* y3 = big + 7864320;
    hipLaunchKernelGGL(gn_part_kernel, dim3(16, 8, 4), dim3(256), 0, stream, hn, gnp);
    hipLaunchKernelGGL(gn_stat_kernel, dim3(1), dim3(32), 0, stream, gnp, gns);
    hipLaunchKernelGGL(gn_apply_kernel, dim3(64, 3, 4), dim3(256), 0, stream, hn, gns, gn_g, gn_b, y0);

    // convs (OX=4 bank-conflict-free variants)
    hipLaunchKernelGGL((circ_conv2<9, 192, 192, 4, 4, 2>), dim3(96, 4, 4), dim3(256), 0, stream,
                       y0, c9_w, c9_b, y1, 1);
    hipLaunchKernelGGL((circ_conv2<7, 192, 96, 4, 4, 2>), dim3(48, 4, 4), dim3(256), 0, stream,
                       y1, c7_w, c7_b, y2, 1);
    hipLaunchKernelGGL((circ_conv2<5, 96, 48, 4, 4, 2>), dim3(24, 4, 4), dim3(256), 0, stream,
                       y2, c5_w, c5_b, y3, 1);
    hipLaunchKernelGGL(conv1_kernel, dim3(BNTOK / 256), dim3(256), 0, stream, y3, c1_w, c1_b, out);
}

// Round 7
// 3612.642 us; speedup vs baseline: 2.0980x; 1.0060x over previous
//
#include <hip/hip_runtime.h>
#include <cmath>

// ---------------- constants ----------------
#define NB      4
#define NTOK    4096
#define BNTOK   16384
#define CDIM    192
#define CINNER  512
#define NHEADS  8
#define DHEAD   64
#define CFF     768
#define MFEAT   266
#define NDEPTH  6

#define DN      0.35355339059327373f   // 64^-0.25
#define RATIO   0.06131393394849658f   // 266^-0.5

typedef unsigned short u16;
typedef __attribute__((ext_vector_type(8))) short s16x8;
typedef __attribute__((ext_vector_type(8))) u16  u16x8;
typedef __attribute__((ext_vector_type(4))) float f32x4;

// workspace offsets (floats)
#define OFF_H    0ull
#define OFF_HN   3145728ull        /* decoder intermediate; first 16K floats double as rownorm scale */
#define OFF_Q    6291456ull
#define OFF_K    14680064ull       /* also attn_inner */
#define OFF_V    23068672ull
#define OFF_BIG  31457280ull       /* ff1 / ctxT partials / decoder NCHW bufs */
#define OFF_PJ   44040192ull       /* u16 pjhi + pjlo = 245760 u16 = 122880 f */
#define OFF_CTXT 44163072ull       /* u16 cthi + ctlo = 1638400 u16 = 819200 f */
#define OFF_KMAX 47368192ull
#define OFF_GNP  47368448ull
#define OFF_GNS  47369472ull
#define OFF_WHI  47370240ull       /* u16[4239360] */
#define OFF_WLO  49489920ull
// weight sub-offsets (u16 units)
#define WOFF_QKV 0ull
#define WOFF_WO  1769472ull
#define WOFF_W1  2359296ull
#define WOFF_W2  3244032ull
#define WOFF_EXP 4128768ull
#define WOFF_FWD 4165632ull
#define WOFF_DEC 4202496ull

#define PJL      20480
#define CTXTN    819200

__device__ __forceinline__ float gelu_f(float x) {
    return 0.5f * x * (1.0f + erff(x * 0.7071067811865476f));
}
__device__ __forceinline__ unsigned f2ord(float f) {
    int i = __float_as_int(f);
    return (i >= 0) ? ((unsigned)i | 0x80000000u) : (unsigned)(~i);
}
__device__ __forceinline__ float ord2f(unsigned u) {
    int i = (u & 0x80000000u) ? (int)(u & 0x7fffffffu) : ~(int)u;
    return __int_as_float(i);
}
__device__ __forceinline__ void split_bf16(float a, u16& h, u16& l) {
    unsigned ua = __float_as_uint(a);
    unsigned rh = (ua + 0x7FFFu + ((ua >> 16) & 1u)) >> 16;
    h = (u16)rh;
    float hf = __uint_as_float(rh << 16);
    float lo = a - hf;
    unsigned ul = __float_as_uint(lo);
    unsigned rl = (ul + 0x7FFFu + ((ul >> 16) & 1u)) >> 16;
    l = (u16)rl;
}
__device__ __forceinline__ u16 hi_bf16(float a) {
    unsigned ua = __float_as_uint(a);
    return (u16)((ua + 0x7FFFu + ((ua >> 16) & 1u)) >> 16);
}

// ---------------- weight conversion ----------------
__global__ __launch_bounds__(256) void cvt_qkv(const float* __restrict__ wq,
    const float* __restrict__ wk, const float* __restrict__ wv,
    u16* __restrict__ hi, u16* __restrict__ lo)
{
    int idx = blockIdx.x * 256 + threadIdx.x;
    int l = idx / 294912, rem = idx - l * 294912;
    int r = rem / 192, c = rem - r * 192;
    float v;
    if (r < 512)       v = wq[((size_t)l * 512 + r) * 192 + c];
    else if (r < 1024) v = wk[((size_t)l * 512 + (r - 512)) * 192 + c];
    else               v = wv[((size_t)l * 512 + (r - 1024)) * 192 + c];
    u16 h, lw; split_bf16(v, h, lw);
    hi[idx] = h; lo[idx] = lw;
}

__global__ __launch_bounds__(256) void cvt_w(const float* __restrict__ src,
    u16* __restrict__ hi, u16* __restrict__ lo, int n)
{
    int idx = blockIdx.x * 256 + threadIdx.x;
    if (idx < n) {
        u16 h, l; split_bf16(src[idx], h, l);
        hi[idx] = h; lo[idx] = l;
    }
}

__global__ __launch_bounds__(256) void cvt_dec(const float* __restrict__ e,
    const float* __restrict__ f, const float* __restrict__ d,
    u16* __restrict__ hi, u16* __restrict__ lo)
{
    int idx = blockIdx.x * 256 + threadIdx.x;
    if (idx >= 110592) return;
    int which = idx / 36864, rem = idx - which * 36864;
    float v = (which == 0) ? e[rem] : (which == 1) ? f[rem] : d[rem];
    u16 h, l; split_bf16(v, h, l);
    hi[idx] = h; lo[idx] = l;
}

__global__ __launch_bounds__(256) void cvt_pj(const float* __restrict__ proj,
    u16* __restrict__ hi, u16* __restrict__ lo)
{
    int idx = blockIdx.x * 256 + threadIdx.x;
    int l = idx / PJL, rem = idx - l * PJL;
    int m = rem >> 6, k = rem & 63;
    float v = (m < MFEAT) ? proj[(size_t)l * MFEAT * DHEAD + m * 64 + k] : 0.f;
    u16 h, lw; split_bf16(v, h, lw);
    hi[idx] = h; lo[idx] = lw;
}

// ---------------- input embed ----------------
__global__ __launch_bounds__(256) void input_embed(const float* __restrict__ x,
    const float* __restrict__ w, const float* __restrict__ bvec,
    const float* __restrict__ pos, float* __restrict__ h)
{
    int idx = blockIdx.x * 256 + threadIdx.x;
    int row = idx / CDIM, c = idx - row * CDIM;
    int p = row & (NTOK - 1);
    const float* xr = x + (size_t)row * 3;
    h[idx] = xr[0]*w[c*3+0] + xr[1]*w[c*3+1] + xr[2]*w[c*3+2] + bvec[c] + pos[(size_t)p*CDIM + c];
}

// ---------------- rownorm: per-row scalenorm scale only ----------------
__global__ __launch_bounds__(256) void rownorm_kernel(const float* __restrict__ in,
    float* __restrict__ sv, const float* __restrict__ gptr, int gidx)
{
    int wv = threadIdx.x >> 6, lane = threadIdx.x & 63;
    int row = blockIdx.x * 4 + wv;
    const float* p = in + (size_t)row * CDIM;
    float x0 = p[lane], x1 = p[lane + 64], x2 = p[lane + 128];
    float ss = x0*x0 + x1*x1 + x2*x2;
    #pragma unroll
    for (int off = 32; off; off >>= 1) ss += __shfl_xor(ss, off);
    if (lane == 0) {
        float g = gptr[gidx];
        float n = sqrtf(ss * (1.0f / 192.0f));
        sv[row] = g / fmaxf(n, 1e-5f);
    }
}

// ---------------- split-bf16 MFMA GEMM (+ optional per-row A scale) ----------------
#define LP 40
__global__ __launch_bounds__(256) void gemm_mfma(const float* __restrict__ A,
    const float* __restrict__ ascale,
    const u16* __restrict__ Bhi, const u16* __restrict__ Blo,
    const float* __restrict__ bias, const float* __restrict__ resid,
    float* __restrict__ C, int M, int N, int K, int epi)
{
    __shared__ u16 a_hi[128 * LP], a_lo[128 * LP], b_hi[128 * LP], b_lo[128 * LP];
    const int tid = threadIdx.x;
    const int n0 = blockIdx.x * 128, m0 = blockIdx.y * 128;
    const int wave = tid >> 6, lane = tid & 63;
    const int wr = wave >> 1, wc = wave & 1;
    const int fr = lane & 15, q = lane >> 4;
    const bool wactive = (n0 + wc * 64) < N;
    f32x4 acc[4][4];
    #pragma unroll
    for (int i = 0; i < 4; ++i)
        #pragma unroll
        for (int j = 0; j < 4; ++j) { acc[i][j][0]=0.f; acc[i][j][1]=0.f; acc[i][j][2]=0.f; acc[i][j][3]=0.f; }

    const int srow = tid >> 1, sc0 = (tid & 1) * 16;
    const float* aptr = A + (size_t)(m0 + srow) * K + sc0;
    const float as = ascale ? ascale[m0 + srow] : 1.0f;
    const bool bval = (n0 + srow) < N;
    const u16* bhp = Bhi + (size_t)(n0 + srow) * K + sc0;
    const u16* blp = Blo + (size_t)(n0 + srow) * K + sc0;
    const int soff = srow * LP + sc0;
    const int aoffb = (wr * 64 + fr) * LP + q * 8;
    const int boffb = (wc * 64 + fr) * LP + q * 8;

    for (int kc = 0; kc < K; kc += 32) {
        float4 f0 = *(const float4*)(aptr + kc);
        float4 f1 = *(const float4*)(aptr + kc + 4);
        float4 f2 = *(const float4*)(aptr + kc + 8);
        float4 f3 = *(const float4*)(aptr + kc + 12);
        u16x8 h0, l0, h1, l1;
        {
            float v[16] = {f0.x,f0.y,f0.z,f0.w, f1.x,f1.y,f1.z,f1.w,
                           f2.x,f2.y,f2.z,f2.w, f3.x,f3.y,f3.z,f3.w};
            u16 hh[16], ll[16];
            #pragma unroll
            for (int i = 0; i < 16; ++i) { float sv = v[i] * as; split_bf16(sv, hh[i], ll[i]); }
            #pragma unroll
            for (int i = 0; i < 8; ++i) { h0[i]=hh[i]; l0[i]=ll[i]; h1[i]=hh[8+i]; l1[i]=ll[8+i]; }
        }
        *(u16x8*)&a_hi[soff]     = h0;  *(u16x8*)&a_hi[soff + 8] = h1;
        *(u16x8*)&a_lo[soff]     = l0;  *(u16x8*)&a_lo[soff + 8] = l1;
        u16x8 bh0 = (u16x8)0, bh1 = (u16x8)0, bl0 = (u16x8)0, bl1 = (u16x8)0;
        if (bval) {
            bh0 = *(const u16x8*)(bhp + kc);  bh1 = *(const u16x8*)(bhp + kc + 8);
            bl0 = *(const u16x8*)(blp + kc);  bl1 = *(const u16x8*)(blp + kc + 8);
        }
        *(u16x8*)&b_hi[soff]     = bh0;  *(u16x8*)&b_hi[soff + 8] = bh1;
        *(u16x8*)&b_lo[soff]     = bl0;  *(u16x8*)&b_lo[soff + 8] = bl1;
        __syncthreads();
        if (wactive) {
            s16x8 Ah[4], Al[4], Bh[4], Bl[4];
            #pragma unroll
            for (int t = 0; t < 4; ++t) {
                Ah[t] = *(const s16x8*)&a_hi[aoffb + t * 16 * LP];
                Al[t] = *(const s16x8*)&a_lo[aoffb + t * 16 * LP];
                Bh[t] = *(const s16x8*)&b_hi[boffb + t * 16 * LP];
                Bl[t] = *(const s16x8*)&b_lo[boffb + t * 16 * LP];
            }
            #pragma unroll
            for (int i = 0; i < 4; ++i)
                #pragma unroll
                for (int j = 0; j < 4; ++j)
                    acc[i][j] = __builtin_amdgcn_mfma_f32_16x16x32_bf16(Ah[i], Bh[j], acc[i][j], 0, 0, 0);
            #pragma unroll
            for (int i = 0; i < 4; ++i)
                #pragma unroll
                for (int j = 0; j < 4; ++j)
                    acc[i][j] = __builtin_amdgcn_mfma_f32_16x16x32_bf16(Ah[i], Bl[j], acc[i][j], 0, 0, 0);
            #pragma unroll
            for (int i = 0; i < 4; ++i)
                #pragma unroll
                for (int j = 0; j < 4; ++j)
                    acc[i][j] = __builtin_amdgcn_mfma_f32_16x16x32_bf16(Al[i], Bh[j], acc[i][j], 0, 0, 0);
        }
        __syncthreads();
    }
    const int c0 = n0 + wc * 64;
    const int rowb = m0 + wr * 64;
    #pragma unroll
    for (int j = 0; j < 4; ++j) {
        int c = c0 + j * 16 + fr;
        if (c >= N) continue;
        float bb = (epi & 1) ? bias[c] : 0.f;
        float* cp;
        if (epi & 8) cp = C + (size_t)(c >> 9) * 8388608ull + (size_t)(c & 511);
        else         cp = C + c;
        const float* rp = (epi & 4) ? (resid + c) : nullptr;
        #pragma unroll
        for (int i = 0; i < 4; ++i) {
            #pragma unroll
            for (int r = 0; r < 4; ++r) {
                int row = rowb + i * 16 + q * 4 + r;
                float val = acc[i][j][r] + bb;
                if (epi & 2) val = gelu_f(val);
                if (epi & 4) val += rp[(size_t)row * N];
                size_t off = (epi & 8) ? (size_t)row * 512 : (size_t)row * N;
                cp[off] = val;
            }
        }
    }
}

// ---------------- kmax init ----------------
__global__ void kmax_init(unsigned* kmaxu) {
    if (threadIdx.x < NDEPTH * 32) kmaxu[threadIdx.x] = 0u;
}

// ---------------- kmax2 ----------------
__global__ __launch_bounds__(256) void kmax2_kernel(const float* __restrict__ Km,
    const u16* __restrict__ pjh, unsigned* __restrict__ kmaxu)
{
    __shared__ __align__(16) u16 khi[64 * 72];
    __shared__ float wred[4];
    const int tid = threadIdx.x;
    const int nt = blockIdx.x, bh = blockIdx.y;
    const int b = bh >> 3, hh = bh & 7;
    const int wave = tid >> 6, lane = tid & 63;
    const int fr = lane & 15, quad = lane >> 4;
    float lm = -1e30f;
    const size_t kbase = ((size_t)b * NTOK) * CINNER + hh * DHEAD;
    for (int ch = 0; ch < 4; ++ch) {
        const int n0 = nt * 256 + ch * 64;
        __syncthreads();
        {
            int tok = tid >> 2, koff = (tid & 3) * 16;
            const float* kp = Km + kbase + (size_t)(n0 + tok) * CINNER + koff;
            u16 hh16[16];
            #pragma unroll
            for (int qd = 0; qd < 4; ++qd) {
                float4 f = *(const float4*)(kp + qd * 4);
                hh16[qd*4+0] = hi_bf16(f.x * DN); hh16[qd*4+1] = hi_bf16(f.y * DN);
                hh16[qd*4+2] = hi_bf16(f.z * DN); hh16[qd*4+3] = hi_bf16(f.w * DN);
            }
            u16x8 v0, v1;
            #pragma unroll
            for (int i = 0; i < 8; ++i) { v0[i] = hh16[i]; v1[i] = hh16[8+i]; }
            *(u16x8*)&khi[tok * 72 + koff] = v0;
            *(u16x8*)&khi[tok * 72 + koff + 8] = v1;
        }
        __syncthreads();
        int rowA = (wave * 16 + fr) * 72;
        s16x8 A0 = *(const s16x8*)&khi[rowA + quad * 8];
        s16x8 A1 = *(const s16x8*)&khi[rowA + 32 + quad * 8];
        for (int ct = 0; ct < 17; ++ct) {
            const u16* bp = pjh + (ct * 16 + fr) * 64 + quad * 8;
            s16x8 B0 = *(const s16x8*)bp;
            s16x8 B1 = *(const s16x8*)(bp + 32);
            f32x4 t; t[0]=0.f; t[1]=0.f; t[2]=0.f; t[3]=0.f;
            t = __builtin_amdgcn_mfma_f32_16x16x32_bf16(A0, B0, t, 0, 0, 0);
            t = __builtin_amdgcn_mfma_f32_16x16x32_bf16(A1, B1, t, 0, 0, 0);
            if (ct * 16 + fr < MFEAT) {
                #pragma unroll
                for (int r = 0; r < 4; ++r) lm = fmaxf(lm, t[r]);
            }
        }
    }
    #pragma unroll
    for (int off = 32; off; off >>= 1) lm = fmaxf(lm, __shfl_xor(lm, off));
    if (lane == 0) wred[wave] = lm;
    __syncthreads();
    if (tid == 0) {
        float m = fmaxf(fmaxf(wred[0], wred[1]), fmaxf(wred[2], wred[3]));
        atomicMax(kmaxu + bh, f2ord(m));
    }
}

// ---------------- ctx2 ----------------
__global__ __launch_bounds__(256) void ctx2_kernel(const float* __restrict__ Km,
    const float* __restrict__ Vm, const u16* __restrict__ pjh, const u16* __restrict__ pjl,
    const unsigned* __restrict__ kmaxu, float* __restrict__ part)
{
    __shared__ __align__(16) u16 khi[32 * 72], klo[32 * 72];
    __shared__ __align__(16) u16 vth[80 * 40], vtl[80 * 40];
    __shared__ __align__(16) u16 kph[4][16 * 40], kpl[4][16 * 40];
    __shared__ float diag[32];
    const int tid = threadIdx.x;
    const int bh = blockIdx.x, seg = blockIdx.y;
    const int b = bh >> 3, hh = bh & 7;
    const int wave = tid >> 6, lane = tid & 63;
    const int fr = lane & 15, quad = lane >> 4;
    const float kmx = ord2f(kmaxu[bh]);
    for (int i = tid; i < 16 * 40; i += 256) {
        int row = 64 + i / 40, col = i - (i / 40) * 40;
        vth[row * 40 + col] = (row == 64) ? (u16)0x3F80 : (u16)0;
        vtl[row * 40 + col] = 0;
    }
    f32x4 accv[5][5];
    #pragma unroll
    for (int i = 0; i < 5; ++i)
        #pragma unroll
        for (int j = 0; j < 5; ++j) { accv[i][j][0]=0.f; accv[i][j][1]=0.f; accv[i][j][2]=0.f; accv[i][j][3]=0.f; }
    const size_t rowbase = ((size_t)b * NTOK) * CINNER + hh * DHEAD;
    u16* sh = kph[wave];  u16* sl = kpl[wave];
    for (int nc = 0; nc < 16; ++nc) {
        const int n0 = seg * 512 + nc * 32;
        __syncthreads();
        {
            int tok = tid >> 3, koff = (tid & 7) * 8;
            const float* kp = Km + rowbase + (size_t)(n0 + tok) * CINNER + koff;
            float4 f0 = *(const float4*)kp;
            float4 f1 = *(const float4*)(kp + 4);
            float v[8] = {f0.x*DN, f0.y*DN, f0.z*DN, f0.w*DN, f1.x*DN, f1.y*DN, f1.z*DN, f1.w*DN};
            u16x8 hv, lv; float ps = 0.f;
            #pragma unroll
            for (int i = 0; i < 8; ++i) { u16 h, l; split_bf16(v[i], h, l); hv[i]=h; lv[i]=l; ps += v[i]*v[i]; }
            *(u16x8*)&khi[tok * 72 + koff] = hv;
            *(u16x8*)&klo[tok * 72 + koff] = lv;
            ps += __shfl_xor(ps, 1); ps += __shfl_xor(ps, 2); ps += __shfl_xor(ps, 4);
            if ((tid & 7) == 0) diag[tok] = 0.5f * ps;
            const float* vp = Vm + rowbase + (size_t)(n0 + tok) * CINNER + koff;
            float4 g0 = *(const float4*)vp;
            float4 g1 = *(const float4*)(vp + 4);
            float vv[8] = {g0.x, g0.y, g0.z, g0.w, g1.x, g1.y, g1.z, g1.w};
            #pragma unroll
            for (int i = 0; i < 8; ++i) {
                u16 h, l; split_bf16(vv[i], h, l);
                vth[(koff + i) * 40 + tok] = h;
                vtl[(koff + i) * 40 + tok] = l;
            }
        }
        __syncthreads();
        s16x8 Ah[2][2], Al[2][2];
        #pragma unroll
        for (int rt = 0; rt < 2; ++rt) {
            int rowA = (rt * 16 + fr) * 72;
            Ah[rt][0] = *(const s16x8*)&khi[rowA + quad * 8];
            Ah[rt][1] = *(const s16x8*)&khi[rowA + 32 + quad * 8];
            Al[rt][0] = *(const s16x8*)&klo[rowA + quad * 8];
            Al[rt][1] = *(const s16x8*)&klo[rowA + 32 + quad * 8];
        }
        for (int mc = 0; mc < 5; ++mc) {
            const int ct = mc * 4 + wave;
            const u16* bph = pjh + (ct * 16 + fr) * 64 + quad * 8;
            const u16* bpl = pjl + (ct * 16 + fr) * 64 + quad * 8;
            s16x8 B0h = *(const s16x8*)bph, B1h = *(const s16x8*)(bph + 32);
            s16x8 B0l = *(const s16x8*)bpl, B1l = *(const s16x8*)(bpl + 32);
            const bool valid = (ct * 16 + fr) < MFEAT;
            #pragma unroll
            for (int rt = 0; rt < 2; ++rt) {
                f32x4 dd; dd[0]=0.f; dd[1]=0.f; dd[2]=0.f; dd[3]=0.f;
                dd = __builtin_amdgcn_mfma_f32_16x16x32_bf16(Ah[rt][0], B0h, dd, 0, 0, 0);
                dd = __builtin_amdgcn_mfma_f32_16x16x32_bf16(Ah[rt][0], B0l, dd, 0, 0, 0);
                dd = __builtin_amdgcn_mfma_f32_16x16x32_bf16(Al[rt][0], B0h, dd, 0, 0, 0);
                dd = __builtin_amdgcn_mfma_f32_16x16x32_bf16(Ah[rt][1], B1h, dd, 0, 0, 0);
                dd = __builtin_amdgcn_mfma_f32_16x16x32_bf16(Ah[rt][1], B1l, dd, 0, 0, 0);
                dd = __builtin_amdgcn_mfma_f32_16x16x32_bf16(Al[rt][1], B1h, dd, 0, 0, 0);
                ushort4 ph, pl;
                #pragma unroll
                for (int r = 0; r < 4; ++r) {
                    float dgv = diag[rt * 16 + quad * 4 + r];
                    float val = valid ? RATIO * (expf(dd[r] - dgv - kmx) + 1e-4f) : 0.f;
                    u16 h, l; split_bf16(val, h, l);
                    (&ph.x)[r] = h; (&pl.x)[r] = l;
                }
                *(ushort4*)&sh[fr * 40 + rt * 16 + quad * 4] = ph;
                *(ushort4*)&sl[fr * 40 + rt * 16 + quad * 4] = pl;
            }
            s16x8 Bh = *(const s16x8*)&sh[fr * 40 + quad * 8];
            s16x8 Bl = *(const s16x8*)&sl[fr * 40 + quad * 8];
            #pragma unroll
            for (int rt2 = 0; rt2 < 5; ++rt2) {
                s16x8 Vh = *(const s16x8*)&vth[(rt2 * 16 + fr) * 40 + quad * 8];
                s16x8 Vl = *(const s16x8*)&vtl[(rt2 * 16 + fr) * 40 + quad * 8];
                accv[rt2][mc] = __builtin_amdgcn_mfma_f32_16x16x32_bf16(Vh, Bh, accv[rt2][mc], 0, 0, 0);
                accv[rt2][mc] = __builtin_amdgcn_mfma_f32_16x16x32_bf16(Vh, Bl, accv[rt2][mc], 0, 0, 0);
                accv[rt2][mc] = __builtin_amdgcn_mfma_f32_16x16x32_bf16(Vl, Bh, accv[rt2][mc], 0, 0, 0);
            }
        }
    }
    float* pb = part + ((size_t)(seg * 32 + bh)) * 80 * 320;
    #pragma unroll
    for (int rt2 = 0; rt2 < 5; ++rt2) {
        #pragma unroll
        for (int mc = 0; mc < 5; ++mc) {
            int ct = mc * 4 + wave;
            #pragma unroll
            for (int r = 0; r < 4; ++r)
                pb[(size_t)(rt2 * 16 + quad * 4 + r) * 320 + ct * 16 + fr] = accv[rt2][mc][r];
        }
    }
}

// ---------------- reduce ctxT partials ----------------
__global__ __launch_bounds__(256) void ctxt_reduce(const float* __restrict__ part,
    u16* __restrict__ cth, u16* __restrict__ ctl)
{
    int idx = blockIdx.x * 256 + threadIdx.x;
    float s = 0.f;
    #pragma unroll
    for (int sg = 0; sg < 8; ++sg) s += part[(size_t)sg * CTXTN + idx];
    u16 h, l; split_bf16(s, h, l);
    cth[idx] = h; ctl[idx] = l;
}

// ---------------- qside2 ----------------
__global__ __launch_bounds__(256) void qside2_kernel(const float* __restrict__ Qm,
    const u16* __restrict__ pjh, const u16* __restrict__ pjl,
    const u16* __restrict__ cth, const u16* __restrict__ ctl,
    float* __restrict__ attn_out)
{
    __shared__ __align__(16) u16 qhi[64 * 72], qlo[64 * 72];
    __shared__ __align__(16) u16 slabh[4][16 * 72], slabl[4][16 * 72];
    __shared__ float diag[64];
    const int tid = threadIdx.x;
    const int nt = blockIdx.x, bh = blockIdx.y;
    const int b = bh >> 3, hh = bh & 7;
    const int wave = tid >> 6, lane = tid & 63;
    const int fr = lane & 15, quad = lane >> 4;
    const int n0 = nt * 64;
    {
        int tok = tid >> 2, koff = (tid & 3) * 16;
        const float* qp = Qm + ((size_t)(b * NTOK + n0 + tok)) * CINNER + hh * DHEAD + koff;
        float v[16]; float ps = 0.f;
        #pragma unroll
        for (int qd = 0; qd < 4; ++qd) {
            float4 f = *(const float4*)(qp + qd * 4);
            v[qd*4+0]=f.x*DN; v[qd*4+1]=f.y*DN; v[qd*4+2]=f.z*DN; v[qd*4+3]=f.w*DN;
        }
        u16x8 h0, l0, h1, l1;
        #pragma unroll
        for (int i = 0; i < 8; ++i) {
            u16 h, l; split_bf16(v[i], h, l); h0[i]=h; l0[i]=l;
            split_bf16(v[8+i], h, l); h1[i]=h; l1[i]=l;
        }
        #pragma unroll
        for (int i = 0; i < 16; ++i) ps += v[i]*v[i];
        *(u16x8*)&qhi[tok * 72 + koff] = h0;  *(u16x8*)&qhi[tok * 72 + koff + 8] = h1;
        *(u16x8*)&qlo[tok * 72 + koff] = l0;  *(u16x8*)&qlo[tok * 72 + koff + 8] = l1;
        ps += __shfl_xor(ps, 1); ps += __shfl_xor(ps, 2);
        if ((tid & 3) == 0) diag[tok] = 0.5f * ps;
    }
    __syncthreads();
    f32x4 dd[20];
    #pragma unroll
    for (int ct = 0; ct < 20; ++ct) { dd[ct][0]=0.f; dd[ct][1]=0.f; dd[ct][2]=0.f; dd[ct][3]=0.f; }
    {
        int rowA = (wave * 16 + fr) * 72;
        s16x8 A0h = *(const s16x8*)&qhi[rowA + quad * 8];
        s16x8 A1h = *(const s16x8*)&qhi[rowA + 32 + quad * 8];
        s16x8 A0l = *(const s16x8*)&qlo[rowA + quad * 8];
        s16x8 A1l = *(const s16x8*)&qlo[rowA + 32 + quad * 8];
        #pragma unroll
        for (int ct = 0; ct < 20; ++ct) {
            const u16* bph = pjh + (ct * 16 + fr) * 64 + quad * 8;
            const u16* bpl = pjl + (ct * 16 + fr) * 64 + quad * 8;
            s16x8 B0h = *(const s16x8*)bph, B1h = *(const s16x8*)(bph + 32);
            s16x8 B0l = *(const s16x8*)bpl, B1l = *(const s16x8*)(bpl + 32);
            dd[ct] = __builtin_amdgcn_mfma_f32_16x16x32_bf16(A0h, B0h, dd[ct], 0, 0, 0);
            dd[ct] = __builtin_amdgcn_mfma_f32_16x16x32_bf16(A0h, B0l, dd[ct], 0, 0, 0);
            dd[ct] = __builtin_amdgcn_mfma_f32_16x16x32_bf16(A0l, B0h, dd[ct], 0, 0, 0);
            dd[ct] = __builtin_amdgcn_mfma_f32_16x16x32_bf16(A1h, B1h, dd[ct], 0, 0, 0);
            dd[ct] = __builtin_amdgcn_mfma_f32_16x16x32_bf16(A1h, B1l, dd[ct], 0, 0, 0);
            dd[ct] = __builtin_amdgcn_mfma_f32_16x16x32_bf16(A1l, B1h, dd[ct], 0, 0, 0);
        }
    }
    float pm[4] = {-1e30f, -1e30f, -1e30f, -1e30f};
    #pragma unroll
    for (int ct = 0; ct < 20; ++ct) {
        if (ct * 16 + fr < MFEAT) {
            #pragma unroll
            for (int r = 0; r < 4; ++r) pm[r] = fmaxf(pm[r], dd[ct][r]);
        }
    }
    #pragma unroll
    for (int r = 0; r < 4; ++r) {
        pm[r] = fmaxf(pm[r], __shfl_xor(pm[r], 1));
        pm[r] = fmaxf(pm[r], __shfl_xor(pm[r], 2));
        pm[r] = fmaxf(pm[r], __shfl_xor(pm[r], 4));
        pm[r] = fmaxf(pm[r], __shfl_xor(pm[r], 8));
    }
    float dg[4];
    #pragma unroll
    for (int r = 0; r < 4; ++r) dg[r] = diag[wave * 16 + quad * 4 + r];
    #pragma unroll
    for (int ct = 0; ct < 20; ++ct) {
        bool valid = (ct * 16 + fr) < MFEAT;
        #pragma unroll
        for (int r = 0; r < 4; ++r)
            dd[ct][r] = valid ? RATIO * (expf(dd[ct][r] - dg[r] - pm[r]) + 1e-4f) : 0.f;
    }
    f32x4 acc[5];
    #pragma unroll
    for (int dt = 0; dt < 5; ++dt) { acc[dt][0]=0.f; acc[dt][1]=0.f; acc[dt][2]=0.f; acc[dt][3]=0.f; }
    u16* sh = slabh[wave];  u16* sl = slabl[wave];
    for (int mc = 0; mc < 5; ++mc) {
        #pragma unroll
        for (int c = 0; c < 4; ++c) {
            int ct = mc * 4 + c;
            #pragma unroll
            for (int r = 0; r < 4; ++r) {
                u16 h, l; split_bf16(dd[ct][r], h, l);
                int tok = quad * 4 + r;
                sh[tok * 72 + c * 16 + fr] = h;
                sl[tok * 72 + c * 16 + fr] = l;
            }
        }
        #pragma unroll
        for (int ks = 0; ks < 2; ++ks) {
            s16x8 Ah = *(const s16x8*)&sh[fr * 72 + ks * 32 + quad * 8];
            s16x8 Al = *(const s16x8*)&sl[fr * 72 + ks * 32 + quad * 8];
            #pragma unroll
            for (int dt = 0; dt < 5; ++dt) {
                const u16* bph = cth + ((size_t)bh * 80 + dt * 16 + fr) * 320 + mc * 64 + ks * 32 + quad * 8;
                const u16* bpl = ctl + ((size_t)bh * 80 + dt * 16 + fr) * 320 + mc * 64 + ks * 32 + quad * 8;
                s16x8 Bh = *(const s16x8*)bph;
                s16x8 Bl = *(const s16x8*)bpl;
                acc[dt] = __builtin_amdgcn_mfma_f32_16x16x32_bf16(Ah, Bh, acc[dt], 0, 0, 0);
                acc[dt] = __builtin_amdgcn_mfma_f32_16x16x32_bf16(Ah, Bl, acc[dt], 0, 0, 0);
                acc[dt] = __builtin_amdgcn_mfma_f32_16x16x32_bf16(Al, Bh, acc[dt], 0, 0, 0);
            }
        }
    }
    #pragma unroll
    for (int r = 0; r < 4; ++r) {
        float denom = __shfl(acc[4][r], lane & 48);
        float inv = 1.0f / denom;
        int token = n0 + wave * 16 + quad * 4 + r;
        float* op = attn_out + ((size_t)(b * NTOK + token)) * CINNER + hh * DHEAD;
        #pragma unroll
        for (int dt = 0; dt < 4; ++dt)
            op[dt * 16 + fr] = acc[dt][r] * inv;
    }
}

// ---------------- group-norm ----------------
__global__ __launch_bounds__(256) void gn_part_kernel(const float* __restrict__ y,
    float2* __restrict__ part)
{
    __shared__ float s_s[256], s_q[256];
    const int tid = threadIdx.x;
    const int sp = blockIdx.x, g = blockIdx.y, b = blockIdx.z;
    int p = sp * 256 + tid;
    const float* base = y + ((size_t)(b * NTOK + p)) * CDIM + g * 24;
    float s = 0.f, q = 0.f;
    #pragma unroll
    for (int i = 0; i < 24; ++i) { float v = base[i]; s += v; q += v * v; }
    s_s[tid] = s; s_q[tid] = q;
    __syncthreads();
    for (int st = 128; st; st >>= 1) {
        if (tid < st) { s_s[tid] += s_s[tid + st]; s_q[tid] += s_q[tid + st]; }
        __syncthreads();
    }
    if (tid == 0) part[(b * 8 + g) * 16 + sp] = make_float2(s_s[0], s_q[0]);
}

__global__ void gn_stat_kernel(const float2* __restrict__ part, float2* __restrict__ stat)
{
    int bg = threadIdx.x;
    if (bg < 32) {
        float s = 0.f, q = 0.f;
        for (int i = 0; i < 16; ++i) { float2 v = part[bg * 16 + i]; s += v.x; q += v.y; }
        float mean = s * (1.0f / 98304.0f);
        float var = q * (1.0f / 98304.0f) - mean * mean;
        stat[bg] = make_float2(mean, rsqrtf(var + 1e-5f));
    }
}

__global__ __launch_bounds__(256) void gn_apply_kernel(const float* __restrict__ y,
    const float2* __restrict__ stat, const float* __restrict__ gg,
    const float* __restrict__ gb, float* __restrict__ out)
{
    __shared__ float tile[64][65];
    const int tid = threadIdx.x;
    const int pt = blockIdx.x, ct = blockIdx.y, b = blockIdx.z;
    const int p0 = pt * 64, c0 = ct * 64;
    #pragma unroll
    for (int r = 0; r < 4; ++r) {
        int id = tid + r * 256;
        int pr = id >> 4, kq = (id & 15) * 4;
        float4 v = *(const float4*)(y + ((size_t)(b * NTOK + p0 + pr)) * CDIM + c0 + kq);
        tile[pr][kq+0] = v.x; tile[pr][kq+1] = v.y; tile[pr][kq+2] = v.z; tile[pr][kq+3] = v.w;
    }
    __syncthreads();
    const int cc = tid >> 6, pp = tid & 63;
    #pragma unroll
    for (int i = 0; i < 16; ++i) {
        int c = c0 + cc * 16 + i;
        int g = c / 24;
        float2 st = stat[b * 8 + g];
        float v = tile[pp][cc * 16 + i];
        out[((size_t)(b * CDIM + c)) * NTOK + p0 + pp] = (v - st.x) * st.y * gg[c] + gb[c];
    }
}

// ---------------- grouped circular conv v3 ----------------
// OX=8/YS=2 layout (R5's fast shape), OCB ocs per block, staging addresses
// hoisted out of the ic loop (kills ~250 integer divides/thread of VALU).
template<int KS, int CIN, int COUT, int OX, int YS, int OCB>
__global__ __launch_bounds__(256) void circ_conv3(const float* __restrict__ in,
    const float* __restrict__ w, const float* __restrict__ bias,
    float* __restrict__ out, int do_gelu)
{
    constexpr int P   = KS / 2;
    constexpr int ICG = CIN / 8;
    constexpr int OCG = COUT / 8;
    constexpr int TW  = 64 + 2 * P;
    constexpr int TR  = 64 / YS + 2 * P;
    constexpr int RS0 = (TW + 3) & ~3;
    constexpr int RS  = (RS0 % 8 == 0) ? RS0 + 4 : RS0;
    constexpr int TCX = 64 / OX;
    constexpr int RV  = (OX + KS - 1 + 3) & ~3;
    constexpr int NLD = (TR * TW + 255) / 256;
    __shared__ __align__(16) float tile[TR * RS];
    const int tid = threadIdx.x;
    const int oc0 = blockIdx.x * OCB;
    const int y0  = blockIdx.y * (64 / YS);
    const int b   = blockIdx.z;
    const int g   = oc0 / OCG;
    const int tx  = tid % TCX, ty = tid / TCX;
    // hoisted staging offsets
    int srcs[NLD], dsts[NLD];
    #pragma unroll
    for (int j = 0; j < NLD; ++j) {
        int idx = tid + j * 256;
        if (idx < TR * TW) {
            int r = idx / TW, c = idx - r * TW;
            int gy = (y0 + r - P) & 63, gx = (c - P) & 63;
            srcs[j] = gy * 64 + gx;
            dsts[j] = r * RS + c;
        } else { srcs[j] = 0; dsts[j] = -1; }
    }
    float acc[OCB][OX] = {};
    const float* ip0 = in + ((size_t)(b * CIN + g * ICG)) * 4096;
    #pragma unroll 1
    for (int ic = 0; ic < ICG; ++ic) {
        __syncthreads();
        const float* ip = ip0 + (size_t)ic * 4096;
        #pragma unroll
        for (int j = 0; j < NLD; ++j)
            if (dsts[j] >= 0) tile[dsts[j]] = ip[srcs[j]];
        __syncthreads();
        const float* wp = w + ((size_t)oc0 * ICG + ic) * (KS * KS);
        #pragma unroll 1
        for (int ky = 0; ky < KS; ++ky) {
            float wreg[OCB][KS];
            #pragma unroll
            for (int oc = 0; oc < OCB; ++oc)
                #pragma unroll
                for (int kx = 0; kx < KS; ++kx)
                    wreg[oc][kx] = wp[(size_t)oc * ICG * KS * KS + ky * KS + kx];
            float rv[RV];
            const float* rp = &tile[(ty + ky) * RS + tx * OX];
            #pragma unroll
            for (int q2 = 0; q2 < RV / 4; ++q2)
                *(float4*)&rv[q2 * 4] = *(const float4*)(rp + q2 * 4);
            #pragma unroll
            for (int kx = 0; kx < KS; ++kx)
                #pragma unroll
                for (int oc = 0; oc < OCB; ++oc)
                    #pragma unroll
                    for (int ox = 0; ox < OX; ++ox)
                        acc[oc][ox] += rv[kx + ox] * wreg[oc][kx];
        }
    }
    const int y = y0 + ty, x = tx * OX;
    #pragma unroll
    for (int oc = 0; oc < OCB; ++oc) {
        float bv = bias[oc0 + oc];
        float vo[OX];
        #pragma unroll
        for (int ox = 0; ox < OX; ++ox) {
            float vv = acc[oc][ox] + bv;
            vo[ox] = do_gelu ? gelu_f(vv) : vv;
        }
        float* op = out + (((size_t)(b * COUT + oc0 + oc) * 64 + y)) * 64 + x;
        #pragma unroll
        for (int q2 = 0; q2 < OX / 4; ++q2)
            *(float4*)(op + q2 * 4) = *(float4*)&vo[q2 * 4];
    }
}

// ---------------- final 1x1 conv ----------------
__global__ __launch_bounds__(256) void conv1_kernel(const float* __restrict__ in,
    const float* __restrict__ w, const float* __restrict__ bias, float* __restrict__ out)
{
    int idx = blockIdx.x * 256 + threadIdx.x;
    int b = idx >> 12, p = idx & 4095;
    float a0 = bias[0], a1 = bias[1], a2 = bias[2];
    const float* ip = in + (size_t)b * 48 * NTOK + p;
    #pragma unroll 8
    for (int ic = 0; ic < 48; ++ic) {
        float v = ip[(size_t)ic * NTOK];
        a0 += v * w[ic]; a1 += v * w[48 + ic]; a2 += v * w[96 + ic];
    }
    float* op = out + (size_t)idx * 3;
    op[0] = a0; op[1] = a1; op[2] = a2;
}

// ---------------- host launch ----------------
static inline void gemm_mf(hipStream_t s, const float* A, const float* ascale,
                           const u16* Bhi, const u16* Blo,
                           const float* bias, const float* resid, float* C,
                           int M, int N, int K, int epi)
{
    dim3 g((N + 127) / 128, M / 128);
    hipLaunchKernelGGL(gemm_mfma, g, dim3(256), 0, s, A, ascale, Bhi, Blo, bias, resid, C, M, N, K, epi);
}

extern "C" void kernel_launch(void* const* d_in, const int* in_sizes, int n_in,
                              void* d_out, int out_size, void* d_ws, size_t ws_size,
                              hipStream_t stream)
{
    (void)in_sizes; (void)n_in; (void)out_size; (void)ws_size;
    const float* x        = (const float*)d_in[0];
    const float* to_in_w  = (const float*)d_in[1];
    const float* to_in_b  = (const float*)d_in[2];
    const float* pos_emb  = (const float*)d_in[3];
    const float* proj     = (const float*)d_in[4];
    const float* sn_attn_g= (const float*)d_in[5];
    const float* wq       = (const float*)d_in[6];
    const float* wk       = (const float*)d_in[7];
    const float* wv       = (const float*)d_in[8];
    const float* wo       = (const float*)d_in[9];
    const float* bo       = (const float*)d_in[10];
    const float* sn_ff_g  = (const float*)d_in[11];
    const float* w1       = (const float*)d_in[12];
    const float* b1       = (const float*)d_in[13];
    const float* w2       = (const float*)d_in[14];
    const float* b2       = (const float*)d_in[15];
    const float* expand_w = (const float*)d_in[16];
    const float* fwd_w    = (const float*)d_in[17];
    const float* dec_lin_w= (const float*)d_in[18];
    const float* dec_lin_b= (const float*)d_in[19];
    const float* gn_g     = (const float*)d_in[20];
    const float* gn_b     = (const float*)d_in[21];
    const float* c9_w     = (const float*)d_in[22];
    const float* c9_b     = (const float*)d_in[23];
    const float* c7_w     = (const float*)d_in[24];
    const float* c7_b     = (const float*)d_in[25];
    const float* c5_w     = (const float*)d_in[26];
    const float* c5_b     = (const float*)d_in[27];
    const float* c1_w     = (const float*)d_in[28];
    const float* c1_b     = (const float*)d_in[29];
    float* out = (float*)d_out;

    float* ws = (float*)d_ws;
    float* h   = ws + OFF_H;
    float* hn  = ws + OFF_HN;
    float* sbuf = ws + OFF_HN;        // rownorm scale (16384 f) — hn only live in decoder
    float* q   = ws + OFF_Q;
    float* k   = ws + OFF_K;
    float* v   = ws + OFF_V;
    float* big = ws + OFF_BIG;
    u16* pjhi = (u16*)(ws + OFF_PJ);
    u16* pjlo = pjhi + 6 * PJL;
    u16* cthi = (u16*)(ws + OFF_CTXT);
    u16* ctlo = cthi + CTXTN;
    unsigned* kmaxu = (unsigned*)(ws + OFF_KMAX);
    float2* gnp = (float2*)(ws + OFF_GNP);
    float2* gns = (float2*)(ws + OFF_GNS);
    u16* whi = (u16*)(ws + OFF_WHI);
    u16* wlo = (u16*)(ws + OFF_WLO);

    // prologue
    hipLaunchKernelGGL(input_embed, dim3(BNTOK * CDIM / 256), dim3(256), 0, stream,
                       x, to_in_w, to_in_b, pos_emb, h);
    hipLaunchKernelGGL(kmax_init, dim3(1), dim3(256), 0, stream, kmaxu);
    hipLaunchKernelGGL(cvt_qkv, dim3(6912), dim3(256), 0, stream, wq, wk, wv,
                       whi + WOFF_QKV, wlo + WOFF_QKV);
    hipLaunchKernelGGL(cvt_w, dim3(2304), dim3(256), 0, stream, wo, whi + WOFF_WO, wlo + WOFF_WO, 589824);
    hipLaunchKernelGGL(cvt_w, dim3(3456), dim3(256), 0, stream, w1, whi + WOFF_W1, wlo + WOFF_W1, 884736);
    hipLaunchKernelGGL(cvt_w, dim3(3456), dim3(256), 0, stream, w2, whi + WOFF_W2, wlo + WOFF_W2, 884736);
    hipLaunchKernelGGL(cvt_dec, dim3(432), dim3(256), 0, stream, expand_w, fwd_w, dec_lin_w,
                       whi + WOFF_EXP, wlo + WOFF_EXP);
    hipLaunchKernelGGL(cvt_pj, dim3(480), dim3(256), 0, stream, proj, pjhi, pjlo);

    for (int l = 0; l < NDEPTH; ++l) {
        const float* bo_l = bo + (size_t)l * CDIM;
        const float* b1_l = b1 + (size_t)l * CFF;
        const float* b2_l = b2 + (size_t)l * CDIM;
        const u16* pjh_l = pjhi + (size_t)l * PJL;
        const u16* pjl_l = pjlo + (size_t)l * PJL;
        unsigned* kmax_l = kmaxu + l * 32;

        // attn (scalenorm fused into qkv GEMM via rownorm scale)
        hipLaunchKernelGGL(rownorm_kernel, dim3(BNTOK / 4), dim3(256), 0, stream, h, sbuf, sn_attn_g, l);
        gemm_mf(stream, h, sbuf, whi + WOFF_QKV + (size_t)l * 294912, wlo + WOFF_QKV + (size_t)l * 294912,
                nullptr, nullptr, q, BNTOK, 1536, CDIM, 8);
        hipLaunchKernelGGL(kmax2_kernel, dim3(16, 32), dim3(256), 0, stream, k, pjh_l, kmax_l);
        hipLaunchKernelGGL(ctx2_kernel, dim3(32, 8), dim3(256), 0, stream, k, v, pjh_l, pjl_l, kmax_l, big);
        hipLaunchKernelGGL(ctxt_reduce, dim3(CTXTN / 256), dim3(256), 0, stream, big, cthi, ctlo);
        hipLaunchKernelGGL(qside2_kernel, dim3(64, 32), dim3(256), 0, stream, q, pjh_l, pjl_l, cthi, ctlo, k);
        gemm_mf(stream, k, nullptr, whi + WOFF_WO + (size_t)l * 98304, wlo + WOFF_WO + (size_t)l * 98304,
                bo_l, h, h, BNTOK, CDIM, CINNER, 1 | 4);

        // ff
        hipLaunchKernelGGL(rownorm_kernel, dim3(BNTOK / 4), dim3(256), 0, stream, h, sbuf, sn_ff_g, l);
        gemm_mf(stream, h, sbuf, whi + WOFF_W1 + (size_t)l * 147456, wlo + WOFF_W1 + (size_t)l * 147456,
                b1_l, nullptr, big, BNTOK, CFF, CDIM, 1 | 2);
        gemm_mf(stream, big, nullptr, whi + WOFF_W2 + (size_t)l * 147456, wlo + WOFF_W2 + (size_t)l * 147456,
                b2_l, h, h, BNTOK, CDIM, CFF, 1 | 4);
    }

    // decoder linears
    gemm_mf(stream, h, nullptr, whi + WOFF_EXP, wlo + WOFF_EXP, nullptr, nullptr, hn, BNTOK, CDIM, CDIM, 0);
    gemm_mf(stream, hn, nullptr, whi + WOFF_FWD, wlo + WOFF_FWD, nullptr, nullptr, h, BNTOK, CDIM, CDIM, 0);
    gemm_mf(stream, h, nullptr, whi + WOFF_DEC, wlo + WOFF_DEC, dec_lin_b, nullptr, hn, BNTOK, CDIM, CDIM, 1);

    // group norm + transpose to NCHW
    float* y0 = big;
    float* y1 = big + 3145728;
    float* y2 = big + 6291456;
    float* y3 = big + 7864320;
    hipLaunchKernelGGL(gn_part_kernel, dim3(16, 8, 4), dim3(256), 0, stream, hn, gnp);
    hipLaunchKernelGGL(gn_stat_kernel, dim3(1), dim3(32), 0, stream, gnp, gns);
    hipLaunchKernelGGL(gn_apply_kernel, dim3(64, 3, 4), dim3(256), 0, stream, hn, gns, gn_g, gn_b, y0);

    // convs v3: OX=8/YS=2, OCB=3, hoisted staging
    hipLaunchKernelGGL((circ_conv3<9, 192, 192, 8, 2, 3>), dim3(64, 2, 4), dim3(256), 0, stream,
                       y0, c9_w, c9_b, y1, 1);
    hipLaunchKernelGGL((circ_conv3<7, 192, 96, 8, 2, 3>), dim3(32, 2, 4), dim3(256), 0, stream,
                       y1, c7_w, c7_b, y2, 1);
    hipLaunchKernelGGL((circ_conv3<5, 96, 48, 4, 4, 3>), dim3(16, 4, 4), dim3(256), 0, stream,
                       y2, c5_w, c5_b, y3, 1);
    hipLaunchKernelGGL(conv1_kernel, dim3(BNTOK / 256), dim3(256), 0, stream, y3, c1_w, c1_b, out);
}